// Round 8
// baseline (559.391 us; speedup 1.0000x reference)
//
#include <hip/hip_runtime.h>
#include <math.h>

#define NB    4
#define NPTS  2048
#define ROWS  (NB*NPTS)   // 8192
#define CIN   64
#define COUT  256
#define KNBR  21
#define NHEADS 7
#define WCH   64
#define DSH   32
#define LOG2E 1.4426950408889634f
#define KLD   76   // LDS row stride (ushorts): 38 dwords -> permuted K rows 2-way free

typedef __attribute__((ext_vector_type(8))) short short8;
typedef __attribute__((ext_vector_type(4))) float floatx4;

#if __has_builtin(__builtin_amdgcn_exp2f)
#define EXP2(x) __builtin_amdgcn_exp2f(x)
#else
#define EXP2(x) __expf((x)*0.6931471805599453f)
#endif
#if __has_builtin(__builtin_amdgcn_rcpf)
#define RCP(x) __builtin_amdgcn_rcpf(x)
#else
#define RCP(x) (1.0f/(x))
#endif

__device__ __forceinline__ ushort f2bf(float x) {
    unsigned u = __float_as_uint(x);
    u += 0x7fffu + ((u >> 16) & 1u);   // RNE
    return (ushort)(u >> 16);
}

// packed f32x2 -> bf16x2 (RNE), single VALU inst; no builtin on gfx950
__device__ __forceinline__ unsigned cvt_pk_bf16(float lo, float hi) {
    unsigned r;
    asm("v_cvt_pk_bf16_f32 %0, %1, %2" : "=v"(r) : "v"(lo), "v"(hi));
    return r;
}

// wave64 u32 min-reduce via DPP chain; broadcast via readlane(63)
template<int CTRL, int RMASK>
__device__ __forceinline__ unsigned dpp_umin_step(unsigned x) {
    unsigned t = (unsigned)__builtin_amdgcn_update_dpp((int)x, (int)x, CTRL, RMASK, 0xF, false);
    return (t < x) ? t : x;
}
__device__ __forceinline__ unsigned wave_min_u32(unsigned x) {
    x = dpp_umin_step<0x111, 0xF>(x);
    x = dpp_umin_step<0x112, 0xF>(x);
    x = dpp_umin_step<0x114, 0xF>(x);
    x = dpp_umin_step<0x118, 0xF>(x);
    x = dpp_umin_step<0x142, 0xA>(x);
    x = dpp_umin_step<0x143, 0xC>(x);
    return (unsigned)__builtin_amdgcn_readlane((int)x, 63);
}

__device__ __forceinline__ unsigned umin2(unsigned a, unsigned b) { return a < b ? a : b; }
__device__ __forceinline__ unsigned umax2(unsigned a, unsigned b) { return a < b ? b : a; }

// insert k into sorted ascending 6-list (m1 smallest); 11 min/max ops, static regs
__device__ __forceinline__ void ins6(unsigned &m1, unsigned &m2, unsigned &m3,
                                     unsigned &m4, unsigned &m5, unsigned &m6, unsigned k) {
    unsigned c = k, t;
    t = umin2(m1, c); c = umax2(m1, c); m1 = t;
    t = umin2(m2, c); c = umax2(m2, c); m2 = t;
    t = umin2(m3, c); c = umax2(m3, c); m3 = t;
    t = umin2(m4, c); c = umax2(m4, c); m4 = t;
    t = umin2(m5, c); c = umax2(m5, c); m5 = t;
    m6 = umin2(m6, c);
}

// ---------------------------------------------------------------- fused prep (blocks 0..511) + KNN (blocks 512..2559)
__global__ __launch_bounds__(256) void prep_knn(const float* __restrict__ f, const float* __restrict__ Wf,
                                                const float* __restrict__ xyz, const float* __restrict__ Wg,
                                                const float* __restrict__ W_q, const float* __restrict__ W_k,
                                                const float* __restrict__ W_v, const float* __restrict__ W_fus,
                                                float* __restrict__ X, float* __restrict__ A,
                                                ushort* __restrict__ Wb, float* __restrict__ sums,
                                                int* __restrict__ idx) {
    __shared__ float4 SXQ[2048];
    int t = threadIdx.x;
    int blk = blockIdx.x;
    if (blk < 512) {
        // ======== prep path ========
        float* As = (float*)SXQ;
        float* Ws = As + 16*68;
        int bx = blk & 127, by = blk >> 7;
        if (by == 0 && bx < 12) sums[bx*256 + t] = 0.f;
        int gid = (by*128 + bx)*256 + t;
        for (int i = gid; i < 311296; i += 131072) {
            const float* Wsrc; int off;
            if (i < 65536)       { Wsrc = W_q;   off = i; }
            else if (i < 131072) { Wsrc = W_k;   off = i - 65536; }
            else if (i < 196608) { Wsrc = W_v;   off = i - 131072; }
            else                 { Wsrc = W_fus; off = i - 196608; }
            Wb[i] = f2bf(Wsrc[off]);
        }
        int r0 = bx * 64, n0 = by * 64;
        for (int e = t; e < 4096; e += 256) {
            int row = r0 + (e >> 6), c = n0 + (e & 63), cc = c & 127;
            float x = xyz[row*3], y = xyz[row*3+1], z = xyz[row*3+2];
            const float* w = Wg + cc*6;
            float s = (c < 128) ? ((w[3]*x + w[4]*y) + w[5]*z)
                                : (((w[0]-w[3])*x + (w[1]-w[4])*y) + (w[2]-w[5])*z);
            A[(size_t)row*256 + c] = s;
        }
        int b = r0 >> 11, nbase = r0 & 2047;
        int tx = t & 15, ty = t >> 4;
        float acc[4][4];
#pragma unroll
        for (int i = 0; i < 4; i++)
#pragma unroll
            for (int j = 0; j < 4; j++) acc[i][j] = 0.f;
        int m64 = t & 63, kg = t >> 6;
        int lk = t & 15, lm = t >> 4;
        for (int k0 = 0; k0 < 64; k0 += 16) {
#pragma unroll
            for (int p = 0; p < 4; p++) {
                int k = kg*4 + p;
                As[k*68 + m64] = f[(size_t)b*CIN*NPTS + (size_t)(k0 + k)*NPTS + nbase + m64];
            }
#pragma unroll
            for (int i2 = 0; i2 < 4; i2++) {
                int cg = n0 + lm + 16*i2;
                Ws[lk*68 + lm + 16*i2] = Wf[(size_t)(cg & 127)*128 + (cg >> 7)*64 + k0 + lk];
            }
            __syncthreads();
#pragma unroll
            for (int kq = 0; kq < 16; kq++) {
                float4 a  = *(const float4*)&As[kq*68 + 4*ty];
                float4 b4 = *(const float4*)&Ws[kq*68 + 4*tx];
                float av[4] = {a.x, a.y, a.z, a.w};
                float bv[4] = {b4.x, b4.y, b4.z, b4.w};
#pragma unroll
                for (int i = 0; i < 4; i++)
#pragma unroll
                    for (int j = 0; j < 4; j++) acc[i][j] = fmaf(av[i], bv[j], acc[i][j]);
            }
            __syncthreads();
        }
#pragma unroll
        for (int i = 0; i < 4; i++)
#pragma unroll
            for (int j = 0; j < 4; j++)
                X[(size_t)(r0 + 4*ty + i)*256 + n0 + 4*tx + j] = acc[i][j];
        return;
    }
    // ======== KNN path ========
    int kb = blk - 512;
    int b = kb >> 9;
    int g = kb & 511;
    for (int m = t; m < NPTS; m += 256) {
        float x = xyz[(size_t)b*NPTS*3 + m*3];
        float y = xyz[(size_t)b*NPTS*3 + m*3 + 1];
        float z = xyz[(size_t)b*NPTS*3 + m*3 + 2];
        SXQ[m] = make_float4(x, y, z, (x*x + y*y) + z*z);
    }
    __syncthreads();
    int w = t >> 6, lane = t & 63;
    int n = g*4 + w;
    float4 q4 = SXQ[n];
    float qx = q4.x, qy = q4.y, qz = q4.z, sqn = q4.w;

    // keys kept for exact fallback; two independent top-6 streams (halves dep chain)
    unsigned key[32];
    unsigned a1 = 0xFFFFFFFFu, a2 = 0xFFFFFFFFu, a3 = 0xFFFFFFFFu,
             a4 = 0xFFFFFFFFu, a5 = 0xFFFFFFFFu, a6 = 0xFFFFFFFFu;
    unsigned c1 = 0xFFFFFFFFu, c2 = 0xFFFFFFFFu, c3 = 0xFFFFFFFFu,
             c4 = 0xFFFFFFFFu, c5 = 0xFFFFFFFFu, c6 = 0xFFFFFFFFu;
#pragma unroll
    for (int i = 0; i < 16; i++) {
        int m = lane + (i << 6);
        float4 p = SXQ[m];
        float dt = (qx*p.x + qy*p.y) + qz*p.z;
        float d2 = fmaxf((sqn + p.w) - 2.0f*dt, 0.f);
        unsigned kv = (__float_as_uint(d2) & 0xFFFFF800u) | (unsigned)m;
        key[i] = kv;
        ins6(a1, a2, a3, a4, a5, a6, kv);
    }
#pragma unroll
    for (int i = 16; i < 32; i++) {
        int m = lane + (i << 6);
        float4 p = SXQ[m];
        float dt = (qx*p.x + qy*p.y) + qz*p.z;
        float d2 = fmaxf((sqn + p.w) - 2.0f*dt, 0.f);
        unsigned kv = (__float_as_uint(d2) & 0xFFFFF800u) | (unsigned)m;
        key[i] = kv;
        ins6(c1, c2, c3, c4, c5, c6, kv);
    }
    // merge stream C into A -> per-lane sorted top-6
    ins6(a1, a2, a3, a4, a5, a6, c1);
    ins6(a1, a2, a3, a4, a5, a6, c2);
    ins6(a1, a2, a3, a4, a5, a6, c3);
    ins6(a1, a2, a3, a4, a5, a6, c4);
    ins6(a1, a2, a3, a4, a5, a6, c5);
    ins6(a1, a2, a3, a4, a5, a6, c6);

    unsigned winkey = 0xFFFFFFFFu;
    {
        // 32-round multiway merge-pop over per-lane sorted fronts.
        // Exact while no lane pops all 6 (checked below; keys unique via index bits).
        unsigned fr = a1, p2 = a2, p3 = a3, p4 = a4, p5 = a5, p6 = a6;
#pragma unroll
        for (int kk = 0; kk < 32; kk++) {
            unsigned win = wave_min_u32(fr);
            if (lane == kk) winkey = win;
            bool own = (fr == win);
            fr = own ? p2 : fr;
            p2 = own ? p3 : p2;
            p3 = own ? p4 : p3;
            p4 = own ? p5 : p4;
            p5 = own ? p6 : p5;
            p6 = own ? 0xFFFFFFFFu : p6;
        }
        if (__ballot(fr == 0xFFFFFFFFu) != 0ULL) {
            // rare fallback (some lane contributed >=6 of top-32): exact serial
            // extraction over the untouched key[] array — original algorithm.
            winkey = 0xFFFFFFFFu;
            for (int kk = 0; kk < 32; kk++) {
                unsigned lv = key[0];
#pragma unroll
                for (int i = 1; i < 32; i++) lv = (key[i] < lv) ? key[i] : lv;
                unsigned win = wave_min_u32(lv);
                if (lane == kk) winkey = win;
                unsigned widx = win & 2047u;
                int slot = (int)(widx >> 6);
                bool own = (lane == (int)(widx & 63u));
#pragma unroll
                for (int i = 0; i < 32; i++)
                    if (i == slot && own) key[i] = 0xFFFFFFFFu;
            }
        }
    }
    double d2r;
    int mr;
    {
        double qx64 = (double)qx, qy64 = (double)qy, qz64 = (double)qz;
        double sqn64 = qx64*qx64 + qy64*qy64 + qz64*qz64;
        if (lane < 32) {
            mr = (int)(winkey & 2047u);
            float4 p = SXQ[mr];
            double x = (double)p.x, y = (double)p.y, z = (double)p.z;
            double sqm = x*x + y*y + z*z;
            double dt  = qx64*x + qy64*y + qz64*z;
            d2r = (sqn64 + sqm) - 2.0*dt;
        } else {
            d2r = INFINITY; mr = 0x7FFFFFFF;
        }
    }
#pragma unroll
    for (int k = 2; k <= 32; k <<= 1) {
#pragma unroll
        for (int j = k >> 1; j > 0; j >>= 1) {
            double od = __shfl_xor(d2r, j, 64);
            int    om = __shfl_xor(mr, j, 64);
            bool up    = ((lane & k) == 0);
            bool lower = ((lane & j) == 0);
            bool oless = (od < d2r) || (od == d2r && om < mr);
            bool keepOther = up ? (lower ? oless : !oless) : (lower ? !oless : oless);
            if (keepOther) { d2r = od; mr = om; }
        }
    }
    if (lane < KNBR)
        idx[((size_t)b*NPTS + n)*KNBR + lane] = mr;
}

// ---------------------------------------------------------------- stats + sign-selected extreme over K
__global__ __launch_bounds__(256) void stats_gf(const float* __restrict__ geoBC, const float* __restrict__ featAC,
                                                const int* __restrict__ idx, const float* __restrict__ g_geo,
                                                const float* __restrict__ g_feat,
                                                float* __restrict__ sums, float* __restrict__ xsel) {
    int c = threadIdx.x;
    int cc = c & 127;
    const float* base = (c < 128) ? geoBC : featAC;
    bool wantmax = ((c < 128) ? g_geo[cc] : g_feat[cc]) >= 0.f;
    float s = 0.f, ss = 0.f;
    int r0 = blockIdx.x * 32;
    for (int r = r0; r < r0 + 32; r++) {
        int b = r >> 11;
        float ctr = base[(size_t)r*256 + 128 + cc];
        float mx = -1e30f, mn = 1e30f;
        const int* ip = idx + (size_t)r*KNBR;
        for (int kk = 0; kk < KNBR; kk++) {
            int j = ip[kk];
            float xv = ctr + base[((size_t)(b*NPTS + j))*256 + cc];
            mx = fmaxf(mx, xv); mn = fminf(mn, xv);
            s += xv; ss += xv*xv;
        }
        xsel[(size_t)r*256 + c] = wantmax ? mx : mn;
    }
    atomicAdd(&sums[c], s);
    atomicAdd(&sums[256 + c], ss);
}

// ---------------------------------------------------------------- feature_ = relu(affine(xsel)) with inline BN finalize; + bn1 stats
__global__ __launch_bounds__(256) void feature_maxsel(const float* __restrict__ xsel, const float* __restrict__ sums,
                                                      const float* __restrict__ g_geo, const float* __restrict__ b_geo,
                                                      const float* __restrict__ g_feat, const float* __restrict__ b_feat,
                                                      float* __restrict__ feat, float* __restrict__ sums_bn1) {
    int c = threadIdx.x;
    const float inv = 1.0f / (float)(ROWS*KNBR);
    float mean = sums[c]*inv;
    float var  = sums[256+c]*inv - mean*mean;
    float g  = (c < 128) ? g_geo[c] : g_feat[c-128];
    float bb = (c < 128) ? b_geo[c] : b_feat[c-128];
    float sc = g / sqrtf(var + 1e-5f);
    float tt = bb - mean*sc;
    float s = 0.f, ss = 0.f;
    int r0 = blockIdx.x*32;
    for (int r = r0; r < r0+32; r++) {
        size_t i = (size_t)r*256 + c;
        float y = fmaxf(fmaf(sc, xsel[i], tt), 0.f);
        feat[i] = y; s += y; ss += y*y;
    }
    atomicAdd(&sums_bn1[c], s); atomicAdd(&sums_bn1[256+c], ss);
}

// ---------------------------------------------------------------- q/k/v GEMM via bf16 MFMA; inline bn1 finalize on A
__global__ __launch_bounds__(256) void gemm_qkv(const float* __restrict__ Af, const float* __restrict__ sums_in,
                                                const float* __restrict__ g_bn, const float* __restrict__ b_bn,
                                                const ushort* __restrict__ Wb,
                                                float* __restrict__ QKVF, float* __restrict__ sums) {
    __shared__ float bns[2][256];
    __shared__ float red[4][256][2];
    int t = threadIdx.x;
    int r0 = blockIdx.x * 64, g = blockIdx.y;
    int w = t >> 6, lane = t & 63;
    int r15 = lane & 15, quad = lane >> 4;
    {
        float mean = sums_in[512 + t] * (1.0f/(float)ROWS);
        float var  = sums_in[768 + t] * (1.0f/(float)ROWS) - mean*mean;
        float sc = g_bn[t] / sqrtf(var + 1e-5f);
        bns[0][t] = sc;
        bns[1][t] = b_bn[t] - mean*sc;
    }
    __syncthreads();
    short8 aq[8];
    {
        const float* ap = Af + (size_t)(r0 + 16*w + r15)*256;
#pragma unroll
        for (int kc = 0; kc < 8; kc++) {
            int k0 = 32*kc + 8*quad;
            float4 a0 = *(const float4*)&ap[k0];
            float4 a1 = *(const float4*)&ap[k0+4];
            float4 s0 = *(const float4*)&bns[0][k0];
            float4 s1 = *(const float4*)&bns[0][k0+4];
            float4 h0 = *(const float4*)&bns[1][k0];
            float4 h1 = *(const float4*)&bns[1][k0+4];
            ushort u8[8];
            u8[0] = f2bf(fmaf(s0.x, a0.x, h0.x)); u8[1] = f2bf(fmaf(s0.y, a0.y, h0.y));
            u8[2] = f2bf(fmaf(s0.z, a0.z, h0.z)); u8[3] = f2bf(fmaf(s0.w, a0.w, h0.w));
            u8[4] = f2bf(fmaf(s1.x, a1.x, h1.x)); u8[5] = f2bf(fmaf(s1.y, a1.y, h1.y));
            u8[6] = f2bf(fmaf(s1.z, a1.z, h1.z)); u8[7] = f2bf(fmaf(s1.w, a1.w, h1.w));
            aq[kc] = *(short8*)u8;
        }
    }
    floatx4 zero4 = {0.f, 0.f, 0.f, 0.f};
    floatx4 acc[16];
#pragma unroll
    for (int st = 0; st < 16; st++) acc[st] = zero4;
    const ushort* wbase = Wb + (size_t)g*65536 + (size_t)r15*256 + 8*quad;
#pragma unroll
    for (int st = 0; st < 16; st++) {
        const ushort* wp = wbase + (size_t)(16*st)*256;
#pragma unroll
        for (int kc = 0; kc < 8; kc++) {
            short8 bf = *(const short8*)(wp + 32*kc);
            acc[st] = __builtin_amdgcn_mfma_f32_16x16x32_bf16(aq[kc], bf, acc[st], 0, 0, 0);
        }
    }
#pragma unroll
    for (int st = 0; st < 16; st++) {
        float s  = (acc[st][0] + acc[st][1]) + (acc[st][2] + acc[st][3]);
        float q2 = (acc[st][0]*acc[st][0] + acc[st][1]*acc[st][1]) +
                   (acc[st][2]*acc[st][2] + acc[st][3]*acc[st][3]);
        s  += __shfl_xor(s, 16, 64);  s  += __shfl_xor(s, 32, 64);
        q2 += __shfl_xor(q2, 16, 64); q2 += __shfl_xor(q2, 32, 64);
        if (lane < 16) { red[w][16*st + r15][0] = s; red[w][16*st + r15][1] = q2; }
#pragma unroll
        for (int reg = 0; reg < 4; reg++)
            QKVF[(size_t)(r0 + 16*w + 4*quad + reg)*768 + g*256 + 16*st + r15] = acc[st][reg];
    }
    __syncthreads();
    {
        float s = red[0][t][0] + red[1][t][0] + red[2][t][0] + red[3][t][0];
        float q = red[0][t][1] + red[1][t][1] + red[2][t][1] + red[3][t][1];
        atomicAdd(&sums[1024 + g*512 + t], s);
        atomicAdd(&sums[1024 + g*512 + 256 + t], q);
    }
}

// ---------------------------------------------------------------- affine+relu+bf16 (inline qkv BN finalize): q/k row-major (q scaled by log2e), v transposed
__global__ __launch_bounds__(256) void affine_qkv(const float* __restrict__ QKVF, const float* __restrict__ sums,
                                                  const float* __restrict__ g_q, const float* __restrict__ b_q,
                                                  const float* __restrict__ g_k, const float* __restrict__ b_k,
                                                  const float* __restrict__ g_v, const float* __restrict__ b_v,
                                                  ushort* __restrict__ qk, ushort* __restrict__ vt) {
    __shared__ float sts[6][256];
    __shared__ ushort tile[64][72];
    int t = threadIdx.x;
    {
        const float* gs[3] = {g_q, g_k, g_v};
        const float* bs[3] = {b_q, b_k, b_v};
#pragma unroll
        for (int g = 0; g < 3; g++) {
            float mean = sums[1024 + g*512 + t] * (1.0f/(float)ROWS);
            float var  = sums[1024 + g*512 + 256 + t] * (1.0f/(float)ROWS) - mean*mean;
            float sc = gs[g][t] / sqrtf(var + 1e-5f);
            float sh = bs[g][t] - mean*sc;
            if (g == 0) { sc *= LOG2E; sh *= LOG2E; }   // exp2-domain softmax
            sts[2*g][t] = sc;
            sts[2*g+1][t] = sh;
        }
    }
    __syncthreads();
    int r0 = blockIdx.x * 64, c0 = blockIdx.y * 64;
    int b = r0 >> 11, nbase = r0 & 2047;
    if (c0 < 512) {
#pragma unroll
        for (int rep = 0; rep < 16; rep++) {
            int e = t + 256*rep;
            int row = e >> 6, c = e & 63;
            int col = c0 + c, g = col >> 8, cc = col & 255;
            float v = QKVF[(size_t)(r0 + row)*768 + col];
            v = fmaxf(fmaf(sts[2*g][cc], v, sts[2*g+1][cc]), 0.f);
            qk[(size_t)(r0 + row)*512 + col] = f2bf(v);
        }
    } else {
#pragma unroll
        for (int rep = 0; rep < 16; rep++) {
            int e = t + 256*rep;
            int row = e >> 6, c = e & 63;
            int col = c0 + c, cc = col & 255;
            float v = QKVF[(size_t)(r0 + row)*768 + col];
            v = fmaxf(fmaf(sts[4][cc], v, sts[5][cc]), 0.f);
            tile[c][row] = f2bf(v);
        }
        __syncthreads();
#pragma unroll
        for (int rep = 0; rep < 16; rep++) {
            int e = t + 256*rep;
            int cc = e >> 6, nn = e & 63;
            vt[((size_t)(b*256 + (c0 - 512) + cc))*2048 + nbase + nn] = tile[cc][nn];
        }
    }
}

// ---------------------------------------------------------------- MFMA bf16 flash attention v6: P entirely in registers.
// Key-permuted QK^T: K rows fed in order K_tt[i]=8(i>>2)+(i&3)+4(tt&1)+32(tt>>1)
// so lane (r15,quad) ends holding S[keys 8q..8q+7, 32+8q..32+8q+7][r15] —
// exactly PV's B-fragment keys. P -> pf is 8 cvt_pk, no LDS, no shuffles.
// K+V LDS double-buffered (stride 76 keeps permuted reads 2-way), raw barriers.
// 8 waves x QBLK=16 = 128 rows/block, 448 blocks.
__global__ __launch_bounds__(512) void attn2(const ushort* __restrict__ qk, const ushort* __restrict__ vt,
                                             float* __restrict__ obuf) {
    __shared__ ushort Ksh[2][64*KLD];
    __shared__ ushort Vts[2][64*KLD];
    int h = blockIdx.y, b = blockIdx.z;
    int r0 = blockIdx.x * 128;
    int t = threadIdx.x;
    int w = t >> 6, lane = t & 63;
    int r15 = lane & 15, quad = lane >> 4;
    size_t rowbase = (size_t)b*NPTS;
    int hoff = h*DSH;
    int rr = t >> 3, c8 = t & 7;

    const ushort* ksrc = qk + (rowbase + rr)*512 + 256 + hoff + 8*c8;     // + m0*512
    const ushort* vsrc = vt + ((size_t)(b*256 + hoff + rr))*2048 + 8*c8;  // + m0
    int ldst = rr*KLD + 8*c8;

    // permuted K-row base for this lane: rows base + {0,4,32,36}
    int kbase = ((r15 & 12) << 1) + (r15 & 3);

    short8 aq[2];
#pragma unroll
    for (int s = 0; s < 2; s++)
        aq[s] = *(const short8*)(qk + (rowbase + r0 + 16*w + r15)*512 + hoff + 32*s + 8*quad);

    // stage tile 0 into buffer 0
    {
        uint4 k0 = *(const uint4*)(ksrc);
        uint4 v0 = *(const uint4*)(vsrc);
        *(uint4*)&Ksh[0][ldst] = k0;
        *(uint4*)&Vts[0][ldst] = v0;
    }

    floatx4 zero4 = {0.f, 0.f, 0.f, 0.f};
    floatx4 oacc[4];
    float mrun = -1e30f, lrun = 0.f;
#pragma unroll
    for (int i = 0; i < 4; i++) oacc[i] = zero4;

    asm volatile("s_waitcnt lgkmcnt(0)" ::: "memory");
    __builtin_amdgcn_s_barrier();
    __builtin_amdgcn_sched_barrier(0);

    int cur = 0;
    for (int m0 = 0; m0 < NPTS; m0 += 64) {
        // prefetch next KV tile into registers (latency hides under compute)
        int mnext = (m0 + 64 < NPTS) ? (m0 + 64) : 0;
        uint4 kreg = *(const uint4*)(ksrc + (size_t)mnext*512);
        uint4 vreg = *(const uint4*)(vsrc + mnext);

        const ushort* Kc = Ksh[cur];
        const ushort* Vc = Vts[cur];

        // S = K * Q^T, key-permuted tiles: sacc[tt] covers keys 8q+reg+4(tt&1)+32(tt>>1)
        floatx4 sacc[4];
#pragma unroll
        for (int tt = 0; tt < 4; tt++) sacc[tt] = zero4;
        __builtin_amdgcn_s_setprio(1);
#pragma unroll
        for (int tt = 0; tt < 4; tt++) {
            int krow = kbase + ((tt & 1) << 2) + ((tt >> 1) << 5);
#pragma unroll
            for (int s = 0; s < 2; s++) {
                short8 kf = *(const short8*)&Kc[krow*KLD + 32*s + 8*quad];
                sacc[tt] = __builtin_amdgcn_mfma_f32_16x16x32_bf16(kf, aq[s], sacc[tt], 0, 0, 0);
            }
        }
        __builtin_amdgcn_s_setprio(0);

        // lane-local row max over this lane's 16 keys, then cross-quad (same r15)
        float mx = sacc[0][0];
#pragma unroll
        for (int tt = 0; tt < 4; tt++)
#pragma unroll
            for (int reg = 0; reg < 4; reg++) mx = fmaxf(mx, sacc[tt][reg]);
        mx = fmaxf(mx, __shfl_xor(mx, 16, 64));
        mx = fmaxf(mx, __shfl_xor(mx, 32, 64));

        // defer-rescale: alpha==1 exactly when no row in the wave got a new max
        if (!__all(mx <= mrun)) {
            float mnew = fmaxf(mrun, mx);
            float alpha = EXP2(mrun - mnew);
            lrun *= alpha;
#pragma unroll
            for (int td = 0; td < 4; td++) oacc[td] *= alpha;
            mrun = mnew;
        }

        // P = exp2(S - m): pm[tt][reg] = P[key 8q + 4(tt&1) + reg + 32(tt>>1)][r15]
        float pm[4][4];
        float rs = 0.f;
#pragma unroll
        for (int tt = 0; tt < 4; tt++) {
#pragma unroll
            for (int reg = 0; reg < 4; reg++) {
                float p = EXP2(sacc[tt][reg] - mrun);
                pm[tt][reg] = p; rs += p;
            }
        }
        rs += __shfl_xor(rs, 16, 64);
        rs += __shfl_xor(rs, 32, 64);
        lrun += rs;

        // pf[s] = P[keys 32s+8q .. 32s+8q+7][r15] — pure in-register pack
        uint4 pk0, pk1;
        pk0.x = cvt_pk_bf16(pm[0][0], pm[0][1]); pk0.y = cvt_pk_bf16(pm[0][2], pm[0][3]);
        pk0.z = cvt_pk_bf16(pm[1][0], pm[1][1]); pk0.w = cvt_pk_bf16(pm[1][2], pm[1][3]);
        pk1.x = cvt_pk_bf16(pm[2][0], pm[2][1]); pk1.y = cvt_pk_bf16(pm[2][2], pm[2][3]);
        pk1.z = cvt_pk_bf16(pm[3][0], pm[3][1]); pk1.w = cvt_pk_bf16(pm[3][2], pm[3][3]);
        short8 pf0 = *(short8*)&pk0;
        short8 pf1 = *(short8*)&pk1;

        // O^T += V^T * P^T
        __builtin_amdgcn_s_setprio(1);
#pragma unroll
        for (int td = 0; td < 4; td++) {
            short8 vf0 = *(const short8*)&Vc[(16*td + r15)*KLD + 8*quad];
            oacc[td] = __builtin_amdgcn_mfma_f32_16x16x32_bf16(vf0, pf0, oacc[td], 0, 0, 0);
            short8 vf1 = *(const short8*)&Vc[(16*td + r15)*KLD + 32 + 8*quad];
            oacc[td] = __builtin_amdgcn_mfma_f32_16x16x32_bf16(vf1, pf1, oacc[td], 0, 0, 0);
        }
        __builtin_amdgcn_s_setprio(0);

        // write prefetched tile into the other buffer (vmcnt wait is ~free by now)
        *(uint4*)&Ksh[cur ^ 1][ldst] = kreg;
        *(uint4*)&Vts[cur ^ 1][ldst] = vreg;
        cur ^= 1;

        // drain own LDS ops, raw barrier (no vmcnt drain), fence scheduler
        asm volatile("s_waitcnt lgkmcnt(0)" ::: "memory");
        __builtin_amdgcn_s_barrier();
        __builtin_amdgcn_sched_barrier(0);
    }

    // lane holds O^T[vchan=16td+4quad+reg][qrow=r15]; coalesced float4 stores
    float invl = RCP(lrun);
#pragma unroll
    for (int td = 0; td < 4; td++) {
        floatx4 o = oacc[td] * invl;
        *(float4*)&obuf[(rowbase + r0 + 16*w + r15)*(size_t)(NHEADS*WCH) + h*WCH + 16*td + 4*quad] =
            *(float4*)&o;
    }
}

// ---------------------------------------------------------------- fus GEMM (bf16 MFMA); A = normalized attention output; bias; stats
__global__ __launch_bounds__(256) void gemm_fus(const float* __restrict__ OBUF, const ushort* __restrict__ Wb,
                                                const float* __restrict__ bias, float* __restrict__ C,
                                                float* __restrict__ sums) {
    __shared__ float red[4][128][2];
    int t = threadIdx.x;
    int r0 = blockIdx.x * 64, n0 = blockIdx.y * 128;
    int w = t >> 6, lane = t & 63;
    int r15 = lane & 15, quad = lane >> 4;
    int arow = 16*w + r15;
    short8 aq[14];
    {
        const float* p0 = OBUF + (size_t)(r0 + arow)*448;
#pragma unroll
        for (int kc = 0; kc < 14; kc++) {
            int k0 = 32*kc + 8*quad;
            float4 x0 = *(const float4*)&p0[k0];
            float4 y0 = *(const float4*)&p0[k0+4];
            ushort u8[8];
            u8[0] = f2bf(x0.x); u8[1] = f2bf(x0.y);
            u8[2] = f2bf(x0.z); u8[3] = f2bf(x0.w);
            u8[4] = f2bf(y0.x); u8[5] = f2bf(y0.y);
            u8[6] = f2bf(y0.z); u8[7] = f2bf(y0.w);
            aq[kc] = *(short8*)u8;
        }
    }
    floatx4 zero4 = {0.f, 0.f, 0.f, 0.f};
    floatx4 acc[8];
#pragma unroll
    for (int st = 0; st < 8; st++) acc[st] = zero4;
    const ushort* wbase = Wb + 196608 + (size_t)(n0 + r15)*448 + 8*quad;
#pragma unroll
    for (int st = 0; st < 8; st++) {
        const ushort* wp = wbase + (size_t)(16*st)*448;
#pragma unroll
        for (int kc = 0; kc < 14; kc++) {
            short8 bf = *(const short8*)(wp + 32*kc);
            acc[st] = __builtin_amdgcn_mfma_f32_16x16x32_bf16(aq[kc], bf, acc[st], 0, 0, 0);
        }
    }
#pragma unroll
    for (int st = 0; st < 8; st++) {
        int col = n0 + 16*st + r15;
        float bi = bias[col];
        float v0 = acc[st][0] + bi, v1 = acc[st][1] + bi, v2 = acc[st][2] + bi, v3 = acc[st][3] + bi;
        float s  = (v0 + v1) + (v2 + v3);
        float q2 = (v0*v0 + v1*v1) + (v2*v2 + v3*v3);
        s  += __shfl_xor(s, 16, 64);  s  += __shfl_xor(s, 32, 64);
        q2 += __shfl_xor(q2, 16, 64); q2 += __shfl_xor(q2, 32, 64);
        if (lane < 16) { red[w][16*st + r15][0] = s; red[w][16*st + r15][1] = q2; }
        C[(size_t)(r0 + 16*w + 4*quad + 0)*256 + col] = v0;
        C[(size_t)(r0 + 16*w + 4*quad + 1)*256 + col] = v1;
        C[(size_t)(r0 + 16*w + 4*quad + 2)*256 + col] = v2;
        C[(size_t)(r0 + 16*w + 4*quad + 3)*256 + col] = v3;
    }
    __syncthreads();
    {
        int col = t >> 1, which = t & 1;
        float v = red[0][col][which] + red[1][col][which] + red[2][col][which] + red[3][col][which];
        atomicAdd(&sums[2560 + which*256 + n0 + col], v);
    }
}

// ---------------------------------------------------------------- fused: fus-BN+relu+residual+LN (per-row) + MLP GEMM + residual + transposed out
__global__ __launch_bounds__(256) void gemm_mlp_ln(const float* __restrict__ FUSP, const float* __restrict__ A,
                                                   const float* __restrict__ sums,
                                                   const float* __restrict__ g_fus, const float* __restrict__ b_fus,
                                                   const float* __restrict__ g_ln, const float* __restrict__ b_ln,
                                                   const float* __restrict__ W, const float* __restrict__ bias,
                                                   float* __restrict__ outp) {
    __shared__ float Ys[256][68];    // y (LN out), k-major: Ys[c][row]
    __shared__ float FFs[64][65];    // feature__ tile (cols n0..n0+63)
    __shared__ float Ws[16][68];
    __shared__ float tr[64][65];
    __shared__ float SC[256], SH[256], GL[256], BL[256];
    int t = threadIdx.x;
    int r0 = blockIdx.x*64, n0 = blockIdx.y*64;
    {
        float mean0 = sums[2560 + t] * (1.0f/(float)ROWS);
        float var0  = sums[2560 + 256 + t] * (1.0f/(float)ROWS) - mean0*mean0;
        float sc = g_fus[t] / sqrtf(var0 + 1e-5f);
        SC[t] = sc; SH[t] = b_fus[t] - mean0*sc;
        GL[t] = g_ln[t]; BL[t] = b_ln[t];
    }
    __syncthreads();
    int row = t >> 2, seg = t & 3;
    size_t rb = (size_t)(r0 + row)*256;
    float4 vv[16];
    float s = 0.f, ss = 0.f;
#pragma unroll
    for (int j = 0; j < 16; j++) {
        int c = seg*64 + 4*j;
        float4 fp = *(const float4*)&FUSP[rb + c];
        float4 fe = *(const float4*)&A[rb + c];
        float4 sc4 = *(const float4*)&SC[c];
        float4 sh4 = *(const float4*)&SH[c];
        float4 v;
        v.x = fmaxf(fmaf(sc4.x, fp.x, sh4.x), 0.f) + fe.x;
        v.y = fmaxf(fmaf(sc4.y, fp.y, sh4.y), 0.f) + fe.y;
        v.z = fmaxf(fmaf(sc4.z, fp.z, sh4.z), 0.f) + fe.z;
        v.w = fmaxf(fmaf(sc4.w, fp.w, sh4.w), 0.f) + fe.w;
        vv[j] = v;
        s  += (v.x + v.y) + (v.z + v.w);
        ss += (v.x*v.x + v.y*v.y) + (v.z*v.z + v.w*v.w);
        if (seg == blockIdx.y) *(float4*)&FFs[row][4*j] = v;
    }
    s  += __shfl_xor(s, 1, 64);  s  += __shfl_xor(s, 2, 64);
    ss += __shfl_xor(ss, 1, 64); ss += __shfl_xor(ss, 2, 64);
    float mean = s * (1.f/256.f);
    float var  = ss * (1.f/256.f) - mean*mean;
    float rin  = 1.f/sqrtf(var + 1e-5f);
#pragma unroll
    for (int j = 0; j < 16; j++) {
        int c = seg*64 + 4*j;
        float4 gl = *(const float4*)&GL[c];
        float4 bl = *(const float4*)&BL[c];
        float4 v = vv[j];
        Ys[c+0][row] = (v.x - mean)*rin*gl.x + bl.x;
        Ys[c+1][row] = (v.y - mean)*rin*gl.y + bl.y;
        Ys[c+2][row] = (v.z - mean)*rin*gl.z + bl.z;
        Ys[c+3][row] = (v.w - mean)*rin*gl.w + bl.w;
    }
    __syncthreads();
    // GEMM: y[64rows x 256] * W_mlp[n0..n0+63][256]^T
    int tx = t & 15, ty = t >> 4;
    int lk = t & 15, lm = t >> 4;
    float acc[4][4];
#pragma unroll
    for (int i = 0; i < 4; i++)
#pragma unroll
        for (int j = 0; j < 4; j++) acc[i][j] = 0.f;
    for (int k0 = 0; k0 < 256; k0 += 16) {
#pragma unroll
        for (int i2 = 0; i2 < 4; i2++)
            Ws[lk][lm + 16*i2] = W[(size_t)(n0 + lm + 16*i2)*256 + k0 + lk];
        __syncthreads();
#pragma unroll
        for (int kq = 0; kq < 16; kq++) {
            float4 a  = *(const float4*)&Ys[k0 + kq][4*ty];
            float4 b4 = *(const float4*)&Ws[kq][4*tx];
            float av[4] = {a.x, a.y, a.z, a.w};
            float bv[4] = {b4.x, b4.y, b4.z, b4.w};
#pragma unroll
            for (int i = 0; i < 4; i++)
#pragma unroll
                for (int j = 0; j < 4; j++) acc[i][j] = fmaf(av[i], bv[j], acc[i][j]);
        }
        __syncthreads();
    }
#pragma unroll
    for (int i = 0; i < 4; i++)
#pragma unroll
        for (int j = 0; j < 4; j++) {
            float v = acc[i][j] + bias[n0 + 4*tx + j] + FFs[4*ty + i][4*tx + j];
            tr[4*tx + j][4*ty + i] = v;
        }
    __syncthreads();
    int b = r0 >> 11, nbase = r0 & 2047;
#pragma unroll
    for (int rep = 0; rep < 16; rep++) {
        int e = t + 256*rep;
        int cl = e >> 6, nl = e & 63;
        outp[((size_t)(b*256 + n0 + cl))*2048 + nbase + nl] = tr[cl][nl];
    }
}

// ================================================================ host
extern "C" void kernel_launch(void* const* d_in, const int* in_sizes, int n_in,
                              void* d_out, int out_size, void* d_ws, size_t ws_size,
                              hipStream_t stream) {
    const float* xyz    = (const float*)d_in[0];
    const float* f      = (const float*)d_in[1];
    const float* W_geo  = (const float*)d_in[2];
    const float* g_geo  = (const float*)d_in[3];
    const float* b_geo  = (const float*)d_in[4];
    const float* W_feat = (const float*)d_in[5];
    const float* g_feat = (const float*)d_in[6];
    const float* b_feat = (const float*)d_in[7];
    const float* g_bn   = (const float*)d_in[8];
    const float* b_bn   = (const float*)d_in[9];
    const float* W_q    = (const float*)d_in[10];
    const float* g_q    = (const float*)d_in[11];
    const float* b_q    = (const float*)d_in[12];
    const float* W_k    = (const float*)d_in[13];
    const float* g_k    = (const float*)d_in[14];
    const float* b_k    = (const float*)d_in[15];
    const float* W_v    = (const float*)d_in[16];
    const float* g_v    = (const float*)d_in[17];
    const float* b_v    = (const float*)d_in[18];
    const float* W_fus  = (const float*)d_in[19];
    const float* bias_fus = (const float*)d_in[20];
    const float* g_fus  = (const float*)d_in[21];
    const float* b_fus  = (const float*)d_in[22];
    const float* g_ln   = (const float*)d_in[23];
    const float* b_ln   = (const float*)d_in[24];
    const float* W_mlp  = (const float*)d_in[25];
    const float* bias_mlp = (const float*)d_in[26];

    float* ws = (float*)d_ws;
    const size_t MBF = 262144;  // floats per MiB
    float* SUMS  = ws;
    int*   IDX   = (int*)(ws + 16384);
    float* A     = ws + 1*MBF;
    float* X     = ws + 9*MBF;
    ushort* QK16 = (ushort*)(ws + 9*MBF);
    float* FUSP  = ws + 9*MBF;
    float* CSEL  = ws + 17*MBF;
    float* QKVF  = ws + 17*MBF;
    float* OBUF  = ws + 17*MBF;
    ushort* VT16 = (ushort*)(ws + 45*MBF);
    ushort* WB16 = (ushort*)(ws + 49*MBF);

    prep_knn<<<2560, 256, 0, stream>>>(f, W_feat, xyz, W_geo, W_q, W_k, W_v, W_fus,
                                       X, A, WB16, SUMS, IDX);
    stats_gf<<<256, 256, 0, stream>>>(A, X, IDX, g_geo, g_feat, SUMS, CSEL);
    feature_maxsel<<<256, 256, 0, stream>>>(CSEL, SUMS, g_geo, b_geo, g_feat, b_feat, A, SUMS + 512);
    gemm_qkv<<<dim3(128, 3), 256, 0, stream>>>(A, SUMS, g_bn, b_bn, WB16, QKVF, SUMS);
    affine_qkv<<<dim3(128, 12), 256, 0, stream>>>(QKVF, SUMS, g_q, b_q, g_k, b_k, g_v, b_v, QK16, VT16);
    attn2<<<dim3(NPTS/128, NHEADS, NB), 512, 0, stream>>>(QK16, VT16, OBUF);
    gemm_fus<<<dim3(128, 2), 256, 0, stream>>>(OBUF, WB16, bias_fus, FUSP, SUMS);
    gemm_mlp_ln<<<dim3(128, 4), 256, 0, stream>>>(FUSP, A, SUMS, g_fus, b_fus, g_ln, b_ln,
                                                  W_mlp, bias_mlp, (float*)d_out);
}

// Round 9
// 376.303 us; speedup vs baseline: 1.4865x; 1.4865x over previous
//
#include <hip/hip_runtime.h>
#include <math.h>

#define NB    4
#define NPTS  2048
#define ROWS  (NB*NPTS)   // 8192
#define CIN   64
#define COUT  256
#define KNBR  21
#define NHEADS 7
#define WCH   64
#define DSH   32
#define LOG2E 1.4426950408889634f
#define KLD   72   // LDS row stride in ushorts = 144 B: multiple of 16 B (b128-aligned)

typedef __attribute__((ext_vector_type(8))) short short8;
typedef __attribute__((ext_vector_type(4))) float floatx4;

#if __has_builtin(__builtin_amdgcn_exp2f)
#define EXP2(x) __builtin_amdgcn_exp2f(x)
#else
#define EXP2(x) __expf((x)*0.6931471805599453f)
#endif
#if __has_builtin(__builtin_amdgcn_rcpf)
#define RCP(x) __builtin_amdgcn_rcpf(x)
#else
#define RCP(x) (1.0f/(x))
#endif

__device__ __forceinline__ ushort f2bf(float x) {
    unsigned u = __float_as_uint(x);
    u += 0x7fffu + ((u >> 16) & 1u);   // RNE
    return (ushort)(u >> 16);
}

// packed f32x2 -> bf16x2 (RNE), single VALU inst; no builtin on gfx950
__device__ __forceinline__ unsigned cvt_pk_bf16(float lo, float hi) {
    unsigned r;
    asm("v_cvt_pk_bf16_f32 %0, %1, %2" : "=v"(r) : "v"(lo), "v"(hi));
    return r;
}

// wave64 u32 min-reduce via DPP chain; broadcast via readlane(63)
template<int CTRL, int RMASK>
__device__ __forceinline__ unsigned dpp_umin_step(unsigned x) {
    unsigned t = (unsigned)__builtin_amdgcn_update_dpp((int)x, (int)x, CTRL, RMASK, 0xF, false);
    return (t < x) ? t : x;
}
__device__ __forceinline__ unsigned wave_min_u32(unsigned x) {
    x = dpp_umin_step<0x111, 0xF>(x);
    x = dpp_umin_step<0x112, 0xF>(x);
    x = dpp_umin_step<0x114, 0xF>(x);
    x = dpp_umin_step<0x118, 0xF>(x);
    x = dpp_umin_step<0x142, 0xA>(x);
    x = dpp_umin_step<0x143, 0xC>(x);
    return (unsigned)__builtin_amdgcn_readlane((int)x, 63);
}

__device__ __forceinline__ unsigned umin2(unsigned a, unsigned b) { return a < b ? a : b; }
__device__ __forceinline__ unsigned umax2(unsigned a, unsigned b) { return a < b ? b : a; }

// insert k into sorted ascending 6-list (m1 smallest); 11 min/max ops, static regs
__device__ __forceinline__ void ins6(unsigned &m1, unsigned &m2, unsigned &m3,
                                     unsigned &m4, unsigned &m5, unsigned &m6, unsigned k) {
    unsigned c = k, t;
    t = umin2(m1, c); c = umax2(m1, c); m1 = t;
    t = umin2(m2, c); c = umax2(m2, c); m2 = t;
    t = umin2(m3, c); c = umax2(m3, c); m3 = t;
    t = umin2(m4, c); c = umax2(m4, c); m4 = t;
    t = umin2(m5, c); c = umax2(m5, c); m5 = t;
    m6 = umin2(m6, c);
}

// ---------------------------------------------------------------- fused prep (blocks 0..511) + KNN (blocks 512..2559)
__global__ __launch_bounds__(256) void prep_knn(const float* __restrict__ f, const float* __restrict__ Wf,
                                                const float* __restrict__ xyz, const float* __restrict__ Wg,
                                                const float* __restrict__ W_q, const float* __restrict__ W_k,
                                                const float* __restrict__ W_v, const float* __restrict__ W_fus,
                                                float* __restrict__ X, float* __restrict__ A,
                                                ushort* __restrict__ Wb, float* __restrict__ sums,
                                                int* __restrict__ idx) {
    __shared__ float4 SXQ[2048];
    int t = threadIdx.x;
    int blk = blockIdx.x;
    if (blk < 512) {
        // ======== prep path ========
        float* As = (float*)SXQ;
        float* Ws = As + 16*68;
        int bx = blk & 127, by = blk >> 7;
        if (by == 0 && bx < 12) sums[bx*256 + t] = 0.f;
        int gid = (by*128 + bx)*256 + t;
        for (int i = gid; i < 311296; i += 131072) {
            const float* Wsrc; int off;
            if (i < 65536)       { Wsrc = W_q;   off = i; }
            else if (i < 131072) { Wsrc = W_k;   off = i - 65536; }
            else if (i < 196608) { Wsrc = W_v;   off = i - 131072; }
            else                 { Wsrc = W_fus; off = i - 196608; }
            Wb[i] = f2bf(Wsrc[off]);
        }
        int r0 = bx * 64, n0 = by * 64;
        for (int e = t; e < 4096; e += 256) {
            int row = r0 + (e >> 6), c = n0 + (e & 63), cc = c & 127;
            float x = xyz[row*3], y = xyz[row*3+1], z = xyz[row*3+2];
            const float* w = Wg + cc*6;
            float s = (c < 128) ? ((w[3]*x + w[4]*y) + w[5]*z)
                                : (((w[0]-w[3])*x + (w[1]-w[4])*y) + (w[2]-w[5])*z);
            A[(size_t)row*256 + c] = s;
        }
        int b = r0 >> 11, nbase = r0 & 2047;
        int tx = t & 15, ty = t >> 4;
        float acc[4][4];
#pragma unroll
        for (int i = 0; i < 4; i++)
#pragma unroll
            for (int j = 0; j < 4; j++) acc[i][j] = 0.f;
        int m64 = t & 63, kg = t >> 6;
        int lk = t & 15, lm = t >> 4;
        for (int k0 = 0; k0 < 64; k0 += 16) {
#pragma unroll
            for (int p = 0; p < 4; p++) {
                int k = kg*4 + p;
                As[k*68 + m64] = f[(size_t)b*CIN*NPTS + (size_t)(k0 + k)*NPTS + nbase + m64];
            }
#pragma unroll
            for (int i2 = 0; i2 < 4; i2++) {
                int cg = n0 + lm + 16*i2;
                Ws[lk*68 + lm + 16*i2] = Wf[(size_t)(cg & 127)*128 + (cg >> 7)*64 + k0 + lk];
            }
            __syncthreads();
#pragma unroll
            for (int kq = 0; kq < 16; kq++) {
                float4 a  = *(const float4*)&As[kq*68 + 4*ty];
                float4 b4 = *(const float4*)&Ws[kq*68 + 4*tx];
                float av[4] = {a.x, a.y, a.z, a.w};
                float bv[4] = {b4.x, b4.y, b4.z, b4.w};
#pragma unroll
                for (int i = 0; i < 4; i++)
#pragma unroll
                    for (int j = 0; j < 4; j++) acc[i][j] = fmaf(av[i], bv[j], acc[i][j]);
            }
            __syncthreads();
        }
#pragma unroll
        for (int i = 0; i < 4; i++)
#pragma unroll
            for (int j = 0; j < 4; j++)
                X[(size_t)(r0 + 4*ty + i)*256 + n0 + 4*tx + j] = acc[i][j];
        return;
    }
    // ======== KNN path ========
    int kb = blk - 512;
    int b = kb >> 9;
    int g = kb & 511;
    for (int m = t; m < NPTS; m += 256) {
        float x = xyz[(size_t)b*NPTS*3 + m*3];
        float y = xyz[(size_t)b*NPTS*3 + m*3 + 1];
        float z = xyz[(size_t)b*NPTS*3 + m*3 + 2];
        SXQ[m] = make_float4(x, y, z, (x*x + y*y) + z*z);
    }
    __syncthreads();
    int w = t >> 6, lane = t & 63;
    int n = g*4 + w;
    float4 q4 = SXQ[n];
    float qx = q4.x, qy = q4.y, qz = q4.z, sqn = q4.w;

    // keys kept for exact fallback; two independent top-6 streams (halves dep chain)
    unsigned key[32];
    unsigned a1 = 0xFFFFFFFFu, a2 = 0xFFFFFFFFu, a3 = 0xFFFFFFFFu,
             a4 = 0xFFFFFFFFu, a5 = 0xFFFFFFFFu, a6 = 0xFFFFFFFFu;
    unsigned c1 = 0xFFFFFFFFu, c2 = 0xFFFFFFFFu, c3 = 0xFFFFFFFFu,
             c4 = 0xFFFFFFFFu, c5 = 0xFFFFFFFFu, c6 = 0xFFFFFFFFu;
#pragma unroll
    for (int i = 0; i < 16; i++) {
        int m = lane + (i << 6);
        float4 p = SXQ[m];
        float dt = (qx*p.x + qy*p.y) + qz*p.z;
        float d2 = fmaxf((sqn + p.w) - 2.0f*dt, 0.f);
        unsigned kv = (__float_as_uint(d2) & 0xFFFFF800u) | (unsigned)m;
        key[i] = kv;
        ins6(a1, a2, a3, a4, a5, a6, kv);
    }
#pragma unroll
    for (int i = 16; i < 32; i++) {
        int m = lane + (i << 6);
        float4 p = SXQ[m];
        float dt = (qx*p.x + qy*p.y) + qz*p.z;
        float d2 = fmaxf((sqn + p.w) - 2.0f*dt, 0.f);
        unsigned kv = (__float_as_uint(d2) & 0xFFFFF800u) | (unsigned)m;
        key[i] = kv;
        ins6(c1, c2, c3, c4, c5, c6, kv);
    }
    // merge stream C into A -> per-lane sorted top-6
    ins6(a1, a2, a3, a4, a5, a6, c1);
    ins6(a1, a2, a3, a4, a5, a6, c2);
    ins6(a1, a2, a3, a4, a5, a6, c3);
    ins6(a1, a2, a3, a4, a5, a6, c4);
    ins6(a1, a2, a3, a4, a5, a6, c5);
    ins6(a1, a2, a3, a4, a5, a6, c6);

    unsigned winkey = 0xFFFFFFFFu;
    {
        // 32-round multiway merge-pop over per-lane sorted fronts.
        // Exact while no lane pops all 6 (checked below; keys unique via index bits).
        unsigned fr = a1, p2 = a2, p3 = a3, p4 = a4, p5 = a5, p6 = a6;
#pragma unroll
        for (int kk = 0; kk < 32; kk++) {
            unsigned win = wave_min_u32(fr);
            if (lane == kk) winkey = win;
            bool own = (fr == win);
            fr = own ? p2 : fr;
            p2 = own ? p3 : p2;
            p3 = own ? p4 : p3;
            p4 = own ? p5 : p4;
            p5 = own ? p6 : p5;
            p6 = own ? 0xFFFFFFFFu : p6;
        }
        if (__ballot(fr == 0xFFFFFFFFu) != 0ULL) {
            // rare fallback (some lane contributed >=6 of top-32): exact serial
            // extraction over the untouched key[] array — original algorithm.
            winkey = 0xFFFFFFFFu;
            for (int kk = 0; kk < 32; kk++) {
                unsigned lv = key[0];
#pragma unroll
                for (int i = 1; i < 32; i++) lv = (key[i] < lv) ? key[i] : lv;
                unsigned win = wave_min_u32(lv);
                if (lane == kk) winkey = win;
                unsigned widx = win & 2047u;
                int slot = (int)(widx >> 6);
                bool own = (lane == (int)(widx & 63u));
#pragma unroll
                for (int i = 0; i < 32; i++)
                    if (i == slot && own) key[i] = 0xFFFFFFFFu;
            }
        }
    }
    double d2r;
    int mr;
    {
        double qx64 = (double)qx, qy64 = (double)qy, qz64 = (double)qz;
        double sqn64 = qx64*qx64 + qy64*qy64 + qz64*qz64;
        if (lane < 32) {
            mr = (int)(winkey & 2047u);
            float4 p = SXQ[mr];
            double x = (double)p.x, y = (double)p.y, z = (double)p.z;
            double sqm = x*x + y*y + z*z;
            double dt  = qx64*x + qy64*y + qz64*z;
            d2r = (sqn64 + sqm) - 2.0*dt;
        } else {
            d2r = INFINITY; mr = 0x7FFFFFFF;
        }
    }
#pragma unroll
    for (int k = 2; k <= 32; k <<= 1) {
#pragma unroll
        for (int j = k >> 1; j > 0; j >>= 1) {
            double od = __shfl_xor(d2r, j, 64);
            int    om = __shfl_xor(mr, j, 64);
            bool up    = ((lane & k) == 0);
            bool lower = ((lane & j) == 0);
            bool oless = (od < d2r) || (od == d2r && om < mr);
            bool keepOther = up ? (lower ? oless : !oless) : (lower ? !oless : oless);
            if (keepOther) { d2r = od; mr = om; }
        }
    }
    if (lane < KNBR)
        idx[((size_t)b*NPTS + n)*KNBR + lane] = mr;
}

// ---------------------------------------------------------------- stats + sign-selected extreme over K
__global__ __launch_bounds__(256) void stats_gf(const float* __restrict__ geoBC, const float* __restrict__ featAC,
                                                const int* __restrict__ idx, const float* __restrict__ g_geo,
                                                const float* __restrict__ g_feat,
                                                float* __restrict__ sums, float* __restrict__ xsel) {
    int c = threadIdx.x;
    int cc = c & 127;
    const float* base = (c < 128) ? geoBC : featAC;
    bool wantmax = ((c < 128) ? g_geo[cc] : g_feat[cc]) >= 0.f;
    float s = 0.f, ss = 0.f;
    int r0 = blockIdx.x * 32;
    for (int r = r0; r < r0 + 32; r++) {
        int b = r >> 11;
        float ctr = base[(size_t)r*256 + 128 + cc];
        float mx = -1e30f, mn = 1e30f;
        const int* ip = idx + (size_t)r*KNBR;
        for (int kk = 0; kk < KNBR; kk++) {
            int j = ip[kk];
            float xv = ctr + base[((size_t)(b*NPTS + j))*256 + cc];
            mx = fmaxf(mx, xv); mn = fminf(mn, xv);
            s += xv; ss += xv*xv;
        }
        xsel[(size_t)r*256 + c] = wantmax ? mx : mn;
    }
    atomicAdd(&sums[c], s);
    atomicAdd(&sums[256 + c], ss);
}

// ---------------------------------------------------------------- feature_ = relu(affine(xsel)) with inline BN finalize; + bn1 stats
__global__ __launch_bounds__(256) void feature_maxsel(const float* __restrict__ xsel, const float* __restrict__ sums,
                                                      const float* __restrict__ g_geo, const float* __restrict__ b_geo,
                                                      const float* __restrict__ g_feat, const float* __restrict__ b_feat,
                                                      float* __restrict__ feat, float* __restrict__ sums_bn1) {
    int c = threadIdx.x;
    const float inv = 1.0f / (float)(ROWS*KNBR);
    float mean = sums[c]*inv;
    float var  = sums[256+c]*inv - mean*mean;
    float g  = (c < 128) ? g_geo[c] : g_feat[c-128];
    float bb = (c < 128) ? b_geo[c] : b_feat[c-128];
    float sc = g / sqrtf(var + 1e-5f);
    float tt = bb - mean*sc;
    float s = 0.f, ss = 0.f;
    int r0 = blockIdx.x*32;
    for (int r = r0; r < r0+32; r++) {
        size_t i = (size_t)r*256 + c;
        float y = fmaxf(fmaf(sc, xsel[i], tt), 0.f);
        feat[i] = y; s += y; ss += y*y;
    }
    atomicAdd(&sums_bn1[c], s); atomicAdd(&sums_bn1[256+c], ss);
}

// ---------------------------------------------------------------- q/k/v GEMM via bf16 MFMA; inline bn1 finalize on A
__global__ __launch_bounds__(256) void gemm_qkv(const float* __restrict__ Af, const float* __restrict__ sums_in,
                                                const float* __restrict__ g_bn, const float* __restrict__ b_bn,
                                                const ushort* __restrict__ Wb,
                                                float* __restrict__ QKVF, float* __restrict__ sums) {
    __shared__ float bns[2][256];
    __shared__ float red[4][256][2];
    int t = threadIdx.x;
    int r0 = blockIdx.x * 64, g = blockIdx.y;
    int w = t >> 6, lane = t & 63;
    int r15 = lane & 15, quad = lane >> 4;
    {
        float mean = sums_in[512 + t] * (1.0f/(float)ROWS);
        float var  = sums_in[768 + t] * (1.0f/(float)ROWS) - mean*mean;
        float sc = g_bn[t] / sqrtf(var + 1e-5f);
        bns[0][t] = sc;
        bns[1][t] = b_bn[t] - mean*sc;
    }
    __syncthreads();
    short8 aq[8];
    {
        const float* ap = Af + (size_t)(r0 + 16*w + r15)*256;
#pragma unroll
        for (int kc = 0; kc < 8; kc++) {
            int k0 = 32*kc + 8*quad;
            float4 a0 = *(const float4*)&ap[k0];
            float4 a1 = *(const float4*)&ap[k0+4];
            float4 s0 = *(const float4*)&bns[0][k0];
            float4 s1 = *(const float4*)&bns[0][k0+4];
            float4 h0 = *(const float4*)&bns[1][k0];
            float4 h1 = *(const float4*)&bns[1][k0+4];
            ushort u8[8];
            u8[0] = f2bf(fmaf(s0.x, a0.x, h0.x)); u8[1] = f2bf(fmaf(s0.y, a0.y, h0.y));
            u8[2] = f2bf(fmaf(s0.z, a0.z, h0.z)); u8[3] = f2bf(fmaf(s0.w, a0.w, h0.w));
            u8[4] = f2bf(fmaf(s1.x, a1.x, h1.x)); u8[5] = f2bf(fmaf(s1.y, a1.y, h1.y));
            u8[6] = f2bf(fmaf(s1.z, a1.z, h1.z)); u8[7] = f2bf(fmaf(s1.w, a1.w, h1.w));
            aq[kc] = *(short8*)u8;
        }
    }
    floatx4 zero4 = {0.f, 0.f, 0.f, 0.f};
    floatx4 acc[16];
#pragma unroll
    for (int st = 0; st < 16; st++) acc[st] = zero4;
    const ushort* wbase = Wb + (size_t)g*65536 + (size_t)r15*256 + 8*quad;
#pragma unroll
    for (int st = 0; st < 16; st++) {
        const ushort* wp = wbase + (size_t)(16*st)*256;
#pragma unroll
        for (int kc = 0; kc < 8; kc++) {
            short8 bf = *(const short8*)(wp + 32*kc);
            acc[st] = __builtin_amdgcn_mfma_f32_16x16x32_bf16(aq[kc], bf, acc[st], 0, 0, 0);
        }
    }
#pragma unroll
    for (int st = 0; st < 16; st++) {
        float s  = (acc[st][0] + acc[st][1]) + (acc[st][2] + acc[st][3]);
        float q2 = (acc[st][0]*acc[st][0] + acc[st][1]*acc[st][1]) +
                   (acc[st][2]*acc[st][2] + acc[st][3]*acc[st][3]);
        s  += __shfl_xor(s, 16, 64);  s  += __shfl_xor(s, 32, 64);
        q2 += __shfl_xor(q2, 16, 64); q2 += __shfl_xor(q2, 32, 64);
        if (lane < 16) { red[w][16*st + r15][0] = s; red[w][16*st + r15][1] = q2; }
#pragma unroll
        for (int reg = 0; reg < 4; reg++)
            QKVF[(size_t)(r0 + 16*w + 4*quad + reg)*768 + g*256 + 16*st + r15] = acc[st][reg];
    }
    __syncthreads();
    {
        float s = red[0][t][0] + red[1][t][0] + red[2][t][0] + red[3][t][0];
        float q = red[0][t][1] + red[1][t][1] + red[2][t][1] + red[3][t][1];
        atomicAdd(&sums[1024 + g*512 + t], s);
        atomicAdd(&sums[1024 + g*512 + 256 + t], q);
    }
}

// ---------------------------------------------------------------- affine+relu+bf16 (inline qkv BN finalize): q/k row-major (q scaled by log2e), v transposed
__global__ __launch_bounds__(256) void affine_qkv(const float* __restrict__ QKVF, const float* __restrict__ sums,
                                                  const float* __restrict__ g_q, const float* __restrict__ b_q,
                                                  const float* __restrict__ g_k, const float* __restrict__ b_k,
                                                  const float* __restrict__ g_v, const float* __restrict__ b_v,
                                                  ushort* __restrict__ qk, ushort* __restrict__ vt) {
    __shared__ float sts[6][256];
    __shared__ ushort tile[64][72];
    int t = threadIdx.x;
    {
        const float* gs[3] = {g_q, g_k, g_v};
        const float* bs[3] = {b_q, b_k, b_v};
#pragma unroll
        for (int g = 0; g < 3; g++) {
            float mean = sums[1024 + g*512 + t] * (1.0f/(float)ROWS);
            float var  = sums[1024 + g*512 + 256 + t] * (1.0f/(float)ROWS) - mean*mean;
            float sc = gs[g][t] / sqrtf(var + 1e-5f);
            float sh = bs[g][t] - mean*sc;
            if (g == 0) { sc *= LOG2E; sh *= LOG2E; }   // exp2-domain softmax
            sts[2*g][t] = sc;
            sts[2*g+1][t] = sh;
        }
    }
    __syncthreads();
    int r0 = blockIdx.x * 64, c0 = blockIdx.y * 64;
    int b = r0 >> 11, nbase = r0 & 2047;
    if (c0 < 512) {
#pragma unroll
        for (int rep = 0; rep < 16; rep++) {
            int e = t + 256*rep;
            int row = e >> 6, c = e & 63;
            int col = c0 + c, g = col >> 8, cc = col & 255;
            float v = QKVF[(size_t)(r0 + row)*768 + col];
            v = fmaxf(fmaf(sts[2*g][cc], v, sts[2*g+1][cc]), 0.f);
            qk[(size_t)(r0 + row)*512 + col] = f2bf(v);
        }
    } else {
#pragma unroll
        for (int rep = 0; rep < 16; rep++) {
            int e = t + 256*rep;
            int row = e >> 6, c = e & 63;
            int col = c0 + c, cc = col & 255;
            float v = QKVF[(size_t)(r0 + row)*768 + col];
            v = fmaxf(fmaf(sts[4][cc], v, sts[5][cc]), 0.f);
            tile[c][row] = f2bf(v);
        }
        __syncthreads();
#pragma unroll
        for (int rep = 0; rep < 16; rep++) {
            int e = t + 256*rep;
            int cc = e >> 6, nn = e & 63;
            vt[((size_t)(b*256 + (c0 - 512) + cc))*2048 + nbase + nn] = tile[cc][nn];
        }
    }
}

// ---------------------------------------------------------------- MFMA bf16 flash attention v7: P fully in registers via
// sigma-permuted V storage. QK^T natural (key = 16tt + r15, R3-proven K access).
// V stored at slot sigma(key): slot bits [b5..b0] = [key5,key3,key2,key4,key1,key0]
// so lane (r15,q)'s natural S values (keys 16tt+4q+reg) pack DIRECTLY into PV's
// B-fragment (slot 32(tt>>1)+8q+4(tt&1)+reg). Psh deleted: no LDS P, no shuffles.
// V staging writes each uint4 as 2 sigma-mapped b64. K+V LDS double-buffered
// (KLD=72 = 144B, 16B-aligned), raw-barrier pipeline. 8 waves x QBLK=16, 448 blocks.
__global__ __launch_bounds__(512) void attn2(const ushort* __restrict__ qk, const ushort* __restrict__ vt,
                                             float* __restrict__ obuf) {
    __shared__ ushort Ksh[2][64*KLD];
    __shared__ ushort Vts[2][64*KLD];
    int h = blockIdx.y, b = blockIdx.z;
    int r0 = blockIdx.x * 128;
    int t = threadIdx.x;
    int w = t >> 6, lane = t & 63;
    int r15 = lane & 15, quad = lane >> 4;
    size_t rowbase = (size_t)b*NPTS;
    int hoff = h*DSH;
    int rr = t >> 3, c8 = t & 7;

    const ushort* ksrc = qk + (rowbase + rr)*512 + 256 + hoff + 8*c8;     // + m0*512
    const ushort* vsrc = vt + ((size_t)(b*256 + hoff + rr))*2048 + 8*c8;  // + m0
    int ldstK = rr*KLD + 8*c8;
    // sigma-mapped V staging base: local keys 8*c8+jj -> slots vb+jj (jj<4), vb+8+(jj-4)
    int vb = 4*((c8 >> 1) & 1) + 16*(c8 & 1) + 32*(c8 >> 2);
    int ldstV = rr*KLD + vb;

    short8 aq[2];
#pragma unroll
    for (int s = 0; s < 2; s++)
        aq[s] = *(const short8*)(qk + (rowbase + r0 + 16*w + r15)*512 + hoff + 32*s + 8*quad);

    // stage tile 0 into buffer 0
    {
        uint4 k0 = *(const uint4*)(ksrc);
        uint4 v0 = *(const uint4*)(vsrc);
        *(uint4*)&Ksh[0][ldstK] = k0;
        *(uint2*)&Vts[0][ldstV]     = make_uint2(v0.x, v0.y);
        *(uint2*)&Vts[0][ldstV + 8] = make_uint2(v0.z, v0.w);
    }

    floatx4 zero4 = {0.f, 0.f, 0.f, 0.f};
    floatx4 oacc[4];
    float mrun = -1e30f, lrun = 0.f;
#pragma unroll
    for (int i = 0; i < 4; i++) oacc[i] = zero4;

    asm volatile("s_waitcnt lgkmcnt(0)" ::: "memory");
    __builtin_amdgcn_s_barrier();
    __builtin_amdgcn_sched_barrier(0);

    int cur = 0;
    for (int m0 = 0; m0 < NPTS; m0 += 64) {
        // prefetch next KV tile into registers (latency hides under compute)
        int mnext = (m0 + 64 < NPTS) ? (m0 + 64) : 0;
        uint4 kreg = *(const uint4*)(ksrc + (size_t)mnext*512);
        uint4 vreg = *(const uint4*)(vsrc + mnext);

        const ushort* Kc = Ksh[cur];
        const ushort* Vc = Vts[cur];

        // S = K * Q^T, natural keys: sacc[tt] covers keys 16tt+4quad+reg, col = qrow = r15
        floatx4 sacc[4];
#pragma unroll
        for (int tt = 0; tt < 4; tt++) sacc[tt] = zero4;
        __builtin_amdgcn_s_setprio(1);
#pragma unroll
        for (int tt = 0; tt < 4; tt++) {
            int key = 16*tt + r15;
#pragma unroll
            for (int s = 0; s < 2; s++) {
                short8 kf = *(const short8*)&Kc[key*KLD + 32*s + 8*quad];
                sacc[tt] = __builtin_amdgcn_mfma_f32_16x16x32_bf16(kf, aq[s], sacc[tt], 0, 0, 0);
            }
        }
        __builtin_amdgcn_s_setprio(0);

        // lane-local row max over this lane's 16 keys, then cross-quad (same r15)
        float mx = sacc[0][0];
#pragma unroll
        for (int tt = 0; tt < 4; tt++)
#pragma unroll
            for (int reg = 0; reg < 4; reg++) mx = fmaxf(mx, sacc[tt][reg]);
        mx = fmaxf(mx, __shfl_xor(mx, 16, 64));
        mx = fmaxf(mx, __shfl_xor(mx, 32, 64));

        // defer-rescale: alpha==1 exactly when no row in the wave got a new max
        if (!__all(mx <= mrun)) {
            float mnew = fmaxf(mrun, mx);
            float alpha = EXP2(mrun - mnew);
            lrun *= alpha;
#pragma unroll
            for (int td = 0; td < 4; td++) oacc[td] *= alpha;
            mrun = mnew;
        }

        // P = exp2(S - m); lane holds P[16tt+4q+reg][r15]
        float pm[4][4];
        float rs = 0.f;
#pragma unroll
        for (int tt = 0; tt < 4; tt++) {
#pragma unroll
            for (int reg = 0; reg < 4; reg++) {
                float p = EXP2(sacc[tt][reg] - mrun);
                pm[tt][reg] = p; rs += p;
            }
        }
        rs += __shfl_xor(rs, 16, 64);
        rs += __shfl_xor(rs, 32, 64);
        lrun += rs;

        // pack P -> PV B-frag in sigma-space: slot 32(tt>>1)+8q+4(tt&1)+reg = sigma(key)
        uint4 pk0, pk1;
        pk0.x = cvt_pk_bf16(pm[0][0], pm[0][1]); pk0.y = cvt_pk_bf16(pm[0][2], pm[0][3]);
        pk0.z = cvt_pk_bf16(pm[1][0], pm[1][1]); pk0.w = cvt_pk_bf16(pm[1][2], pm[1][3]);
        pk1.x = cvt_pk_bf16(pm[2][0], pm[2][1]); pk1.y = cvt_pk_bf16(pm[2][2], pm[2][3]);
        pk1.z = cvt_pk_bf16(pm[3][0], pm[3][1]); pk1.w = cvt_pk_bf16(pm[3][2], pm[3][3]);
        short8 pf0 = *(short8*)&pk0;
        short8 pf1 = *(short8*)&pk1;

        // O^T += V^T * P^T over sigma-permuted slots (order-invariant sum)
        __builtin_amdgcn_s_setprio(1);
#pragma unroll
        for (int td = 0; td < 4; td++) {
            short8 vf0 = *(const short8*)&Vc[(16*td + r15)*KLD + 8*quad];
            oacc[td] = __builtin_amdgcn_mfma_f32_16x16x32_bf16(vf0, pf0, oacc[td], 0, 0, 0);
            short8 vf1 = *(const short8*)&Vc[(16*td + r15)*KLD + 32 + 8*quad];
            oacc[td] = __builtin_amdgcn_mfma_f32_16x16x32_bf16(vf1, pf1, oacc[td], 0, 0, 0);
        }
        __builtin_amdgcn_s_setprio(0);

        // write prefetched tile into the other buffer (vmcnt wait is ~free by now)
        *(uint4*)&Ksh[cur ^ 1][ldstK] = kreg;
        *(uint2*)&Vts[cur ^ 1][ldstV]     = make_uint2(vreg.x, vreg.y);
        *(uint2*)&Vts[cur ^ 1][ldstV + 8] = make_uint2(vreg.z, vreg.w);
        cur ^= 1;

        // drain own LDS ops, raw barrier (no vmcnt drain), fence scheduler
        asm volatile("s_waitcnt lgkmcnt(0)" ::: "memory");
        __builtin_amdgcn_s_barrier();
        __builtin_amdgcn_sched_barrier(0);
    }

    // lane holds O^T[vchan=16td+4quad+reg][qrow=r15]; coalesced float4 stores
    float invl = RCP(lrun);
#pragma unroll
    for (int td = 0; td < 4; td++) {
        floatx4 o = oacc[td] * invl;
        *(float4*)&obuf[(rowbase + r0 + 16*w + r15)*(size_t)(NHEADS*WCH) + h*WCH + 16*td + 4*quad] =
            *(float4*)&o;
    }
}

// ---------------------------------------------------------------- fus GEMM (bf16 MFMA); A = normalized attention output; bias; stats
__global__ __launch_bounds__(256) void gemm_fus(const float* __restrict__ OBUF, const ushort* __restrict__ Wb,
                                                const float* __restrict__ bias, float* __restrict__ C,
                                                float* __restrict__ sums) {
    __shared__ float red[4][128][2];
    int t = threadIdx.x;
    int r0 = blockIdx.x * 64, n0 = blockIdx.y * 128;
    int w = t >> 6, lane = t & 63;
    int r15 = lane & 15, quad = lane >> 4;
    int arow = 16*w + r15;
    short8 aq[14];
    {
        const float* p0 = OBUF + (size_t)(r0 + arow)*448;
#pragma unroll
        for (int kc = 0; kc < 14; kc++) {
            int k0 = 32*kc + 8*quad;
            float4 x0 = *(const float4*)&p0[k0];
            float4 y0 = *(const float4*)&p0[k0+4];
            ushort u8[8];
            u8[0] = f2bf(x0.x); u8[1] = f2bf(x0.y);
            u8[2] = f2bf(x0.z); u8[3] = f2bf(x0.w);
            u8[4] = f2bf(y0.x); u8[5] = f2bf(y0.y);
            u8[6] = f2bf(y0.z); u8[7] = f2bf(y0.w);
            aq[kc] = *(short8*)u8;
        }
    }
    floatx4 zero4 = {0.f, 0.f, 0.f, 0.f};
    floatx4 acc[8];
#pragma unroll
    for (int st = 0; st < 8; st++) acc[st] = zero4;
    const ushort* wbase = Wb + 196608 + (size_t)(n0 + r15)*448 + 8*quad;
#pragma unroll
    for (int st = 0; st < 8; st++) {
        const ushort* wp = wbase + (size_t)(16*st)*448;
#pragma unroll
        for (int kc = 0; kc < 14; kc++) {
            short8 bf = *(const short8*)(wp + 32*kc);
            acc[st] = __builtin_amdgcn_mfma_f32_16x16x32_bf16(aq[kc], bf, acc[st], 0, 0, 0);
        }
    }
#pragma unroll
    for (int st = 0; st < 8; st++) {
        int col = n0 + 16*st + r15;
        float bi = bias[col];
        float v0 = acc[st][0] + bi, v1 = acc[st][1] + bi, v2 = acc[st][2] + bi, v3 = acc[st][3] + bi;
        float s  = (v0 + v1) + (v2 + v3);
        float q2 = (v0*v0 + v1*v1) + (v2*v2 + v3*v3);
        s  += __shfl_xor(s, 16, 64);  s  += __shfl_xor(s, 32, 64);
        q2 += __shfl_xor(q2, 16, 64); q2 += __shfl_xor(q2, 32, 64);
        if (lane < 16) { red[w][16*st + r15][0] = s; red[w][16*st + r15][1] = q2; }
        C[(size_t)(r0 + 16*w + 4*quad + 0)*256 + col] = v0;
        C[(size_t)(r0 + 16*w + 4*quad + 1)*256 + col] = v1;
        C[(size_t)(r0 + 16*w + 4*quad + 2)*256 + col] = v2;
        C[(size_t)(r0 + 16*w + 4*quad + 3)*256 + col] = v3;
    }
    __syncthreads();
    {
        int col = t >> 1, which = t & 1;
        float v = red[0][col][which] + red[1][col][which] + red[2][col][which] + red[3][col][which];
        atomicAdd(&sums[2560 + which*256 + n0 + col], v);
    }
}

// ---------------------------------------------------------------- fused: fus-BN+relu+residual+LN (per-row) + MLP GEMM + residual + transposed out
__global__ __launch_bounds__(256) void gemm_mlp_ln(const float* __restrict__ FUSP, const float* __restrict__ A,
                                                   const float* __restrict__ sums,
                                                   const float* __restrict__ g_fus, const float* __restrict__ b_fus,
                                                   const float* __restrict__ g_ln, const float* __restrict__ b_ln,
                                                   const float* __restrict__ W, const float* __restrict__ bias,
                                                   float* __restrict__ outp) {
    __shared__ float Ys[256][68];    // y (LN out), k-major: Ys[c][row]
    __shared__ float FFs[64][65];    // feature__ tile (cols n0..n0+63)
    __shared__ float Ws[16][68];
    __shared__ float tr[64][65];
    __shared__ float SC[256], SH[256], GL[256], BL[256];
    int t = threadIdx.x;
    int r0 = blockIdx.x*64, n0 = blockIdx.y*64;
    {
        float mean0 = sums[2560 + t] * (1.0f/(float)ROWS);
        float var0  = sums[2560 + 256 + t] * (1.0f/(float)ROWS) - mean0*mean0;
        float sc = g_fus[t] / sqrtf(var0 + 1e-5f);
        SC[t] = sc; SH[t] = b_fus[t] - mean0*sc;
        GL[t] = g_ln[t]; BL[t] = b_ln[t];
    }
    __syncthreads();
    int row = t >> 2, seg = t & 3;
    size_t rb = (size_t)(r0 + row)*256;
    float4 vv[16];
    float s = 0.f, ss = 0.f;
#pragma unroll
    for (int j = 0; j < 16; j++) {
        int c = seg*64 + 4*j;
        float4 fp = *(const float4*)&FUSP[rb + c];
        float4 fe = *(const float4*)&A[rb + c];
        float4 sc4 = *(const float4*)&SC[c];
        float4 sh4 = *(const float4*)&SH[c];
        float4 v;
        v.x = fmaxf(fmaf(sc4.x, fp.x, sh4.x), 0.f) + fe.x;
        v.y = fmaxf(fmaf(sc4.y, fp.y, sh4.y), 0.f) + fe.y;
        v.z = fmaxf(fmaf(sc4.z, fp.z, sh4.z), 0.f) + fe.z;
        v.w = fmaxf(fmaf(sc4.w, fp.w, sh4.w), 0.f) + fe.w;
        vv[j] = v;
        s  += (v.x + v.y) + (v.z + v.w);
        ss += (v.x*v.x + v.y*v.y) + (v.z*v.z + v.w*v.w);
        if (seg == blockIdx.y) *(float4*)&FFs[row][4*j] = v;
    }
    s  += __shfl_xor(s, 1, 64);  s  += __shfl_xor(s, 2, 64);
    ss += __shfl_xor(ss, 1, 64); ss += __shfl_xor(ss, 2, 64);
    float mean = s * (1.f/256.f);
    float var  = ss * (1.f/256.f) - mean*mean;
    float rin  = 1.f/sqrtf(var + 1e-5f);
#pragma unroll
    for (int j = 0; j < 16; j++) {
        int c = seg*64 + 4*j;
        float4 gl = *(const float4*)&GL[c];
        float4 bl = *(const float4*)&BL[c];
        float4 v = vv[j];
        Ys[c+0][row] = (v.x - mean)*rin*gl.x + bl.x;
        Ys[c+1][row] = (v.y - mean)*rin*gl.y + bl.y;
        Ys[c+2][row] = (v.z - mean)*rin*gl.z + bl.z;
        Ys[c+3][row] = (v.w - mean)*rin*gl.w + bl.w;
    }
    __syncthreads();
    // GEMM: y[64rows x 256] * W_mlp[n0..n0+63][256]^T
    int tx = t & 15, ty = t >> 4;
    int lk = t & 15, lm = t >> 4;
    float acc[4][4];
#pragma unroll
    for (int i = 0; i < 4; i++)
#pragma unroll
        for (int j = 0; j < 4; j++) acc[i][j] = 0.f;
    for (int k0 = 0; k0 < 256; k0 += 16) {
#pragma unroll
        for (int i2 = 0; i2 < 4; i2++)
            Ws[lk][lm + 16*i2] = W[(size_t)(n0 + lm + 16*i2)*256 + k0 + lk];
        __syncthreads();
#pragma unroll
        for (int kq = 0; kq < 16; kq++) {
            float4 a  = *(const float4*)&Ys[k0 + kq][4*ty];
            float4 b4 = *(const float4*)&Ws[kq][4*tx];
            float av[4] = {a.x, a.y, a.z, a.w};
            float bv[4] = {b4.x, b4.y, b4.z, b4.w};
#pragma unroll
            for (int i = 0; i < 4; i++)
#pragma unroll
                for (int j = 0; j < 4; j++) acc[i][j] = fmaf(av[i], bv[j], acc[i][j]);
        }
        __syncthreads();
    }
#pragma unroll
    for (int i = 0; i < 4; i++)
#pragma unroll
        for (int j = 0; j < 4; j++) {
            float v = acc[i][j] + bias[n0 + 4*tx + j] + FFs[4*ty + i][4*tx + j];
            tr[4*tx + j][4*ty + i] = v;
        }
    __syncthreads();
    int b = r0 >> 11, nbase = r0 & 2047;
#pragma unroll
    for (int rep = 0; rep < 16; rep++) {
        int e = t + 256*rep;
        int cl = e >> 6, nl = e & 63;
        outp[((size_t)(b*256 + n0 + cl))*2048 + nbase + nl] = tr[cl][nl];
    }
}

// ================================================================ host
extern "C" void kernel_launch(void* const* d_in, const int* in_sizes, int n_in,
                              void* d_out, int out_size, void* d_ws, size_t ws_size,
                              hipStream_t stream) {
    const float* xyz    = (const float*)d_in[0];
    const float* f      = (const float*)d_in[1];
    const float* W_geo  = (const float*)d_in[2];
    const float* g_geo  = (const float*)d_in[3];
    const float* b_geo  = (const float*)d_in[4];
    const float* W_feat = (const float*)d_in[5];
    const float* g_feat = (const float*)d_in[6];
    const float* b_feat = (const float*)d_in[7];
    const float* g_bn   = (const float*)d_in[8];
    const float* b_bn   = (const float*)d_in[9];
    const float* W_q    = (const float*)d_in[10];
    const float* g_q    = (const float*)d_in[11];
    const float* b_q    = (const float*)d_in[12];
    const float* W_k    = (const float*)d_in[13];
    const float* g_k    = (const float*)d_in[14];
    const float* b_k    = (const float*)d_in[15];
    const float* W_v    = (const float*)d_in[16];
    const float* g_v    = (const float*)d_in[17];
    const float* b_v    = (const float*)d_in[18];
    const float* W_fus  = (const float*)d_in[19];
    const float* bias_fus = (const float*)d_in[20];
    const float* g_fus  = (const float*)d_in[21];
    const float* b_fus  = (const float*)d_in[22];
    const float* g_ln   = (const float*)d_in[23];
    const float* b_ln   = (const float*)d_in[24];
    const float* W_mlp  = (const float*)d_in[25];
    const float* bias_mlp = (const float*)d_in[26];

    float* ws = (float*)d_ws;
    const size_t MBF = 262144;  // floats per MiB
    float* SUMS  = ws;
    int*   IDX   = (int*)(ws + 16384);
    float* A     = ws + 1*MBF;
    float* X     = ws + 9*MBF;
    ushort* QK16 = (ushort*)(ws + 9*MBF);
    float* FUSP  = ws + 9*MBF;
    float* CSEL  = ws + 17*MBF;
    float* QKVF  = ws + 17*MBF;
    float* OBUF  = ws + 17*MBF;
    ushort* VT16 = (ushort*)(ws + 45*MBF);
    ushort* WB16 = (ushort*)(ws + 49*MBF);

    prep_knn<<<2560, 256, 0, stream>>>(f, W_feat, xyz, W_geo, W_q, W_k, W_v, W_fus,
                                       X, A, WB16, SUMS, IDX);
    stats_gf<<<256, 256, 0, stream>>>(A, X, IDX, g_geo, g_feat, SUMS, CSEL);
    feature_maxsel<<<256, 256, 0, stream>>>(CSEL, SUMS, g_geo, b_geo, g_feat, b_feat, A, SUMS + 512);
    gemm_qkv<<<dim3(128, 3), 256, 0, stream>>>(A, SUMS, g_bn, b_bn, WB16, QKVF, SUMS);
    affine_qkv<<<dim3(128, 12), 256, 0, stream>>>(QKVF, SUMS, g_q, b_q, g_k, b_k, g_v, b_v, QK16, VT16);
    attn2<<<dim3(NPTS/128, NHEADS, NB), 512, 0, stream>>>(QK16, VT16, OBUF);
    gemm_fus<<<dim3(128, 2), 256, 0, stream>>>(OBUF, WB16, bias_fus, FUSP, SUMS);
    gemm_mlp_ln<<<dim3(128, 4), 256, 0, stream>>>(FUSP, A, SUMS, g_fus, b_fus, g_ln, b_ln,
                                                  W_mlp, bias_mlp, (float*)d_out);
}

// Round 10
// 372.890 us; speedup vs baseline: 1.5002x; 1.0092x over previous
//
#include <hip/hip_runtime.h>
#include <math.h>

#define NB    4
#define NPTS  2048
#define ROWS  (NB*NPTS)   // 8192
#define CIN   64
#define COUT  256
#define KNBR  21
#define NHEADS 7
#define WCH   64
#define DSH   32
#define LOG2E 1.4426950408889634f
#define KLD   72   // LDS row stride in ushorts = 144 B: multiple of 16 B (b128-aligned)

typedef __attribute__((ext_vector_type(8))) short short8;
typedef __attribute__((ext_vector_type(4))) float floatx4;

#if __has_builtin(__builtin_amdgcn_exp2f)
#define EXP2(x) __builtin_amdgcn_exp2f(x)
#else
#define EXP2(x) __expf((x)*0.6931471805599453f)
#endif
#if __has_builtin(__builtin_amdgcn_rcpf)
#define RCP(x) __builtin_amdgcn_rcpf(x)
#else
#define RCP(x) (1.0f/(x))
#endif

__device__ __forceinline__ ushort f2bf(float x) {
    unsigned u = __float_as_uint(x);
    u += 0x7fffu + ((u >> 16) & 1u);   // RNE
    return (ushort)(u >> 16);
}

__device__ __forceinline__ float bf2f(short u) {
    return __uint_as_float(((unsigned)(unsigned short)u) << 16);
}

// packed f32x2 -> bf16x2 (RNE), single VALU inst; no builtin on gfx950
__device__ __forceinline__ unsigned cvt_pk_bf16(float lo, float hi) {
    unsigned r;
    asm("v_cvt_pk_bf16_f32 %0, %1, %2" : "=v"(r) : "v"(lo), "v"(hi));
    return r;
}

// wave64 u32 min-reduce via DPP chain; broadcast via readlane(63)
template<int CTRL, int RMASK>
__device__ __forceinline__ unsigned dpp_umin_step(unsigned x) {
    unsigned t = (unsigned)__builtin_amdgcn_update_dpp((int)x, (int)x, CTRL, RMASK, 0xF, false);
    return (t < x) ? t : x;
}
__device__ __forceinline__ unsigned wave_min_u32(unsigned x) {
    x = dpp_umin_step<0x111, 0xF>(x);
    x = dpp_umin_step<0x112, 0xF>(x);
    x = dpp_umin_step<0x114, 0xF>(x);
    x = dpp_umin_step<0x118, 0xF>(x);
    x = dpp_umin_step<0x142, 0xA>(x);
    x = dpp_umin_step<0x143, 0xC>(x);
    return (unsigned)__builtin_amdgcn_readlane((int)x, 63);
}

__device__ __forceinline__ unsigned umin2(unsigned a, unsigned b) { return a < b ? a : b; }
__device__ __forceinline__ unsigned umax2(unsigned a, unsigned b) { return a < b ? b : a; }

// insert k into sorted ascending 6-list (m1 smallest); 11 min/max ops, static regs
__device__ __forceinline__ void ins6(unsigned &m1, unsigned &m2, unsigned &m3,
                                     unsigned &m4, unsigned &m5, unsigned &m6, unsigned k) {
    unsigned c = k, t;
    t = umin2(m1, c); c = umax2(m1, c); m1 = t;
    t = umin2(m2, c); c = umax2(m2, c); m2 = t;
    t = umin2(m3, c); c = umax2(m3, c); m3 = t;
    t = umin2(m4, c); c = umax2(m4, c); m4 = t;
    t = umin2(m5, c); c = umax2(m5, c); m5 = t;
    m6 = umin2(m6, c);
}

// ---------------------------------------------------------------- fused prep (blocks 0..511) + KNN (blocks 512..2559)
__global__ __launch_bounds__(256) void prep_knn(const float* __restrict__ f, const float* __restrict__ Wf,
                                                const float* __restrict__ xyz, const float* __restrict__ Wg,
                                                const float* __restrict__ W_q, const float* __restrict__ W_k,
                                                const float* __restrict__ W_v, const float* __restrict__ W_fus,
                                                float* __restrict__ X, float* __restrict__ A,
                                                ushort* __restrict__ Wb, float* __restrict__ sums,
                                                int* __restrict__ idx) {
    __shared__ float4 SXQ[2048];
    int t = threadIdx.x;
    int blk = blockIdx.x;
    if (blk < 512) {
        // ======== prep path ========
        float* As = (float*)SXQ;
        float* Ws = As + 16*68;
        int bx = blk & 127, by = blk >> 7;
        if (by == 0 && bx < 12) sums[bx*256 + t] = 0.f;
        int gid = (by*128 + bx)*256 + t;
        for (int i = gid; i < 311296; i += 131072) {
            const float* Wsrc; int off;
            if (i < 65536)       { Wsrc = W_q;   off = i; }
            else if (i < 131072) { Wsrc = W_k;   off = i - 65536; }
            else if (i < 196608) { Wsrc = W_v;   off = i - 131072; }
            else                 { Wsrc = W_fus; off = i - 196608; }
            Wb[i] = f2bf(Wsrc[off]);
        }
        int r0 = bx * 64, n0 = by * 64;
        for (int e = t; e < 4096; e += 256) {
            int row = r0 + (e >> 6), c = n0 + (e & 63), cc = c & 127;
            float x = xyz[row*3], y = xyz[row*3+1], z = xyz[row*3+2];
            const float* w = Wg + cc*6;
            float s = (c < 128) ? ((w[3]*x + w[4]*y) + w[5]*z)
                                : (((w[0]-w[3])*x + (w[1]-w[4])*y) + (w[2]-w[5])*z);
            A[(size_t)row*256 + c] = s;
        }
        int b = r0 >> 11, nbase = r0 & 2047;
        int tx = t & 15, ty = t >> 4;
        float acc[4][4];
#pragma unroll
        for (int i = 0; i < 4; i++)
#pragma unroll
            for (int j = 0; j < 4; j++) acc[i][j] = 0.f;
        int m64 = t & 63, kg = t >> 6;
        int lk = t & 15, lm = t >> 4;
        for (int k0 = 0; k0 < 64; k0 += 16) {
#pragma unroll
            for (int p = 0; p < 4; p++) {
                int k = kg*4 + p;
                As[k*68 + m64] = f[(size_t)b*CIN*NPTS + (size_t)(k0 + k)*NPTS + nbase + m64];
            }
#pragma unroll
            for (int i2 = 0; i2 < 4; i2++) {
                int cg = n0 + lm + 16*i2;
                Ws[lk*68 + lm + 16*i2] = Wf[(size_t)(cg & 127)*128 + (cg >> 7)*64 + k0 + lk];
            }
            __syncthreads();
#pragma unroll
            for (int kq = 0; kq < 16; kq++) {
                float4 a  = *(const float4*)&As[kq*68 + 4*ty];
                float4 b4 = *(const float4*)&Ws[kq*68 + 4*tx];
                float av[4] = {a.x, a.y, a.z, a.w};
                float bv[4] = {b4.x, b4.y, b4.z, b4.w};
#pragma unroll
                for (int i = 0; i < 4; i++)
#pragma unroll
                    for (int j = 0; j < 4; j++) acc[i][j] = fmaf(av[i], bv[j], acc[i][j]);
            }
            __syncthreads();
        }
#pragma unroll
        for (int i = 0; i < 4; i++)
#pragma unroll
            for (int j = 0; j < 4; j++)
                X[(size_t)(r0 + 4*ty + i)*256 + n0 + 4*tx + j] = acc[i][j];
        return;
    }
    // ======== KNN path ========
    int kb = blk - 512;
    int b = kb >> 9;
    int g = kb & 511;
    for (int m = t; m < NPTS; m += 256) {
        float x = xyz[(size_t)b*NPTS*3 + m*3];
        float y = xyz[(size_t)b*NPTS*3 + m*3 + 1];
        float z = xyz[(size_t)b*NPTS*3 + m*3 + 2];
        SXQ[m] = make_float4(x, y, z, (x*x + y*y) + z*z);
    }
    __syncthreads();
    int w = t >> 6, lane = t & 63;
    int n = g*4 + w;
    float4 q4 = SXQ[n];
    float qx = q4.x, qy = q4.y, qz = q4.z, sqn = q4.w;

    // keys kept for exact fallback; two independent top-6 streams (halves dep chain)
    unsigned key[32];
    unsigned a1 = 0xFFFFFFFFu, a2 = 0xFFFFFFFFu, a3 = 0xFFFFFFFFu,
             a4 = 0xFFFFFFFFu, a5 = 0xFFFFFFFFu, a6 = 0xFFFFFFFFu;
    unsigned c1 = 0xFFFFFFFFu, c2 = 0xFFFFFFFFu, c3 = 0xFFFFFFFFu,
             c4 = 0xFFFFFFFFu, c5 = 0xFFFFFFFFu, c6 = 0xFFFFFFFFu;
#pragma unroll
    for (int i = 0; i < 16; i++) {
        int m = lane + (i << 6);
        float4 p = SXQ[m];
        float dt = (qx*p.x + qy*p.y) + qz*p.z;
        float d2 = fmaxf((sqn + p.w) - 2.0f*dt, 0.f);
        unsigned kv = (__float_as_uint(d2) & 0xFFFFF800u) | (unsigned)m;
        key[i] = kv;
        ins6(a1, a2, a3, a4, a5, a6, kv);
    }
#pragma unroll
    for (int i = 16; i < 32; i++) {
        int m = lane + (i << 6);
        float4 p = SXQ[m];
        float dt = (qx*p.x + qy*p.y) + qz*p.z;
        float d2 = fmaxf((sqn + p.w) - 2.0f*dt, 0.f);
        unsigned kv = (__float_as_uint(d2) & 0xFFFFF800u) | (unsigned)m;
        key[i] = kv;
        ins6(c1, c2, c3, c4, c5, c6, kv);
    }
    // merge stream C into A -> per-lane sorted top-6
    ins6(a1, a2, a3, a4, a5, a6, c1);
    ins6(a1, a2, a3, a4, a5, a6, c2);
    ins6(a1, a2, a3, a4, a5, a6, c3);
    ins6(a1, a2, a3, a4, a5, a6, c4);
    ins6(a1, a2, a3, a4, a5, a6, c5);
    ins6(a1, a2, a3, a4, a5, a6, c6);

    unsigned winkey = 0xFFFFFFFFu;
    {
        // 32-round multiway merge-pop over per-lane sorted fronts.
        // Exact while no lane pops all 6 (checked below; keys unique via index bits).
        unsigned fr = a1, p2 = a2, p3 = a3, p4 = a4, p5 = a5, p6 = a6;
#pragma unroll
        for (int kk = 0; kk < 32; kk++) {
            unsigned win = wave_min_u32(fr);
            if (lane == kk) winkey = win;
            bool own = (fr == win);
            fr = own ? p2 : fr;
            p2 = own ? p3 : p2;
            p3 = own ? p4 : p3;
            p4 = own ? p5 : p4;
            p5 = own ? p6 : p5;
            p6 = own ? 0xFFFFFFFFu : p6;
        }
        if (__ballot(fr == 0xFFFFFFFFu) != 0ULL) {
            // rare fallback (some lane contributed >=6 of top-32): exact serial
            // extraction over the untouched key[] array — original algorithm.
            winkey = 0xFFFFFFFFu;
            for (int kk = 0; kk < 32; kk++) {
                unsigned lv = key[0];
#pragma unroll
                for (int i = 1; i < 32; i++) lv = (key[i] < lv) ? key[i] : lv;
                unsigned win = wave_min_u32(lv);
                if (lane == kk) winkey = win;
                unsigned widx = win & 2047u;
                int slot = (int)(widx >> 6);
                bool own = (lane == (int)(widx & 63u));
#pragma unroll
                for (int i = 0; i < 32; i++)
                    if (i == slot && own) key[i] = 0xFFFFFFFFu;
            }
        }
    }
    double d2r;
    int mr;
    {
        double qx64 = (double)qx, qy64 = (double)qy, qz64 = (double)qz;
        double sqn64 = qx64*qx64 + qy64*qy64 + qz64*qz64;
        if (lane < 32) {
            mr = (int)(winkey & 2047u);
            float4 p = SXQ[mr];
            double x = (double)p.x, y = (double)p.y, z = (double)p.z;
            double sqm = x*x + y*y + z*z;
            double dt  = qx64*x + qy64*y + qz64*z;
            d2r = (sqn64 + sqm) - 2.0*dt;
        } else {
            d2r = INFINITY; mr = 0x7FFFFFFF;
        }
    }
#pragma unroll
    for (int k = 2; k <= 32; k <<= 1) {
#pragma unroll
        for (int j = k >> 1; j > 0; j >>= 1) {
            double od = __shfl_xor(d2r, j, 64);
            int    om = __shfl_xor(mr, j, 64);
            bool up    = ((lane & k) == 0);
            bool lower = ((lane & j) == 0);
            bool oless = (od < d2r) || (od == d2r && om < mr);
            bool keepOther = up ? (lower ? oless : !oless) : (lower ? !oless : oless);
            if (keepOther) { d2r = od; mr = om; }
        }
    }
    if (lane < KNBR)
        idx[((size_t)b*NPTS + n)*KNBR + lane] = mr;
}

// ---------------------------------------------------------------- stats + sign-selected extreme over K
__global__ __launch_bounds__(256) void stats_gf(const float* __restrict__ geoBC, const float* __restrict__ featAC,
                                                const int* __restrict__ idx, const float* __restrict__ g_geo,
                                                const float* __restrict__ g_feat,
                                                float* __restrict__ sums, float* __restrict__ xsel) {
    int c = threadIdx.x;
    int cc = c & 127;
    const float* base = (c < 128) ? geoBC : featAC;
    bool wantmax = ((c < 128) ? g_geo[cc] : g_feat[cc]) >= 0.f;
    float s = 0.f, ss = 0.f;
    int r0 = blockIdx.x * 32;
    for (int r = r0; r < r0 + 32; r++) {
        int b = r >> 11;
        float ctr = base[(size_t)r*256 + 128 + cc];
        float mx = -1e30f, mn = 1e30f;
        const int* ip = idx + (size_t)r*KNBR;
        for (int kk = 0; kk < KNBR; kk++) {
            int j = ip[kk];
            float xv = ctr + base[((size_t)(b*NPTS + j))*256 + cc];
            mx = fmaxf(mx, xv); mn = fminf(mn, xv);
            s += xv; ss += xv*xv;
        }
        xsel[(size_t)r*256 + c] = wantmax ? mx : mn;
    }
    atomicAdd(&sums[c], s);
    atomicAdd(&sums[256 + c], ss);
}

// ---------------------------------------------------------------- feature_ = relu(affine(xsel)) with inline BN finalize; + bn1 stats
__global__ __launch_bounds__(256) void feature_maxsel(const float* __restrict__ xsel, const float* __restrict__ sums,
                                                      const float* __restrict__ g_geo, const float* __restrict__ b_geo,
                                                      const float* __restrict__ g_feat, const float* __restrict__ b_feat,
                                                      float* __restrict__ feat, float* __restrict__ sums_bn1) {
    int c = threadIdx.x;
    const float inv = 1.0f / (float)(ROWS*KNBR);
    float mean = sums[c]*inv;
    float var  = sums[256+c]*inv - mean*mean;
    float g  = (c < 128) ? g_geo[c] : g_feat[c-128];
    float bb = (c < 128) ? b_geo[c] : b_feat[c-128];
    float sc = g / sqrtf(var + 1e-5f);
    float tt = bb - mean*sc;
    float s = 0.f, ss = 0.f;
    int r0 = blockIdx.x*32;
    for (int r = r0; r < r0+32; r++) {
        size_t i = (size_t)r*256 + c;
        float y = fmaxf(fmaf(sc, xsel[i], tt), 0.f);
        feat[i] = y; s += y; ss += y*y;
    }
    atomicAdd(&sums_bn1[c], s); atomicAdd(&sums_bn1[256+c], ss);
}

// ---------------------------------------------------------------- q/k/v GEMM via bf16 MFMA; inline bn1 finalize on A
__global__ __launch_bounds__(256) void gemm_qkv(const float* __restrict__ Af, const float* __restrict__ sums_in,
                                                const float* __restrict__ g_bn, const float* __restrict__ b_bn,
                                                const ushort* __restrict__ Wb,
                                                float* __restrict__ QKVF, float* __restrict__ sums) {
    __shared__ float bns[2][256];
    __shared__ float red[4][256][2];
    int t = threadIdx.x;
    int r0 = blockIdx.x * 64, g = blockIdx.y;
    int w = t >> 6, lane = t & 63;
    int r15 = lane & 15, quad = lane >> 4;
    {
        float mean = sums_in[512 + t] * (1.0f/(float)ROWS);
        float var  = sums_in[768 + t] * (1.0f/(float)ROWS) - mean*mean;
        float sc = g_bn[t] / sqrtf(var + 1e-5f);
        bns[0][t] = sc;
        bns[1][t] = b_bn[t] - mean*sc;
    }
    __syncthreads();
    short8 aq[8];
    {
        const float* ap = Af + (size_t)(r0 + 16*w + r15)*256;
#pragma unroll
        for (int kc = 0; kc < 8; kc++) {
            int k0 = 32*kc + 8*quad;
            float4 a0 = *(const float4*)&ap[k0];
            float4 a1 = *(const float4*)&ap[k0+4];
            float4 s0 = *(const float4*)&bns[0][k0];
            float4 s1 = *(const float4*)&bns[0][k0+4];
            float4 h0 = *(const float4*)&bns[1][k0];
            float4 h1 = *(const float4*)&bns[1][k0+4];
            ushort u8[8];
            u8[0] = f2bf(fmaf(s0.x, a0.x, h0.x)); u8[1] = f2bf(fmaf(s0.y, a0.y, h0.y));
            u8[2] = f2bf(fmaf(s0.z, a0.z, h0.z)); u8[3] = f2bf(fmaf(s0.w, a0.w, h0.w));
            u8[4] = f2bf(fmaf(s1.x, a1.x, h1.x)); u8[5] = f2bf(fmaf(s1.y, a1.y, h1.y));
            u8[6] = f2bf(fmaf(s1.z, a1.z, h1.z)); u8[7] = f2bf(fmaf(s1.w, a1.w, h1.w));
            aq[kc] = *(short8*)u8;
        }
    }
    floatx4 zero4 = {0.f, 0.f, 0.f, 0.f};
    floatx4 acc[16];
#pragma unroll
    for (int st = 0; st < 16; st++) acc[st] = zero4;
    const ushort* wbase = Wb + (size_t)g*65536 + (size_t)r15*256 + 8*quad;
#pragma unroll
    for (int st = 0; st < 16; st++) {
        const ushort* wp = wbase + (size_t)(16*st)*256;
#pragma unroll
        for (int kc = 0; kc < 8; kc++) {
            short8 bf = *(const short8*)(wp + 32*kc);
            acc[st] = __builtin_amdgcn_mfma_f32_16x16x32_bf16(aq[kc], bf, acc[st], 0, 0, 0);
        }
    }
#pragma unroll
    for (int st = 0; st < 16; st++) {
        float s  = (acc[st][0] + acc[st][1]) + (acc[st][2] + acc[st][3]);
        float q2 = (acc[st][0]*acc[st][0] + acc[st][1]*acc[st][1]) +
                   (acc[st][2]*acc[st][2] + acc[st][3]*acc[st][3]);
        s  += __shfl_xor(s, 16, 64);  s  += __shfl_xor(s, 32, 64);
        q2 += __shfl_xor(q2, 16, 64); q2 += __shfl_xor(q2, 32, 64);
        if (lane < 16) { red[w][16*st + r15][0] = s; red[w][16*st + r15][1] = q2; }
#pragma unroll
        for (int reg = 0; reg < 4; reg++)
            QKVF[(size_t)(r0 + 16*w + 4*quad + reg)*768 + g*256 + 16*st + r15] = acc[st][reg];
    }
    __syncthreads();
    {
        float s = red[0][t][0] + red[1][t][0] + red[2][t][0] + red[3][t][0];
        float q = red[0][t][1] + red[1][t][1] + red[2][t][1] + red[3][t][1];
        atomicAdd(&sums[1024 + g*512 + t], s);
        atomicAdd(&sums[1024 + g*512 + 256 + t], q);
    }
}

// ---------------------------------------------------------------- affine+relu+bf16 (inline qkv BN finalize): q/k row-major (q scaled by log2e), v transposed
__global__ __launch_bounds__(256) void affine_qkv(const float* __restrict__ QKVF, const float* __restrict__ sums,
                                                  const float* __restrict__ g_q, const float* __restrict__ b_q,
                                                  const float* __restrict__ g_k, const float* __restrict__ b_k,
                                                  const float* __restrict__ g_v, const float* __restrict__ b_v,
                                                  ushort* __restrict__ qk, ushort* __restrict__ vt) {
    __shared__ float sts[6][256];
    __shared__ ushort tile[64][72];
    int t = threadIdx.x;
    {
        const float* gs[3] = {g_q, g_k, g_v};
        const float* bs[3] = {b_q, b_k, b_v};
#pragma unroll
        for (int g = 0; g < 3; g++) {
            float mean = sums[1024 + g*512 + t] * (1.0f/(float)ROWS);
            float var  = sums[1024 + g*512 + 256 + t] * (1.0f/(float)ROWS) - mean*mean;
            float sc = gs[g][t] / sqrtf(var + 1e-5f);
            float sh = bs[g][t] - mean*sc;
            if (g == 0) { sc *= LOG2E; sh *= LOG2E; }   // exp2-domain softmax
            sts[2*g][t] = sc;
            sts[2*g+1][t] = sh;
        }
    }
    __syncthreads();
    int r0 = blockIdx.x * 64, c0 = blockIdx.y * 64;
    int b = r0 >> 11, nbase = r0 & 2047;
    if (c0 < 512) {
#pragma unroll
        for (int rep = 0; rep < 16; rep++) {
            int e = t + 256*rep;
            int row = e >> 6, c = e & 63;
            int col = c0 + c, g = col >> 8, cc = col & 255;
            float v = QKVF[(size_t)(r0 + row)*768 + col];
            v = fmaxf(fmaf(sts[2*g][cc], v, sts[2*g+1][cc]), 0.f);
            qk[(size_t)(r0 + row)*512 + col] = f2bf(v);
        }
    } else {
#pragma unroll
        for (int rep = 0; rep < 16; rep++) {
            int e = t + 256*rep;
            int row = e >> 6, c = e & 63;
            int col = c0 + c, cc = col & 255;
            float v = QKVF[(size_t)(r0 + row)*768 + col];
            v = fmaxf(fmaf(sts[4][cc], v, sts[5][cc]), 0.f);
            tile[c][row] = f2bf(v);
        }
        __syncthreads();
#pragma unroll
        for (int rep = 0; rep < 16; rep++) {
            int e = t + 256*rep;
            int cc = e >> 6, nn = e & 63;
            vt[((size_t)(b*256 + (c0 - 512) + cc))*2048 + nbase + nn] = tile[cc][nn];
        }
    }
}

// ---------------------------------------------------------------- MFMA bf16 flash attention v8: split-K (flash-decoding).
// Each (row-tile, head, batch) handled by 2 blocks, each owning half the keys
// (16 KV tiles). Grid 896 blocks -> ~3.5 blocks/CU resident (~28 waves/CU),
// double the latency hiding vs v7. Blocks emit UNNORMALIZED bf16 partial O
// (P<=1 by max-tracking) + per-(row,head) (m,l); merge folded into gemm_fus.
// v7 core per block: sigma-permuted V, P in registers, K+V LDS double-buffered
// (KLD=72=144B aligned), raw-barrier pipeline, 8 waves x QBLK=16.
__global__ __launch_bounds__(512) void attn2(const ushort* __restrict__ qk, const ushort* __restrict__ vt,
                                             ushort* __restrict__ obp, float* __restrict__ ml) {
    __shared__ ushort Ksh[2][64*KLD];
    __shared__ ushort Vts[2][64*KLD];
    int h = blockIdx.y;
    int z = blockIdx.z, b = z >> 1, half = z & 1;
    int r0 = blockIdx.x * 128;
    int t = threadIdx.x;
    int w = t >> 6, lane = t & 63;
    int r15 = lane & 15, quad = lane >> 4;
    size_t rowbase = (size_t)b*NPTS;
    int hoff = h*DSH;
    int rr = t >> 3, c8 = t & 7;
    int mstart = half << 10, mend = mstart + 1024;

    const ushort* ksrc = qk + (rowbase + rr)*512 + 256 + hoff + 8*c8;     // + m0*512
    const ushort* vsrc = vt + ((size_t)(b*256 + hoff + rr))*2048 + 8*c8;  // + m0
    int ldstK = rr*KLD + 8*c8;
    // sigma-mapped V staging base: local keys 8*c8+jj -> slots vb+jj (jj<4), vb+8+(jj-4)
    int vb = 4*((c8 >> 1) & 1) + 16*(c8 & 1) + 32*(c8 >> 2);
    int ldstV = rr*KLD + vb;

    short8 aq[2];
#pragma unroll
    for (int s = 0; s < 2; s++)
        aq[s] = *(const short8*)(qk + (rowbase + r0 + 16*w + r15)*512 + hoff + 32*s + 8*quad);

    // stage this half's first tile into buffer 0
    {
        uint4 k0 = *(const uint4*)(ksrc + (size_t)mstart*512);
        uint4 v0 = *(const uint4*)(vsrc + mstart);
        *(uint4*)&Ksh[0][ldstK] = k0;
        *(uint2*)&Vts[0][ldstV]     = make_uint2(v0.x, v0.y);
        *(uint2*)&Vts[0][ldstV + 8] = make_uint2(v0.z, v0.w);
    }

    floatx4 zero4 = {0.f, 0.f, 0.f, 0.f};
    floatx4 oacc[4];
    float mrun = -1e30f, lrun = 0.f;
#pragma unroll
    for (int i = 0; i < 4; i++) oacc[i] = zero4;

    asm volatile("s_waitcnt lgkmcnt(0)" ::: "memory");
    __builtin_amdgcn_s_barrier();
    __builtin_amdgcn_sched_barrier(0);

    int cur = 0;
    for (int m0 = mstart; m0 < mend; m0 += 64) {
        // prefetch next KV tile into registers (latency hides under compute)
        int mnext = (m0 + 64 < mend) ? (m0 + 64) : mstart;
        uint4 kreg = *(const uint4*)(ksrc + (size_t)mnext*512);
        uint4 vreg = *(const uint4*)(vsrc + mnext);

        const ushort* Kc = Ksh[cur];
        const ushort* Vc = Vts[cur];

        // S = K * Q^T, natural keys: sacc[tt] covers keys 16tt+4quad+reg, col = qrow = r15
        floatx4 sacc[4];
#pragma unroll
        for (int tt = 0; tt < 4; tt++) sacc[tt] = zero4;
        __builtin_amdgcn_s_setprio(1);
#pragma unroll
        for (int tt = 0; tt < 4; tt++) {
            int key = 16*tt + r15;
#pragma unroll
            for (int s = 0; s < 2; s++) {
                short8 kf = *(const short8*)&Kc[key*KLD + 32*s + 8*quad];
                sacc[tt] = __builtin_amdgcn_mfma_f32_16x16x32_bf16(kf, aq[s], sacc[tt], 0, 0, 0);
            }
        }
        __builtin_amdgcn_s_setprio(0);

        // lane-local row max over this lane's 16 keys, then cross-quad (same r15)
        float mx = sacc[0][0];
#pragma unroll
        for (int tt = 0; tt < 4; tt++)
#pragma unroll
            for (int reg = 0; reg < 4; reg++) mx = fmaxf(mx, sacc[tt][reg]);
        mx = fmaxf(mx, __shfl_xor(mx, 16, 64));
        mx = fmaxf(mx, __shfl_xor(mx, 32, 64));

        // defer-rescale: alpha==1 exactly when no row in the wave got a new max
        if (!__all(mx <= mrun)) {
            float mnew = fmaxf(mrun, mx);
            float alpha = EXP2(mrun - mnew);
            lrun *= alpha;
#pragma unroll
            for (int td = 0; td < 4; td++) oacc[td] *= alpha;
            mrun = mnew;
        }

        // P = exp2(S - m); lane holds P[16tt+4q+reg][r15]
        float pm[4][4];
        float rs = 0.f;
#pragma unroll
        for (int tt = 0; tt < 4; tt++) {
#pragma unroll
            for (int reg = 0; reg < 4; reg++) {
                float p = EXP2(sacc[tt][reg] - mrun);
                pm[tt][reg] = p; rs += p;
            }
        }
        rs += __shfl_xor(rs, 16, 64);
        rs += __shfl_xor(rs, 32, 64);
        lrun += rs;

        // pack P -> PV B-frag in sigma-space: slot 32(tt>>1)+8q+4(tt&1)+reg = sigma(key)
        uint4 pk0, pk1;
        pk0.x = cvt_pk_bf16(pm[0][0], pm[0][1]); pk0.y = cvt_pk_bf16(pm[0][2], pm[0][3]);
        pk0.z = cvt_pk_bf16(pm[1][0], pm[1][1]); pk0.w = cvt_pk_bf16(pm[1][2], pm[1][3]);
        pk1.x = cvt_pk_bf16(pm[2][0], pm[2][1]); pk1.y = cvt_pk_bf16(pm[2][2], pm[2][3]);
        pk1.z = cvt_pk_bf16(pm[3][0], pm[3][1]); pk1.w = cvt_pk_bf16(pm[3][2], pm[3][3]);
        short8 pf0 = *(short8*)&pk0;
        short8 pf1 = *(short8*)&pk1;

        // O^T += V^T * P^T over sigma-permuted slots (order-invariant sum)
        __builtin_amdgcn_s_setprio(1);
#pragma unroll
        for (int td = 0; td < 4; td++) {
            short8 vf0 = *(const short8*)&Vc[(16*td + r15)*KLD + 8*quad];
            oacc[td] = __builtin_amdgcn_mfma_f32_16x16x32_bf16(vf0, pf0, oacc[td], 0, 0, 0);
            short8 vf1 = *(const short8*)&Vc[(16*td + r15)*KLD + 32 + 8*quad];
            oacc[td] = __builtin_amdgcn_mfma_f32_16x16x32_bf16(vf1, pf1, oacc[td], 0, 0, 0);
        }
        __builtin_amdgcn_s_setprio(0);

        // write prefetched tile into the other buffer (vmcnt wait is ~free by now)
        *(uint4*)&Ksh[cur ^ 1][ldstK] = kreg;
        *(uint2*)&Vts[cur ^ 1][ldstV]     = make_uint2(vreg.x, vreg.y);
        *(uint2*)&Vts[cur ^ 1][ldstV + 8] = make_uint2(vreg.z, vreg.w);
        cur ^= 1;

        // drain own LDS ops, raw barrier (no vmcnt drain), fence scheduler
        asm volatile("s_waitcnt lgkmcnt(0)" ::: "memory");
        __builtin_amdgcn_s_barrier();
        __builtin_amdgcn_sched_barrier(0);
    }

    // emit UNNORMALIZED partial: lane holds O^T[vchan=16td+4quad+reg][qrow=r15]
    size_t grow = rowbase + r0 + 16*w + r15;
    ushort* op = obp + (size_t)half*((size_t)ROWS*448) + grow*448 + h*WCH;
#pragma unroll
    for (int td = 0; td < 4; td++) {
        uint2 o2;
        o2.x = cvt_pk_bf16(oacc[td][0], oacc[td][1]);
        o2.y = cvt_pk_bf16(oacc[td][2], oacc[td][3]);
        *(uint2*)&op[16*td + 4*quad] = o2;
    }
    if (quad == 0) {
        *(float2*)&ml[(grow*7 + h)*4 + half*2] = make_float2(mrun, lrun);
    }
}

// ---------------------------------------------------------------- fus GEMM (bf16 MFMA); A = split-K merge of bf16 partials; bias; stats
__global__ __launch_bounds__(256) void gemm_fus(const ushort* __restrict__ OBP, const float* __restrict__ ML,
                                                const ushort* __restrict__ Wb,
                                                const float* __restrict__ bias, float* __restrict__ C,
                                                float* __restrict__ sums) {
    __shared__ float red[4][128][2];
    int t = threadIdx.x;
    int r0 = blockIdx.x * 64, n0 = blockIdx.y * 128;
    int w = t >> 6, lane = t & 63;
    int r15 = lane & 15, quad = lane >> 4;
    int arow = 16*w + r15;
    short8 aq[14];
    {
        const ushort* p1 = OBP + (size_t)(r0 + arow)*448;
        const ushort* p2 = p1 + (size_t)ROWS*448;
        const float* mlr = ML + (size_t)(r0 + arow)*28;
        float w1[7], w2[7];
#pragma unroll
        for (int hh = 0; hh < 7; hh++) {
            float m1 = mlr[hh*4+0], l1 = mlr[hh*4+1];
            float m2 = mlr[hh*4+2], l2 = mlr[hh*4+3];
            float M  = fmaxf(m1, m2);
            float e1 = EXP2(m1 - M), e2 = EXP2(m2 - M);
            float inv = RCP(fmaf(e1, l1, e2*l2));
            w1[hh] = e1*inv; w2[hh] = e2*inv;
        }
#pragma unroll
        for (int kc = 0; kc < 14; kc++) {
            int k0 = 32*kc + 8*quad;
            short8 a1 = *(const short8*)(p1 + k0);
            short8 a2 = *(const short8*)(p2 + k0);
            const int hh = kc >> 1;   // head = (32kc+8q)>>6 = kc>>1 (8q<32)
            float c0 = fmaf(w1[hh], bf2f(a1[0]), w2[hh]*bf2f(a2[0]));
            float c1 = fmaf(w1[hh], bf2f(a1[1]), w2[hh]*bf2f(a2[1]));
            float c2 = fmaf(w1[hh], bf2f(a1[2]), w2[hh]*bf2f(a2[2]));
            float c3 = fmaf(w1[hh], bf2f(a1[3]), w2[hh]*bf2f(a2[3]));
            float c4 = fmaf(w1[hh], bf2f(a1[4]), w2[hh]*bf2f(a2[4]));
            float c5 = fmaf(w1[hh], bf2f(a1[5]), w2[hh]*bf2f(a2[5]));
            float c6 = fmaf(w1[hh], bf2f(a1[6]), w2[hh]*bf2f(a2[6]));
            float c7 = fmaf(w1[hh], bf2f(a1[7]), w2[hh]*bf2f(a2[7]));
            uint4 pk;
            pk.x = cvt_pk_bf16(c0, c1); pk.y = cvt_pk_bf16(c2, c3);
            pk.z = cvt_pk_bf16(c4, c5); pk.w = cvt_pk_bf16(c6, c7);
            aq[kc] = *(short8*)&pk;
        }
    }
    floatx4 zero4 = {0.f, 0.f, 0.f, 0.f};
    floatx4 acc[8];
#pragma unroll
    for (int st = 0; st < 8; st++) acc[st] = zero4;
    const ushort* wbase = Wb + 196608 + (size_t)(n0 + r15)*448 + 8*quad;
#pragma unroll
    for (int st = 0; st < 8; st++) {
        const ushort* wp = wbase + (size_t)(16*st)*448;
#pragma unroll
        for (int kc = 0; kc < 14; kc++) {
            short8 bf = *(const short8*)(wp + 32*kc);
            acc[st] = __builtin_amdgcn_mfma_f32_16x16x32_bf16(aq[kc], bf, acc[st], 0, 0, 0);
        }
    }
#pragma unroll
    for (int st = 0; st < 8; st++) {
        int col = n0 + 16*st + r15;
        float bi = bias[col];
        float v0 = acc[st][0] + bi, v1 = acc[st][1] + bi, v2 = acc[st][2] + bi, v3 = acc[st][3] + bi;
        float s  = (v0 + v1) + (v2 + v3);
        float q2 = (v0*v0 + v1*v1) + (v2*v2 + v3*v3);
        s  += __shfl_xor(s, 16, 64);  s  += __shfl_xor(s, 32, 64);
        q2 += __shfl_xor(q2, 16, 64); q2 += __shfl_xor(q2, 32, 64);
        if (lane < 16) { red[w][16*st + r15][0] = s; red[w][16*st + r15][1] = q2; }
        C[(size_t)(r0 + 16*w + 4*quad + 0)*256 + col] = v0;
        C[(size_t)(r0 + 16*w + 4*quad + 1)*256 + col] = v1;
        C[(size_t)(r0 + 16*w + 4*quad + 2)*256 + col] = v2;
        C[(size_t)(r0 + 16*w + 4*quad + 3)*256 + col] = v3;
    }
    __syncthreads();
    {
        int col = t >> 1, which = t & 1;
        float v = red[0][col][which] + red[1][col][which] + red[2][col][which] + red[3][col][which];
        atomicAdd(&sums[2560 + which*256 + n0 + col], v);
    }
}

// ---------------------------------------------------------------- fused: fus-BN+relu+residual+LN (per-row) + MLP GEMM + residual + transposed out
__global__ __launch_bounds__(256) void gemm_mlp_ln(const float* __restrict__ FUSP, const float* __restrict__ A,
                                                   const float* __restrict__ sums,
                                                   const float* __restrict__ g_fus, const float* __restrict__ b_fus,
                                                   const float* __restrict__ g_ln, const float* __restrict__ b_ln,
                                                   const float* __restrict__ W, const float* __restrict__ bias,
                                                   float* __restrict__ outp) {
    __shared__ float Ys[256][68];    // y (LN out), k-major: Ys[c][row]
    __shared__ float FFs[64][65];    // feature__ tile (cols n0..n0+63)
    __shared__ float Ws[16][68];
    __shared__ float tr[64][65];
    __shared__ float SC[256], SH[256], GL[256], BL[256];
    int t = threadIdx.x;
    int r0 = blockIdx.x*64, n0 = blockIdx.y*64;
    {
        float mean0 = sums[2560 + t] * (1.0f/(float)ROWS);
        float var0  = sums[2560 + 256 + t] * (1.0f/(float)ROWS) - mean0*mean0;
        float sc = g_fus[t] / sqrtf(var0 + 1e-5f);
        SC[t] = sc; SH[t] = b_fus[t] - mean0*sc;
        GL[t] = g_ln[t]; BL[t] = b_ln[t];
    }
    __syncthreads();
    int row = t >> 2, seg = t & 3;
    size_t rb = (size_t)(r0 + row)*256;
    float4 vv[16];
    float s = 0.f, ss = 0.f;
#pragma unroll
    for (int j = 0; j < 16; j++) {
        int c = seg*64 + 4*j;
        float4 fp = *(const float4*)&FUSP[rb + c];
        float4 fe = *(const float4*)&A[rb + c];
        float4 sc4 = *(const float4*)&SC[c];
        float4 sh4 = *(const float4*)&SH[c];
        float4 v;
        v.x = fmaxf(fmaf(sc4.x, fp.x, sh4.x), 0.f) + fe.x;
        v.y = fmaxf(fmaf(sc4.y, fp.y, sh4.y), 0.f) + fe.y;
        v.z = fmaxf(fmaf(sc4.z, fp.z, sh4.z), 0.f) + fe.z;
        v.w = fmaxf(fmaf(sc4.w, fp.w, sh4.w), 0.f) + fe.w;
        vv[j] = v;
        s  += (v.x + v.y) + (v.z + v.w);
        ss += (v.x*v.x + v.y*v.y) + (v.z*v.z + v.w*v.w);
        if (seg == blockIdx.y) *(float4*)&FFs[row][4*j] = v;
    }
    s  += __shfl_xor(s, 1, 64);  s  += __shfl_xor(s, 2, 64);
    ss += __shfl_xor(ss, 1, 64); ss += __shfl_xor(ss, 2, 64);
    float mean = s * (1.f/256.f);
    float var  = ss * (1.f/256.f) - mean*mean;
    float rin  = 1.f/sqrtf(var + 1e-5f);
#pragma unroll
    for (int j = 0; j < 16; j++) {
        int c = seg*64 + 4*j;
        float4 gl = *(const float4*)&GL[c];
        float4 bl = *(const float4*)&BL[c];
        float4 v = vv[j];
        Ys[c+0][row] = (v.x - mean)*rin*gl.x + bl.x;
        Ys[c+1][row] = (v.y - mean)*rin*gl.y + bl.y;
        Ys[c+2][row] = (v.z - mean)*rin*gl.z + bl.z;
        Ys[c+3][row] = (v.w - mean)*rin*gl.w + bl.w;
    }
    __syncthreads();
    // GEMM: y[64rows x 256] * W_mlp[n0..n0+63][256]^T
    int tx = t & 15, ty = t >> 4;
    int lk = t & 15, lm = t >> 4;
    float acc[4][4];
#pragma unroll
    for (int i = 0; i < 4; i++)
#pragma unroll
        for (int j = 0; j < 4; j++) acc[i][j] = 0.f;
    for (int k0 = 0; k0 < 256; k0 += 16) {
#pragma unroll
        for (int i2 = 0; i2 < 4; i2++)
            Ws[lk][lm + 16*i2] = W[(size_t)(n0 + lm + 16*i2)*256 + k0 + lk];
        __syncthreads();
#pragma unroll
        for (int kq = 0; kq < 16; kq++) {
            float4 a  = *(const float4*)&Ys[k0 + kq][4*ty];
            float4 b4 = *(const float4*)&Ws[kq][4*tx];
            float av[4] = {a.x, a.y, a.z, a.w};
            float bv[4] = {b4.x, b4.y, b4.z, b4.w};
#pragma unroll
            for (int i = 0; i < 4; i++)
#pragma unroll
                for (int j = 0; j < 4; j++) acc[i][j] = fmaf(av[i], bv[j], acc[i][j]);
        }
        __syncthreads();
    }
#pragma unroll
    for (int i = 0; i < 4; i++)
#pragma unroll
        for (int j = 0; j < 4; j++) {
            float v = acc[i][j] + bias[n0 + 4*tx + j] + FFs[4*ty + i][4*tx + j];
            tr[4*tx + j][4*ty + i] = v;
        }
    __syncthreads();
    int b = r0 >> 11, nbase = r0 & 2047;
#pragma unroll
    for (int rep = 0; rep < 16; rep++) {
        int e = t + 256*rep;
        int cl = e >> 6, nl = e & 63;
        outp[((size_t)(b*256 + n0 + cl))*2048 + nbase + nl] = tr[cl][nl];
    }
}

// ================================================================ host
extern "C" void kernel_launch(void* const* d_in, const int* in_sizes, int n_in,
                              void* d_out, int out_size, void* d_ws, size_t ws_size,
                              hipStream_t stream) {
    const float* xyz    = (const float*)d_in[0];
    const float* f      = (const float*)d_in[1];
    const float* W_geo  = (const float*)d_in[2];
    const float* g_geo  = (const float*)d_in[3];
    const float* b_geo  = (const float*)d_in[4];
    const float* W_feat = (const float*)d_in[5];
    const float* g_feat = (const float*)d_in[6];
    const float* b_feat = (const float*)d_in[7];
    const float* g_bn   = (const float*)d_in[8];
    const float* b_bn   = (const float*)d_in[9];
    const float* W_q    = (const float*)d_in[10];
    const float* g_q    = (const float*)d_in[11];
    const float* b_q    = (const float*)d_in[12];
    const float* W_k    = (const float*)d_in[13];
    const float* g_k    = (const float*)d_in[14];
    const float* b_k    = (const float*)d_in[15];
    const float* W_v    = (const float*)d_in[16];
    const float* g_v    = (const float*)d_in[17];
    const float* b_v    = (const float*)d_in[18];
    const float* W_fus  = (const float*)d_in[19];
    const float* bias_fus = (const float*)d_in[20];
    const float* g_fus  = (const float*)d_in[21];
    const float* b_fus  = (const float*)d_in[22];
    const float* g_ln   = (const float*)d_in[23];
    const float* b_ln   = (const float*)d_in[24];
    const float* W_mlp  = (const float*)d_in[25];
    const float* bias_mlp = (const float*)d_in[26];

    float* ws = (float*)d_ws;
    const size_t MBF = 262144;  // floats per MiB
    float* SUMS  = ws;
    int*   IDX   = (int*)(ws + 16384);
    float* A     = ws + 1*MBF;
    float* X     = ws + 9*MBF;
    ushort* QK16 = (ushort*)(ws + 9*MBF);
    float* FUSP  = ws + 9*MBF;
    float* CSEL  = ws + 17*MBF;
    float* QKVF  = ws + 17*MBF;
    ushort* OBP  = (ushort*)(ws + 17*MBF);   // 2 x 8192 x 448 bf16 = 14.7 MiB (17..31.7)
    float* ML    = ws + 33*MBF;              // 8192 x 7 x 4 floats = 0.92 MiB (33..34)
    ushort* VT16 = (ushort*)(ws + 45*MBF);
    ushort* WB16 = (ushort*)(ws + 49*MBF);

    prep_knn<<<2560, 256, 0, stream>>>(f, W_feat, xyz, W_geo, W_q, W_k, W_v, W_fus,
                                       X, A, WB16, SUMS, IDX);
    stats_gf<<<256, 256, 0, stream>>>(A, X, IDX, g_geo, g_feat, SUMS, CSEL);
    feature_maxsel<<<256, 256, 0, stream>>>(CSEL, SUMS, g_geo, b_geo, g_feat, b_feat, A, SUMS + 512);
    gemm_qkv<<<dim3(128, 3), 256, 0, stream>>>(A, SUMS, g_bn, b_bn, WB16, QKVF, SUMS);
    affine_qkv<<<dim3(128, 12), 256, 0, stream>>>(QKVF, SUMS, g_q, b_q, g_k, b_k, g_v, b_v, QK16, VT16);
    attn2<<<dim3(NPTS/128, NHEADS, NB*2), 512, 0, stream>>>(QK16, VT16, OBP, ML);
    gemm_fus<<<dim3(128, 2), 256, 0, stream>>>(OBP, ML, WB16, bias_fus, FUSP, SUMS);
    gemm_mlp_ln<<<dim3(128, 4), 256, 0, stream>>>(FUSP, A, SUMS, g_fus, b_fus, g_ln, b_ln,
                                                  W_mlp, bias_mlp, (float*)d_out);
}

// Round 11
// 371.963 us; speedup vs baseline: 1.5039x; 1.0025x over previous
//
#include <hip/hip_runtime.h>
#include <math.h>

#define NB    4
#define NPTS  2048
#define ROWS  (NB*NPTS)   // 8192
#define CIN   64
#define COUT  256
#define KNBR  21
#define NHEADS 7
#define WCH   64
#define DSH   32
#define LOG2E 1.4426950408889634f
#define KLD   72   // LDS row stride in ushorts = 144 B: multiple of 16 B (b128-aligned)

typedef __attribute__((ext_vector_type(8))) short short8;
typedef __attribute__((ext_vector_type(4))) float floatx4;

#if __has_builtin(__builtin_amdgcn_exp2f)
#define EXP2(x) __builtin_amdgcn_exp2f(x)
#else
#define EXP2(x) __expf((x)*0.6931471805599453f)
#endif
#if __has_builtin(__builtin_amdgcn_rcpf)
#define RCP(x) __builtin_amdgcn_rcpf(x)
#else
#define RCP(x) (1.0f/(x))
#endif

__device__ __forceinline__ ushort f2bf(float x) {
    unsigned u = __float_as_uint(x);
    u += 0x7fffu + ((u >> 16) & 1u);   // RNE
    return (ushort)(u >> 16);
}

__device__ __forceinline__ float bf2f(short u) {
    return __uint_as_float(((unsigned)(unsigned short)u) << 16);
}

// packed f32x2 -> bf16x2 (RNE), single VALU inst; no builtin on gfx950
__device__ __forceinline__ unsigned cvt_pk_bf16(float lo, float hi) {
    unsigned r;
    asm("v_cvt_pk_bf16_f32 %0, %1, %2" : "=v"(r) : "v"(lo), "v"(hi));
    return r;
}

// wave64 u32 min-reduce via DPP chain; broadcast via readlane(63)
template<int CTRL, int RMASK>
__device__ __forceinline__ unsigned dpp_umin_step(unsigned x) {
    unsigned t = (unsigned)__builtin_amdgcn_update_dpp((int)x, (int)x, CTRL, RMASK, 0xF, false);
    return (t < x) ? t : x;
}
__device__ __forceinline__ unsigned wave_min_u32(unsigned x) {
    x = dpp_umin_step<0x111, 0xF>(x);
    x = dpp_umin_step<0x112, 0xF>(x);
    x = dpp_umin_step<0x114, 0xF>(x);
    x = dpp_umin_step<0x118, 0xF>(x);
    x = dpp_umin_step<0x142, 0xA>(x);
    x = dpp_umin_step<0x143, 0xC>(x);
    return (unsigned)__builtin_amdgcn_readlane((int)x, 63);
}

__device__ __forceinline__ unsigned umin2(unsigned a, unsigned b) { return a < b ? a : b; }
__device__ __forceinline__ unsigned umax2(unsigned a, unsigned b) { return a < b ? b : a; }

// insert k into sorted ascending 6-list (m1 smallest); 11 min/max ops, static regs
__device__ __forceinline__ void ins6(unsigned &m1, unsigned &m2, unsigned &m3,
                                     unsigned &m4, unsigned &m5, unsigned &m6, unsigned k) {
    unsigned c = k, t;
    t = umin2(m1, c); c = umax2(m1, c); m1 = t;
    t = umin2(m2, c); c = umax2(m2, c); m2 = t;
    t = umin2(m3, c); c = umax2(m3, c); m3 = t;
    t = umin2(m4, c); c = umax2(m4, c); m4 = t;
    t = umin2(m5, c); c = umax2(m5, c); m5 = t;
    m6 = umin2(m6, c);
}

// ---------------------------------------------------------------- fused prep (blocks 0..511) + KNN (blocks 512..2559)
__global__ __launch_bounds__(256) void prep_knn(const float* __restrict__ f, const float* __restrict__ Wf,
                                                const float* __restrict__ xyz, const float* __restrict__ Wg,
                                                const float* __restrict__ W_q, const float* __restrict__ W_k,
                                                const float* __restrict__ W_v, const float* __restrict__ W_fus,
                                                float* __restrict__ X, float* __restrict__ A,
                                                ushort* __restrict__ Wb, float* __restrict__ sums,
                                                int* __restrict__ idx) {
    __shared__ float4 SXQ[2048];
    int t = threadIdx.x;
    int blk = blockIdx.x;
    if (blk < 512) {
        // ======== prep path ========
        float* As = (float*)SXQ;
        float* Ws = As + 16*68;
        int bx = blk & 127, by = blk >> 7;
        if (by == 0 && bx < 12) sums[bx*256 + t] = 0.f;
        int gid = (by*128 + bx)*256 + t;
        for (int i = gid; i < 311296; i += 131072) {
            const float* Wsrc; int off;
            if (i < 65536)       { Wsrc = W_q;   off = i; }
            else if (i < 131072) { Wsrc = W_k;   off = i - 65536; }
            else if (i < 196608) { Wsrc = W_v;   off = i - 131072; }
            else                 { Wsrc = W_fus; off = i - 196608; }
            Wb[i] = f2bf(Wsrc[off]);
        }
        int r0 = bx * 64, n0 = by * 64;
        for (int e = t; e < 4096; e += 256) {
            int row = r0 + (e >> 6), c = n0 + (e & 63), cc = c & 127;
            float x = xyz[row*3], y = xyz[row*3+1], z = xyz[row*3+2];
            const float* w = Wg + cc*6;
            float s = (c < 128) ? ((w[3]*x + w[4]*y) + w[5]*z)
                                : (((w[0]-w[3])*x + (w[1]-w[4])*y) + (w[2]-w[5])*z);
            A[(size_t)row*256 + c] = s;
        }
        int b = r0 >> 11, nbase = r0 & 2047;
        int tx = t & 15, ty = t >> 4;
        float acc[4][4];
#pragma unroll
        for (int i = 0; i < 4; i++)
#pragma unroll
            for (int j = 0; j < 4; j++) acc[i][j] = 0.f;
        int m64 = t & 63, kg = t >> 6;
        int lk = t & 15, lm = t >> 4;
        for (int k0 = 0; k0 < 64; k0 += 16) {
#pragma unroll
            for (int p = 0; p < 4; p++) {
                int k = kg*4 + p;
                As[k*68 + m64] = f[(size_t)b*CIN*NPTS + (size_t)(k0 + k)*NPTS + nbase + m64];
            }
#pragma unroll
            for (int i2 = 0; i2 < 4; i2++) {
                int cg = n0 + lm + 16*i2;
                Ws[lk*68 + lm + 16*i2] = Wf[(size_t)(cg & 127)*128 + (cg >> 7)*64 + k0 + lk];
            }
            __syncthreads();
#pragma unroll
            for (int kq = 0; kq < 16; kq++) {
                float4 a  = *(const float4*)&As[kq*68 + 4*ty];
                float4 b4 = *(const float4*)&Ws[kq*68 + 4*tx];
                float av[4] = {a.x, a.y, a.z, a.w};
                float bv[4] = {b4.x, b4.y, b4.z, b4.w};
#pragma unroll
                for (int i = 0; i < 4; i++)
#pragma unroll
                    for (int j = 0; j < 4; j++) acc[i][j] = fmaf(av[i], bv[j], acc[i][j]);
            }
            __syncthreads();
        }
#pragma unroll
        for (int i = 0; i < 4; i++)
#pragma unroll
            for (int j = 0; j < 4; j++)
                X[(size_t)(r0 + 4*ty + i)*256 + n0 + 4*tx + j] = acc[i][j];
        return;
    }
    // ======== KNN path ========
    int kb = blk - 512;
    int b = kb >> 9;
    int g = kb & 511;
    for (int m = t; m < NPTS; m += 256) {
        float x = xyz[(size_t)b*NPTS*3 + m*3];
        float y = xyz[(size_t)b*NPTS*3 + m*3 + 1];
        float z = xyz[(size_t)b*NPTS*3 + m*3 + 2];
        SXQ[m] = make_float4(x, y, z, (x*x + y*y) + z*z);
    }
    __syncthreads();
    int w = t >> 6, lane = t & 63;
    int n = g*4 + w;
    float4 q4 = SXQ[n];
    float qx = q4.x, qy = q4.y, qz = q4.z, sqn = q4.w;

    // keys kept for exact fallback; two independent top-6 streams (halves dep chain)
    unsigned key[32];
    unsigned a1 = 0xFFFFFFFFu, a2 = 0xFFFFFFFFu, a3 = 0xFFFFFFFFu,
             a4 = 0xFFFFFFFFu, a5 = 0xFFFFFFFFu, a6 = 0xFFFFFFFFu;
    unsigned c1 = 0xFFFFFFFFu, c2 = 0xFFFFFFFFu, c3 = 0xFFFFFFFFu,
             c4 = 0xFFFFFFFFu, c5 = 0xFFFFFFFFu, c6 = 0xFFFFFFFFu;
#pragma unroll
    for (int i = 0; i < 16; i++) {
        int m = lane + (i << 6);
        float4 p = SXQ[m];
        float dt = (qx*p.x + qy*p.y) + qz*p.z;
        float d2 = fmaxf((sqn + p.w) - 2.0f*dt, 0.f);
        unsigned kv = (__float_as_uint(d2) & 0xFFFFF800u) | (unsigned)m;
        key[i] = kv;
        ins6(a1, a2, a3, a4, a5, a6, kv);
    }
#pragma unroll
    for (int i = 16; i < 32; i++) {
        int m = lane + (i << 6);
        float4 p = SXQ[m];
        float dt = (qx*p.x + qy*p.y) + qz*p.z;
        float d2 = fmaxf((sqn + p.w) - 2.0f*dt, 0.f);
        unsigned kv = (__float_as_uint(d2) & 0xFFFFF800u) | (unsigned)m;
        key[i] = kv;
        ins6(c1, c2, c3, c4, c5, c6, kv);
    }
    // merge stream C into A -> per-lane sorted top-6
    ins6(a1, a2, a3, a4, a5, a6, c1);
    ins6(a1, a2, a3, a4, a5, a6, c2);
    ins6(a1, a2, a3, a4, a5, a6, c3);
    ins6(a1, a2, a3, a4, a5, a6, c4);
    ins6(a1, a2, a3, a4, a5, a6, c5);
    ins6(a1, a2, a3, a4, a5, a6, c6);

    unsigned winkey = 0xFFFFFFFFu;
    {
        // 32-round multiway merge-pop over per-lane sorted fronts.
        // Exact while no lane pops all 6 (checked below; keys unique via index bits).
        unsigned fr = a1, p2 = a2, p3 = a3, p4 = a4, p5 = a5, p6 = a6;
#pragma unroll
        for (int kk = 0; kk < 32; kk++) {
            unsigned win = wave_min_u32(fr);
            if (lane == kk) winkey = win;
            bool own = (fr == win);
            fr = own ? p2 : fr;
            p2 = own ? p3 : p2;
            p3 = own ? p4 : p3;
            p4 = own ? p5 : p4;
            p5 = own ? p6 : p5;
            p6 = own ? 0xFFFFFFFFu : p6;
        }
        if (__ballot(fr == 0xFFFFFFFFu) != 0ULL) {
            // rare fallback (some lane contributed >=6 of top-32): exact serial
            // extraction over the untouched key[] array — original algorithm.
            winkey = 0xFFFFFFFFu;
            for (int kk = 0; kk < 32; kk++) {
                unsigned lv = key[0];
#pragma unroll
                for (int i = 1; i < 32; i++) lv = (key[i] < lv) ? key[i] : lv;
                unsigned win = wave_min_u32(lv);
                if (lane == kk) winkey = win;
                unsigned widx = win & 2047u;
                int slot = (int)(widx >> 6);
                bool own = (lane == (int)(widx & 63u));
#pragma unroll
                for (int i = 0; i < 32; i++)
                    if (i == slot && own) key[i] = 0xFFFFFFFFu;
            }
        }
    }
    double d2r;
    int mr;
    {
        double qx64 = (double)qx, qy64 = (double)qy, qz64 = (double)qz;
        double sqn64 = qx64*qx64 + qy64*qy64 + qz64*qz64;
        if (lane < 32) {
            mr = (int)(winkey & 2047u);
            float4 p = SXQ[mr];
            double x = (double)p.x, y = (double)p.y, z = (double)p.z;
            double sqm = x*x + y*y + z*z;
            double dt  = qx64*x + qy64*y + qz64*z;
            d2r = (sqn64 + sqm) - 2.0*dt;
        } else {
            d2r = INFINITY; mr = 0x7FFFFFFF;
        }
    }
#pragma unroll
    for (int k = 2; k <= 32; k <<= 1) {
#pragma unroll
        for (int j = k >> 1; j > 0; j >>= 1) {
            double od = __shfl_xor(d2r, j, 64);
            int    om = __shfl_xor(mr, j, 64);
            bool up    = ((lane & k) == 0);
            bool lower = ((lane & j) == 0);
            bool oless = (od < d2r) || (od == d2r && om < mr);
            bool keepOther = up ? (lower ? oless : !oless) : (lower ? !oless : oless);
            if (keepOther) { d2r = od; mr = om; }
        }
    }
    if (lane < KNBR)
        idx[((size_t)b*NPTS + n)*KNBR + lane] = mr;
}

// ---------------------------------------------------------------- stats + sign-selected extreme over K
__global__ __launch_bounds__(256) void stats_gf(const float* __restrict__ geoBC, const float* __restrict__ featAC,
                                                const int* __restrict__ idx, const float* __restrict__ g_geo,
                                                const float* __restrict__ g_feat,
                                                float* __restrict__ sums, float* __restrict__ xsel) {
    int c = threadIdx.x;
    int cc = c & 127;
    const float* base = (c < 128) ? geoBC : featAC;
    bool wantmax = ((c < 128) ? g_geo[cc] : g_feat[cc]) >= 0.f;
    float s = 0.f, ss = 0.f;
    int r0 = blockIdx.x * 32;
    for (int r = r0; r < r0 + 32; r++) {
        int b = r >> 11;
        float ctr = base[(size_t)r*256 + 128 + cc];
        float mx = -1e30f, mn = 1e30f;
        const int* ip = idx + (size_t)r*KNBR;
        for (int kk = 0; kk < KNBR; kk++) {
            int j = ip[kk];
            float xv = ctr + base[((size_t)(b*NPTS + j))*256 + cc];
            mx = fmaxf(mx, xv); mn = fminf(mn, xv);
            s += xv; ss += xv*xv;
        }
        xsel[(size_t)r*256 + c] = wantmax ? mx : mn;
    }
    atomicAdd(&sums[c], s);
    atomicAdd(&sums[256 + c], ss);
}

// ---------------------------------------------------------------- feature_ = relu(affine(xsel)) with inline BN finalize; + bn1 stats
__global__ __launch_bounds__(256) void feature_maxsel(const float* __restrict__ xsel, const float* __restrict__ sums,
                                                      const float* __restrict__ g_geo, const float* __restrict__ b_geo,
                                                      const float* __restrict__ g_feat, const float* __restrict__ b_feat,
                                                      float* __restrict__ feat, float* __restrict__ sums_bn1) {
    int c = threadIdx.x;
    const float inv = 1.0f / (float)(ROWS*KNBR);
    float mean = sums[c]*inv;
    float var  = sums[256+c]*inv - mean*mean;
    float g  = (c < 128) ? g_geo[c] : g_feat[c-128];
    float bb = (c < 128) ? b_geo[c] : b_feat[c-128];
    float sc = g / sqrtf(var + 1e-5f);
    float tt = bb - mean*sc;
    float s = 0.f, ss = 0.f;
    int r0 = blockIdx.x*32;
    for (int r = r0; r < r0+32; r++) {
        size_t i = (size_t)r*256 + c;
        float y = fmaxf(fmaf(sc, xsel[i], tt), 0.f);
        feat[i] = y; s += y; ss += y*y;
    }
    atomicAdd(&sums_bn1[c], s); atomicAdd(&sums_bn1[256+c], ss);
}

// ---------------------------------------------------------------- q/k/v GEMM via bf16 MFMA; inline bn1 finalize on A
__global__ __launch_bounds__(256) void gemm_qkv(const float* __restrict__ Af, const float* __restrict__ sums_in,
                                                const float* __restrict__ g_bn, const float* __restrict__ b_bn,
                                                const ushort* __restrict__ Wb,
                                                float* __restrict__ QKVF, float* __restrict__ sums) {
    __shared__ float bns[2][256];
    __shared__ float red[4][256][2];
    int t = threadIdx.x;
    int r0 = blockIdx.x * 64, g = blockIdx.y;
    int w = t >> 6, lane = t & 63;
    int r15 = lane & 15, quad = lane >> 4;
    {
        float mean = sums_in[512 + t] * (1.0f/(float)ROWS);
        float var  = sums_in[768 + t] * (1.0f/(float)ROWS) - mean*mean;
        float sc = g_bn[t] / sqrtf(var + 1e-5f);
        bns[0][t] = sc;
        bns[1][t] = b_bn[t] - mean*sc;
    }
    __syncthreads();
    short8 aq[8];
    {
        const float* ap = Af + (size_t)(r0 + 16*w + r15)*256;
#pragma unroll
        for (int kc = 0; kc < 8; kc++) {
            int k0 = 32*kc + 8*quad;
            float4 a0 = *(const float4*)&ap[k0];
            float4 a1 = *(const float4*)&ap[k0+4];
            float4 s0 = *(const float4*)&bns[0][k0];
            float4 s1 = *(const float4*)&bns[0][k0+4];
            float4 h0 = *(const float4*)&bns[1][k0];
            float4 h1 = *(const float4*)&bns[1][k0+4];
            ushort u8[8];
            u8[0] = f2bf(fmaf(s0.x, a0.x, h0.x)); u8[1] = f2bf(fmaf(s0.y, a0.y, h0.y));
            u8[2] = f2bf(fmaf(s0.z, a0.z, h0.z)); u8[3] = f2bf(fmaf(s0.w, a0.w, h0.w));
            u8[4] = f2bf(fmaf(s1.x, a1.x, h1.x)); u8[5] = f2bf(fmaf(s1.y, a1.y, h1.y));
            u8[6] = f2bf(fmaf(s1.z, a1.z, h1.z)); u8[7] = f2bf(fmaf(s1.w, a1.w, h1.w));
            aq[kc] = *(short8*)u8;
        }
    }
    floatx4 zero4 = {0.f, 0.f, 0.f, 0.f};
    floatx4 acc[16];
#pragma unroll
    for (int st = 0; st < 16; st++) acc[st] = zero4;
    const ushort* wbase = Wb + (size_t)g*65536 + (size_t)r15*256 + 8*quad;
#pragma unroll
    for (int st = 0; st < 16; st++) {
        const ushort* wp = wbase + (size_t)(16*st)*256;
#pragma unroll
        for (int kc = 0; kc < 8; kc++) {
            short8 bf = *(const short8*)(wp + 32*kc);
            acc[st] = __builtin_amdgcn_mfma_f32_16x16x32_bf16(aq[kc], bf, acc[st], 0, 0, 0);
        }
    }
#pragma unroll
    for (int st = 0; st < 16; st++) {
        float s  = (acc[st][0] + acc[st][1]) + (acc[st][2] + acc[st][3]);
        float q2 = (acc[st][0]*acc[st][0] + acc[st][1]*acc[st][1]) +
                   (acc[st][2]*acc[st][2] + acc[st][3]*acc[st][3]);
        s  += __shfl_xor(s, 16, 64);  s  += __shfl_xor(s, 32, 64);
        q2 += __shfl_xor(q2, 16, 64); q2 += __shfl_xor(q2, 32, 64);
        if (lane < 16) { red[w][16*st + r15][0] = s; red[w][16*st + r15][1] = q2; }
#pragma unroll
        for (int reg = 0; reg < 4; reg++)
            QKVF[(size_t)(r0 + 16*w + 4*quad + reg)*768 + g*256 + 16*st + r15] = acc[st][reg];
    }
    __syncthreads();
    {
        float s = red[0][t][0] + red[1][t][0] + red[2][t][0] + red[3][t][0];
        float q = red[0][t][1] + red[1][t][1] + red[2][t][1] + red[3][t][1];
        atomicAdd(&sums[1024 + g*512 + t], s);
        atomicAdd(&sums[1024 + g*512 + 256 + t], q);
    }
}

// ---------------------------------------------------------------- affine+relu+bf16 (inline qkv BN finalize): q/k row-major (q scaled by log2e), v transposed
__global__ __launch_bounds__(256) void affine_qkv(const float* __restrict__ QKVF, const float* __restrict__ sums,
                                                  const float* __restrict__ g_q, const float* __restrict__ b_q,
                                                  const float* __restrict__ g_k, const float* __restrict__ b_k,
                                                  const float* __restrict__ g_v, const float* __restrict__ b_v,
                                                  ushort* __restrict__ qk, ushort* __restrict__ vt) {
    __shared__ float sts[6][256];
    __shared__ ushort tile[64][72];
    int t = threadIdx.x;
    {
        const float* gs[3] = {g_q, g_k, g_v};
        const float* bs[3] = {b_q, b_k, b_v};
#pragma unroll
        for (int g = 0; g < 3; g++) {
            float mean = sums[1024 + g*512 + t] * (1.0f/(float)ROWS);
            float var  = sums[1024 + g*512 + 256 + t] * (1.0f/(float)ROWS) - mean*mean;
            float sc = gs[g][t] / sqrtf(var + 1e-5f);
            float sh = bs[g][t] - mean*sc;
            if (g == 0) { sc *= LOG2E; sh *= LOG2E; }   // exp2-domain softmax
            sts[2*g][t] = sc;
            sts[2*g+1][t] = sh;
        }
    }
    __syncthreads();
    int r0 = blockIdx.x * 64, c0 = blockIdx.y * 64;
    int b = r0 >> 11, nbase = r0 & 2047;
    if (c0 < 512) {
#pragma unroll
        for (int rep = 0; rep < 16; rep++) {
            int e = t + 256*rep;
            int row = e >> 6, c = e & 63;
            int col = c0 + c, g = col >> 8, cc = col & 255;
            float v = QKVF[(size_t)(r0 + row)*768 + col];
            v = fmaxf(fmaf(sts[2*g][cc], v, sts[2*g+1][cc]), 0.f);
            qk[(size_t)(r0 + row)*512 + col] = f2bf(v);
        }
    } else {
#pragma unroll
        for (int rep = 0; rep < 16; rep++) {
            int e = t + 256*rep;
            int row = e >> 6, c = e & 63;
            int col = c0 + c, cc = col & 255;
            float v = QKVF[(size_t)(r0 + row)*768 + col];
            v = fmaxf(fmaf(sts[4][cc], v, sts[5][cc]), 0.f);
            tile[c][row] = f2bf(v);
        }
        __syncthreads();
#pragma unroll
        for (int rep = 0; rep < 16; rep++) {
            int e = t + 256*rep;
            int cc = e >> 6, nn = e & 63;
            vt[((size_t)(b*256 + (c0 - 512) + cc))*2048 + nbase + nn] = tile[cc][nn];
        }
    }
}

// ---------------------------------------------------------------- MFMA bf16 flash attention v9: split-K + QBLK=32/wave.
// LDS-throughput-bound regime (R10 counters): each K/V fragment read now feeds
// BOTH u-tiles' MFMAs -> ~1.8x fewer LDS cycles per Q-row. 8 waves x QBLK=32 =
// 256 rows/block; split-K halves (16 KV tiles each) keep grid at 448 blocks.
// sigma-permuted V, P in registers, K+V LDS double-buffered (KLD=72=144B),
// raw-barrier pipeline. Emits unnormalized bf16 partials + (m,l); merge in gemm_fus.
__global__ __launch_bounds__(512) void attn2(const ushort* __restrict__ qk, const ushort* __restrict__ vt,
                                             ushort* __restrict__ obp, float* __restrict__ ml) {
    __shared__ ushort Ksh[2][64*KLD];
    __shared__ ushort Vts[2][64*KLD];
    int h = blockIdx.y;
    int z = blockIdx.z, b = z >> 1, half = z & 1;
    int r0 = blockIdx.x * 256;
    int t = threadIdx.x;
    int w = t >> 6, lane = t & 63;
    int r15 = lane & 15, quad = lane >> 4;
    size_t rowbase = (size_t)b*NPTS;
    int hoff = h*DSH;
    int rr = t >> 3, c8 = t & 7;
    int mstart = half << 10, mend = mstart + 1024;

    const ushort* ksrc = qk + (rowbase + rr)*512 + 256 + hoff + 8*c8;     // + m0*512
    const ushort* vsrc = vt + ((size_t)(b*256 + hoff + rr))*2048 + 8*c8;  // + m0
    int ldstK = rr*KLD + 8*c8;
    // sigma-mapped V staging base: local keys 8*c8+jj -> slots vb+jj (jj<4), vb+8+(jj-4)
    int vb = 4*((c8 >> 1) & 1) + 16*(c8 & 1) + 32*(c8 >> 2);
    int ldstV = rr*KLD + vb;

    short8 aq[2][2];
#pragma unroll
    for (int u = 0; u < 2; u++)
#pragma unroll
        for (int s = 0; s < 2; s++)
            aq[u][s] = *(const short8*)(qk + (rowbase + r0 + 32*w + 16*u + r15)*512 + hoff + 32*s + 8*quad);

    // stage this half's first tile into buffer 0
    {
        uint4 k0 = *(const uint4*)(ksrc + (size_t)mstart*512);
        uint4 v0 = *(const uint4*)(vsrc + mstart);
        *(uint4*)&Ksh[0][ldstK] = k0;
        *(uint2*)&Vts[0][ldstV]     = make_uint2(v0.x, v0.y);
        *(uint2*)&Vts[0][ldstV + 8] = make_uint2(v0.z, v0.w);
    }

    floatx4 zero4 = {0.f, 0.f, 0.f, 0.f};
    floatx4 oacc[2][4];
    float mrun[2], lrun[2];
#pragma unroll
    for (int u = 0; u < 2; u++) {
        mrun[u] = -1e30f; lrun[u] = 0.f;
#pragma unroll
        for (int i = 0; i < 4; i++) oacc[u][i] = zero4;
    }

    asm volatile("s_waitcnt lgkmcnt(0)" ::: "memory");
    __builtin_amdgcn_s_barrier();
    __builtin_amdgcn_sched_barrier(0);

    int cur = 0;
    for (int m0 = mstart; m0 < mend; m0 += 64) {
        // prefetch next KV tile into registers (latency hides under compute)
        int mnext = (m0 + 64 < mend) ? (m0 + 64) : mstart;
        uint4 kreg = *(const uint4*)(ksrc + (size_t)mnext*512);
        uint4 vreg = *(const uint4*)(vsrc + mnext);

        const ushort* Kc = Ksh[cur];
        const ushort* Vc = Vts[cur];

        // S = K * Q^T for both u-tiles: one K-frag read feeds 2 MFMAs
        floatx4 sacc[2][4];
#pragma unroll
        for (int u = 0; u < 2; u++)
#pragma unroll
            for (int tt = 0; tt < 4; tt++) sacc[u][tt] = zero4;
        __builtin_amdgcn_s_setprio(1);
#pragma unroll
        for (int tt = 0; tt < 4; tt++) {
            int key = 16*tt + r15;
#pragma unroll
            for (int s = 0; s < 2; s++) {
                short8 kf = *(const short8*)&Kc[key*KLD + 32*s + 8*quad];
                sacc[0][tt] = __builtin_amdgcn_mfma_f32_16x16x32_bf16(kf, aq[0][s], sacc[0][tt], 0, 0, 0);
                sacc[1][tt] = __builtin_amdgcn_mfma_f32_16x16x32_bf16(kf, aq[1][s], sacc[1][tt], 0, 0, 0);
            }
        }
        __builtin_amdgcn_s_setprio(0);

        // softmax per u-tile; P packed directly into PV B-frags (sigma space)
        short8 pf[2][2];
#pragma unroll
        for (int u = 0; u < 2; u++) {
            float mx = sacc[u][0][0];
#pragma unroll
            for (int tt = 0; tt < 4; tt++)
#pragma unroll
                for (int reg = 0; reg < 4; reg++) mx = fmaxf(mx, sacc[u][tt][reg]);
            mx = fmaxf(mx, __shfl_xor(mx, 16, 64));
            mx = fmaxf(mx, __shfl_xor(mx, 32, 64));

            // defer-rescale: alpha==1 exactly when no row in the wave got a new max
            if (!__all(mx <= mrun[u])) {
                float mnew = fmaxf(mrun[u], mx);
                float alpha = EXP2(mrun[u] - mnew);
                lrun[u] *= alpha;
#pragma unroll
                for (int td = 0; td < 4; td++) oacc[u][td] *= alpha;
                mrun[u] = mnew;
            }

            float pm[4][4];
            float rs = 0.f;
#pragma unroll
            for (int tt = 0; tt < 4; tt++) {
#pragma unroll
                for (int reg = 0; reg < 4; reg++) {
                    float p = EXP2(sacc[u][tt][reg] - mrun[u]);
                    pm[tt][reg] = p; rs += p;
                }
            }
            rs += __shfl_xor(rs, 16, 64);
            rs += __shfl_xor(rs, 32, 64);
            lrun[u] += rs;

            uint4 pk0, pk1;
            pk0.x = cvt_pk_bf16(pm[0][0], pm[0][1]); pk0.y = cvt_pk_bf16(pm[0][2], pm[0][3]);
            pk0.z = cvt_pk_bf16(pm[1][0], pm[1][1]); pk0.w = cvt_pk_bf16(pm[1][2], pm[1][3]);
            pk1.x = cvt_pk_bf16(pm[2][0], pm[2][1]); pk1.y = cvt_pk_bf16(pm[2][2], pm[2][3]);
            pk1.z = cvt_pk_bf16(pm[3][0], pm[3][1]); pk1.w = cvt_pk_bf16(pm[3][2], pm[3][3]);
            pf[u][0] = *(short8*)&pk0;
            pf[u][1] = *(short8*)&pk1;
        }

        // O^T += V^T * P^T : one V-frag read feeds both u-tiles
        __builtin_amdgcn_s_setprio(1);
#pragma unroll
        for (int td = 0; td < 4; td++) {
            short8 vf0 = *(const short8*)&Vc[(16*td + r15)*KLD + 8*quad];
            oacc[0][td] = __builtin_amdgcn_mfma_f32_16x16x32_bf16(vf0, pf[0][0], oacc[0][td], 0, 0, 0);
            oacc[1][td] = __builtin_amdgcn_mfma_f32_16x16x32_bf16(vf0, pf[1][0], oacc[1][td], 0, 0, 0);
            short8 vf1 = *(const short8*)&Vc[(16*td + r15)*KLD + 32 + 8*quad];
            oacc[0][td] = __builtin_amdgcn_mfma_f32_16x16x32_bf16(vf1, pf[0][1], oacc[0][td], 0, 0, 0);
            oacc[1][td] = __builtin_amdgcn_mfma_f32_16x16x32_bf16(vf1, pf[1][1], oacc[1][td], 0, 0, 0);
        }
        __builtin_amdgcn_s_setprio(0);

        // write prefetched tile into the other buffer (vmcnt wait is ~free by now)
        *(uint4*)&Ksh[cur ^ 1][ldstK] = kreg;
        *(uint2*)&Vts[cur ^ 1][ldstV]     = make_uint2(vreg.x, vreg.y);
        *(uint2*)&Vts[cur ^ 1][ldstV + 8] = make_uint2(vreg.z, vreg.w);
        cur ^= 1;

        // drain own LDS ops, raw barrier (no vmcnt drain), fence scheduler
        asm volatile("s_waitcnt lgkmcnt(0)" ::: "memory");
        __builtin_amdgcn_s_barrier();
        __builtin_amdgcn_sched_barrier(0);
    }

    // emit UNNORMALIZED partials: lane holds O^T[vchan=16td+4quad+reg][qrow=r15]
#pragma unroll
    for (int u = 0; u < 2; u++) {
        size_t grow = rowbase + r0 + 32*w + 16*u + r15;
        ushort* op = obp + (size_t)half*((size_t)ROWS*448) + grow*448 + h*WCH;
#pragma unroll
        for (int td = 0; td < 4; td++) {
            uint2 o2;
            o2.x = cvt_pk_bf16(oacc[u][td][0], oacc[u][td][1]);
            o2.y = cvt_pk_bf16(oacc[u][td][2], oacc[u][td][3]);
            *(uint2*)&op[16*td + 4*quad] = o2;
        }
        if (quad == 0) {
            *(float2*)&ml[(grow*7 + h)*4 + half*2] = make_float2(mrun[u], lrun[u]);
        }
    }
}

// ---------------------------------------------------------------- fus GEMM (bf16 MFMA); A = split-K merge of bf16 partials; bias; stats
__global__ __launch_bounds__(256) void gemm_fus(const ushort* __restrict__ OBP, const float* __restrict__ ML,
                                                const ushort* __restrict__ Wb,
                                                const float* __restrict__ bias, float* __restrict__ C,
                                                float* __restrict__ sums) {
    __shared__ float red[4][128][2];
    int t = threadIdx.x;
    int r0 = blockIdx.x * 64, n0 = blockIdx.y * 128;
    int w = t >> 6, lane = t & 63;
    int r15 = lane & 15, quad = lane >> 4;
    int arow = 16*w + r15;
    short8 aq[14];
    {
        const ushort* p1 = OBP + (size_t)(r0 + arow)*448;
        const ushort* p2 = p1 + (size_t)ROWS*448;
        const float* mlr = ML + (size_t)(r0 + arow)*28;
        float w1[7], w2[7];
#pragma unroll
        for (int hh = 0; hh < 7; hh++) {
            float m1 = mlr[hh*4+0], l1 = mlr[hh*4+1];
            float m2 = mlr[hh*4+2], l2 = mlr[hh*4+3];
            float M  = fmaxf(m1, m2);
            float e1 = EXP2(m1 - M), e2 = EXP2(m2 - M);
            float inv = RCP(fmaf(e1, l1, e2*l2));
            w1[hh] = e1*inv; w2[hh] = e2*inv;
        }
#pragma unroll
        for (int kc = 0; kc < 14; kc++) {
            int k0 = 32*kc + 8*quad;
            short8 a1 = *(const short8*)(p1 + k0);
            short8 a2 = *(const short8*)(p2 + k0);
            const int hh = kc >> 1;   // head = (32kc+8q)>>6 = kc>>1 (8q<32)
            float c0 = fmaf(w1[hh], bf2f(a1[0]), w2[hh]*bf2f(a2[0]));
            float c1 = fmaf(w1[hh], bf2f(a1[1]), w2[hh]*bf2f(a2[1]));
            float c2 = fmaf(w1[hh], bf2f(a1[2]), w2[hh]*bf2f(a2[2]));
            float c3 = fmaf(w1[hh], bf2f(a1[3]), w2[hh]*bf2f(a2[3]));
            float c4 = fmaf(w1[hh], bf2f(a1[4]), w2[hh]*bf2f(a2[4]));
            float c5 = fmaf(w1[hh], bf2f(a1[5]), w2[hh]*bf2f(a2[5]));
            float c6 = fmaf(w1[hh], bf2f(a1[6]), w2[hh]*bf2f(a2[6]));
            float c7 = fmaf(w1[hh], bf2f(a1[7]), w2[hh]*bf2f(a2[7]));
            uint4 pk;
            pk.x = cvt_pk_bf16(c0, c1); pk.y = cvt_pk_bf16(c2, c3);
            pk.z = cvt_pk_bf16(c4, c5); pk.w = cvt_pk_bf16(c6, c7);
            aq[kc] = *(short8*)&pk;
        }
    }
    floatx4 zero4 = {0.f, 0.f, 0.f, 0.f};
    floatx4 acc[8];
#pragma unroll
    for (int st = 0; st < 8; st++) acc[st] = zero4;
    const ushort* wbase = Wb + 196608 + (size_t)(n0 + r15)*448 + 8*quad;
#pragma unroll
    for (int st = 0; st < 8; st++) {
        const ushort* wp = wbase + (size_t)(16*st)*448;
#pragma unroll
        for (int kc = 0; kc < 14; kc++) {
            short8 bf = *(const short8*)(wp + 32*kc);
            acc[st] = __builtin_amdgcn_mfma_f32_16x16x32_bf16(aq[kc], bf, acc[st], 0, 0, 0);
        }
    }
#pragma unroll
    for (int st = 0; st < 8; st++) {
        int col = n0 + 16*st + r15;
        float bi = bias[col];
        float v0 = acc[st][0] + bi, v1 = acc[st][1] + bi, v2 = acc[st][2] + bi, v3 = acc[st][3] + bi;
        float s  = (v0 + v1) + (v2 + v3);
        float q2 = (v0*v0 + v1*v1) + (v2*v2 + v3*v3);
        s  += __shfl_xor(s, 16, 64);  s  += __shfl_xor(s, 32, 64);
        q2 += __shfl_xor(q2, 16, 64); q2 += __shfl_xor(q2, 32, 64);
        if (lane < 16) { red[w][16*st + r15][0] = s; red[w][16*st + r15][1] = q2; }
        C[(size_t)(r0 + 16*w + 4*quad + 0)*256 + col] = v0;
        C[(size_t)(r0 + 16*w + 4*quad + 1)*256 + col] = v1;
        C[(size_t)(r0 + 16*w + 4*quad + 2)*256 + col] = v2;
        C[(size_t)(r0 + 16*w + 4*quad + 3)*256 + col] = v3;
    }
    __syncthreads();
    {
        int col = t >> 1, which = t & 1;
        float v = red[0][col][which] + red[1][col][which] + red[2][col][which] + red[3][col][which];
        atomicAdd(&sums[2560 + which*256 + n0 + col], v);
    }
}

// ---------------------------------------------------------------- fused: fus-BN+relu+residual+LN (per-row) + MLP GEMM + residual + transposed out
__global__ __launch_bounds__(256) void gemm_mlp_ln(const float* __restrict__ FUSP, const float* __restrict__ A,
                                                   const float* __restrict__ sums,
                                                   const float* __restrict__ g_fus, const float* __restrict__ b_fus,
                                                   const float* __restrict__ g_ln, const float* __restrict__ b_ln,
                                                   const float* __restrict__ W, const float* __restrict__ bias,
                                                   float* __restrict__ outp) {
    __shared__ float Ys[256][68];    // y (LN out), k-major: Ys[c][row]
    __shared__ float FFs[64][65];    // feature__ tile (cols n0..n0+63)
    __shared__ float Ws[16][68];
    __shared__ float tr[64][65];
    __shared__ float SC[256], SH[256], GL[256], BL[256];
    int t = threadIdx.x;
    int r0 = blockIdx.x*64, n0 = blockIdx.y*64;
    {
        float mean0 = sums[2560 + t] * (1.0f/(float)ROWS);
        float var0  = sums[2560 + 256 + t] * (1.0f/(float)ROWS) - mean0*mean0;
        float sc = g_fus[t] / sqrtf(var0 + 1e-5f);
        SC[t] = sc; SH[t] = b_fus[t] - mean0*sc;
        GL[t] = g_ln[t]; BL[t] = b_ln[t];
    }
    __syncthreads();
    int row = t >> 2, seg = t & 3;
    size_t rb = (size_t)(r0 + row)*256;
    float4 vv[16];
    float s = 0.f, ss = 0.f;
#pragma unroll
    for (int j = 0; j < 16; j++) {
        int c = seg*64 + 4*j;
        float4 fp = *(const float4*)&FUSP[rb + c];
        float4 fe = *(const float4*)&A[rb + c];
        float4 sc4 = *(const float4*)&SC[c];
        float4 sh4 = *(const float4*)&SH[c];
        float4 v;
        v.x = fmaxf(fmaf(sc4.x, fp.x, sh4.x), 0.f) + fe.x;
        v.y = fmaxf(fmaf(sc4.y, fp.y, sh4.y), 0.f) + fe.y;
        v.z = fmaxf(fmaf(sc4.z, fp.z, sh4.z), 0.f) + fe.z;
        v.w = fmaxf(fmaf(sc4.w, fp.w, sh4.w), 0.f) + fe.w;
        vv[j] = v;
        s  += (v.x + v.y) + (v.z + v.w);
        ss += (v.x*v.x + v.y*v.y) + (v.z*v.z + v.w*v.w);
        if (seg == blockIdx.y) *(float4*)&FFs[row][4*j] = v;
    }
    s  += __shfl_xor(s, 1, 64);  s  += __shfl_xor(s, 2, 64);
    ss += __shfl_xor(ss, 1, 64); ss += __shfl_xor(ss, 2, 64);
    float mean = s * (1.f/256.f);
    float var  = ss * (1.f/256.f) - mean*mean;
    float rin  = 1.f/sqrtf(var + 1e-5f);
#pragma unroll
    for (int j = 0; j < 16; j++) {
        int c = seg*64 + 4*j;
        float4 gl = *(const float4*)&GL[c];
        float4 bl = *(const float4*)&BL[c];
        float4 v = vv[j];
        Ys[c+0][row] = (v.x - mean)*rin*gl.x + bl.x;
        Ys[c+1][row] = (v.y - mean)*rin*gl.y + bl.y;
        Ys[c+2][row] = (v.z - mean)*rin*gl.z + bl.z;
        Ys[c+3][row] = (v.w - mean)*rin*gl.w + bl.w;
    }
    __syncthreads();
    // GEMM: y[64rows x 256] * W_mlp[n0..n0+63][256]^T
    int tx = t & 15, ty = t >> 4;
    int lk = t & 15, lm = t >> 4;
    float acc[4][4];
#pragma unroll
    for (int i = 0; i < 4; i++)
#pragma unroll
        for (int j = 0; j < 4; j++) acc[i][j] = 0.f;
    for (int k0 = 0; k0 < 256; k0 += 16) {
#pragma unroll
        for (int i2 = 0; i2 < 4; i2++)
            Ws[lk][lm + 16*i2] = W[(size_t)(n0 + lm + 16*i2)*256 + k0 + lk];
        __syncthreads();
#pragma unroll
        for (int kq = 0; kq < 16; kq++) {
            float4 a  = *(const float4*)&Ys[k0 + kq][4*ty];
            float4 b4 = *(const float4*)&Ws[kq][4*tx];
            float av[4] = {a.x, a.y, a.z, a.w};
            float bv[4] = {b4.x, b4.y, b4.z, b4.w};
#pragma unroll
            for (int i = 0; i < 4; i++)
#pragma unroll
                for (int j = 0; j < 4; j++) acc[i][j] = fmaf(av[i], bv[j], acc[i][j]);
        }
        __syncthreads();
    }
#pragma unroll
    for (int i = 0; i < 4; i++)
#pragma unroll
        for (int j = 0; j < 4; j++) {
            float v = acc[i][j] + bias[n0 + 4*tx + j] + FFs[4*ty + i][4*tx + j];
            tr[4*tx + j][4*ty + i] = v;
        }
    __syncthreads();
    int b = r0 >> 11, nbase = r0 & 2047;
#pragma unroll
    for (int rep = 0; rep < 16; rep++) {
        int e = t + 256*rep;
        int cl = e >> 6, nl = e & 63;
        outp[((size_t)(b*256 + n0 + cl))*2048 + nbase + nl] = tr[cl][nl];
    }
}

// ================================================================ host
extern "C" void kernel_launch(void* const* d_in, const int* in_sizes, int n_in,
                              void* d_out, int out_size, void* d_ws, size_t ws_size,
                              hipStream_t stream) {
    const float* xyz    = (const float*)d_in[0];
    const float* f      = (const float*)d_in[1];
    const float* W_geo  = (const float*)d_in[2];
    const float* g_geo  = (const float*)d_in[3];
    const float* b_geo  = (const float*)d_in[4];
    const float* W_feat = (const float*)d_in[5];
    const float* g_feat = (const float*)d_in[6];
    const float* b_feat = (const float*)d_in[7];
    const float* g_bn   = (const float*)d_in[8];
    const float* b_bn   = (const float*)d_in[9];
    const float* W_q    = (const float*)d_in[10];
    const float* g_q    = (const float*)d_in[11];
    const float* b_q    = (const float*)d_in[12];
    const float* W_k    = (const float*)d_in[13];
    const float* g_k    = (const float*)d_in[14];
    const float* b_k    = (const float*)d_in[15];
    const float* W_v    = (const float*)d_in[16];
    const float* g_v    = (const float*)d_in[17];
    const float* b_v    = (const float*)d_in[18];
    const float* W_fus  = (const float*)d_in[19];
    const float* bias_fus = (const float*)d_in[20];
    const float* g_fus  = (const float*)d_in[21];
    const float* b_fus  = (const float*)d_in[22];
    const float* g_ln   = (const float*)d_in[23];
    const float* b_ln   = (const float*)d_in[24];
    const float* W_mlp  = (const float*)d_in[25];
    const float* bias_mlp = (const float*)d_in[26];

    float* ws = (float*)d_ws;
    const size_t MBF = 262144;  // floats per MiB
    float* SUMS  = ws;
    int*   IDX   = (int*)(ws + 16384);
    float* A     = ws + 1*MBF;
    float* X     = ws + 9*MBF;
    ushort* QK16 = (ushort*)(ws + 9*MBF);
    float* FUSP  = ws + 9*MBF;
    float* CSEL  = ws + 17*MBF;
    float* QKVF  = ws + 17*MBF;
    ushort* OBP  = (ushort*)(ws + 17*MBF);   // 2 x 8192 x 448 bf16 = 14.7 MiB (17..31.7)
    float* ML    = ws + 33*MBF;              // 8192 x 7 x 4 floats = 0.92 MiB (33..34)
    ushort* VT16 = (ushort*)(ws + 45*MBF);
    ushort* WB16 = (ushort*)(ws + 49*MBF);

    prep_knn<<<2560, 256, 0, stream>>>(f, W_feat, xyz, W_geo, W_q, W_k, W_v, W_fus,
                                       X, A, WB16, SUMS, IDX);
    stats_gf<<<256, 256, 0, stream>>>(A, X, IDX, g_geo, g_feat, SUMS, CSEL);
    feature_maxsel<<<256, 256, 0, stream>>>(CSEL, SUMS, g_geo, b_geo, g_feat, b_feat, A, SUMS + 512);
    gemm_qkv<<<dim3(128, 3), 256, 0, stream>>>(A, SUMS, g_bn, b_bn, WB16, QKVF, SUMS);
    affine_qkv<<<dim3(128, 12), 256, 0, stream>>>(QKVF, SUMS, g_q, b_q, g_k, b_k, g_v, b_v, QK16, VT16);
    attn2<<<dim3(NPTS/256, NHEADS, NB*2), 512, 0, stream>>>(QK16, VT16, OBP, ML);
    gemm_fus<<<dim3(128, 2), 256, 0, stream>>>(OBP, ML, WB16, bias_fus, FUSP, SUMS);
    gemm_mlp_ln<<<dim3(128, 4), 256, 0, stream>>>(FUSP, A, SUMS, g_fus, b_fus, g_ln, b_ln,
                                                  W_mlp, bias_mlp, (float*)d_out);
}

// Round 12
// 357.774 us; speedup vs baseline: 1.5635x; 1.0397x over previous
//
#include <hip/hip_runtime.h>
#include <math.h>

#define NB    4
#define NPTS  2048
#define ROWS  (NB*NPTS)   // 8192
#define CIN   64
#define COUT  256
#define KNBR  21
#define NHEADS 7
#define WCH   64
#define DSH   32
#define LOG2E 1.4426950408889634f
#define KLD   72   // LDS row stride in ushorts = 144 B: multiple of 16 B (b128-aligned)

typedef __attribute__((ext_vector_type(8))) short short8;
typedef __attribute__((ext_vector_type(4))) float floatx4;

#if __has_builtin(__builtin_amdgcn_exp2f)
#define EXP2(x) __builtin_amdgcn_exp2f(x)
#else
#define EXP2(x) __expf((x)*0.6931471805599453f)
#endif
#if __has_builtin(__builtin_amdgcn_rcpf)
#define RCP(x) __builtin_amdgcn_rcpf(x)
#else
#define RCP(x) (1.0f/(x))
#endif

__device__ __forceinline__ ushort f2bf(float x) {
    unsigned u = __float_as_uint(x);
    u += 0x7fffu + ((u >> 16) & 1u);   // RNE
    return (ushort)(u >> 16);
}

__device__ __forceinline__ float bf2f(short u) {
    return __uint_as_float(((unsigned)(unsigned short)u) << 16);
}

// packed f32x2 -> bf16x2 (RNE), single VALU inst; no builtin on gfx950
__device__ __forceinline__ unsigned cvt_pk_bf16(float lo, float hi) {
    unsigned r;
    asm("v_cvt_pk_bf16_f32 %0, %1, %2" : "=v"(r) : "v"(lo), "v"(hi));
    return r;
}

// wave64 u32 min-reduce via DPP chain; broadcast via readlane(63)
template<int CTRL, int RMASK>
__device__ __forceinline__ unsigned dpp_umin_step(unsigned x) {
    unsigned t = (unsigned)__builtin_amdgcn_update_dpp((int)x, (int)x, CTRL, RMASK, 0xF, false);
    return (t < x) ? t : x;
}
__device__ __forceinline__ unsigned wave_min_u32(unsigned x) {
    x = dpp_umin_step<0x111, 0xF>(x);
    x = dpp_umin_step<0x112, 0xF>(x);
    x = dpp_umin_step<0x114, 0xF>(x);
    x = dpp_umin_step<0x118, 0xF>(x);
    x = dpp_umin_step<0x142, 0xA>(x);
    x = dpp_umin_step<0x143, 0xC>(x);
    return (unsigned)__builtin_amdgcn_readlane((int)x, 63);
}

__device__ __forceinline__ unsigned umin2(unsigned a, unsigned b) { return a < b ? a : b; }
__device__ __forceinline__ unsigned umax2(unsigned a, unsigned b) { return a < b ? b : a; }

// insert k into sorted ascending 6-list (m1 smallest); 11 min/max ops, static regs
__device__ __forceinline__ void ins6(unsigned &m1, unsigned &m2, unsigned &m3,
                                     unsigned &m4, unsigned &m5, unsigned &m6, unsigned k) {
    unsigned c = k, t;
    t = umin2(m1, c); c = umax2(m1, c); m1 = t;
    t = umin2(m2, c); c = umax2(m2, c); m2 = t;
    t = umin2(m3, c); c = umax2(m3, c); m3 = t;
    t = umin2(m4, c); c = umax2(m4, c); m4 = t;
    t = umin2(m5, c); c = umax2(m5, c); m5 = t;
    m6 = umin2(m6, c);
}

// ---------------------------------------------------------------- fused prep (blocks 0..511) + KNN (blocks 512..2559)
__global__ __launch_bounds__(256) void prep_knn(const float* __restrict__ f, const float* __restrict__ Wf,
                                                const float* __restrict__ xyz, const float* __restrict__ Wg,
                                                const float* __restrict__ W_q, const float* __restrict__ W_k,
                                                const float* __restrict__ W_v, const float* __restrict__ W_fus,
                                                float* __restrict__ X, float* __restrict__ A,
                                                ushort* __restrict__ Wb, float* __restrict__ sums,
                                                int* __restrict__ idx) {
    __shared__ float4 SXQ[2048];
    int t = threadIdx.x;
    int blk = blockIdx.x;
    if (blk < 512) {
        // ======== prep path ========
        float* As = (float*)SXQ;
        float* Ws = As + 16*68;
        int bx = blk & 127, by = blk >> 7;
        if (by == 0 && bx < 12) sums[bx*256 + t] = 0.f;
        int gid = (by*128 + bx)*256 + t;
        for (int i = gid; i < 311296; i += 131072) {
            const float* Wsrc; int off;
            if (i < 65536)       { Wsrc = W_q;   off = i; }
            else if (i < 131072) { Wsrc = W_k;   off = i - 65536; }
            else if (i < 196608) { Wsrc = W_v;   off = i - 131072; }
            else                 { Wsrc = W_fus; off = i - 196608; }
            Wb[i] = f2bf(Wsrc[off]);
        }
        int r0 = bx * 64, n0 = by * 64;
        for (int e = t; e < 4096; e += 256) {
            int row = r0 + (e >> 6), c = n0 + (e & 63), cc = c & 127;
            float x = xyz[row*3], y = xyz[row*3+1], z = xyz[row*3+2];
            const float* w = Wg + cc*6;
            float s = (c < 128) ? ((w[3]*x + w[4]*y) + w[5]*z)
                                : (((w[0]-w[3])*x + (w[1]-w[4])*y) + (w[2]-w[5])*z);
            A[(size_t)row*256 + c] = s;
        }
        int b = r0 >> 11, nbase = r0 & 2047;
        int tx = t & 15, ty = t >> 4;
        float acc[4][4];
#pragma unroll
        for (int i = 0; i < 4; i++)
#pragma unroll
            for (int j = 0; j < 4; j++) acc[i][j] = 0.f;
        int m64 = t & 63, kg = t >> 6;
        int lk = t & 15, lm = t >> 4;
        for (int k0 = 0; k0 < 64; k0 += 16) {
#pragma unroll
            for (int p = 0; p < 4; p++) {
                int k = kg*4 + p;
                As[k*68 + m64] = f[(size_t)b*CIN*NPTS + (size_t)(k0 + k)*NPTS + nbase + m64];
            }
#pragma unroll
            for (int i2 = 0; i2 < 4; i2++) {
                int cg = n0 + lm + 16*i2;
                Ws[lk*68 + lm + 16*i2] = Wf[(size_t)(cg & 127)*128 + (cg >> 7)*64 + k0 + lk];
            }
            __syncthreads();
#pragma unroll
            for (int kq = 0; kq < 16; kq++) {
                float4 a  = *(const float4*)&As[kq*68 + 4*ty];
                float4 b4 = *(const float4*)&Ws[kq*68 + 4*tx];
                float av[4] = {a.x, a.y, a.z, a.w};
                float bv[4] = {b4.x, b4.y, b4.z, b4.w};
#pragma unroll
                for (int i = 0; i < 4; i++)
#pragma unroll
                    for (int j = 0; j < 4; j++) acc[i][j] = fmaf(av[i], bv[j], acc[i][j]);
            }
            __syncthreads();
        }
#pragma unroll
        for (int i = 0; i < 4; i++)
#pragma unroll
            for (int j = 0; j < 4; j++)
                X[(size_t)(r0 + 4*ty + i)*256 + n0 + 4*tx + j] = acc[i][j];
        return;
    }
    // ======== KNN path ========
    int kb = blk - 512;
    int b = kb >> 9;
    int g = kb & 511;
    for (int m = t; m < NPTS; m += 256) {
        float x = xyz[(size_t)b*NPTS*3 + m*3];
        float y = xyz[(size_t)b*NPTS*3 + m*3 + 1];
        float z = xyz[(size_t)b*NPTS*3 + m*3 + 2];
        SXQ[m] = make_float4(x, y, z, (x*x + y*y) + z*z);
    }
    __syncthreads();
    int w = t >> 6, lane = t & 63;
    int n = g*4 + w;
    float4 q4 = SXQ[n];
    float qx = q4.x, qy = q4.y, qz = q4.z, sqn = q4.w;

    // two independent top-6 streams (halves dep chain); NO key[] array:
    // the rare exact-fallback recomputes keys from SXQ (bit-identical FP)
    // with a 32-bit taken-mask, keeping hot-path VGPR low for occupancy.
    unsigned a1 = 0xFFFFFFFFu, a2 = 0xFFFFFFFFu, a3 = 0xFFFFFFFFu,
             a4 = 0xFFFFFFFFu, a5 = 0xFFFFFFFFu, a6 = 0xFFFFFFFFu;
    unsigned c1 = 0xFFFFFFFFu, c2 = 0xFFFFFFFFu, c3 = 0xFFFFFFFFu,
             c4 = 0xFFFFFFFFu, c5 = 0xFFFFFFFFu, c6 = 0xFFFFFFFFu;
#pragma unroll
    for (int i = 0; i < 16; i++) {
        int m = lane + (i << 6);
        float4 p = SXQ[m];
        float dt = (qx*p.x + qy*p.y) + qz*p.z;
        float d2 = fmaxf((sqn + p.w) - 2.0f*dt, 0.f);
        unsigned kv = (__float_as_uint(d2) & 0xFFFFF800u) | (unsigned)m;
        ins6(a1, a2, a3, a4, a5, a6, kv);
    }
#pragma unroll
    for (int i = 16; i < 32; i++) {
        int m = lane + (i << 6);
        float4 p = SXQ[m];
        float dt = (qx*p.x + qy*p.y) + qz*p.z;
        float d2 = fmaxf((sqn + p.w) - 2.0f*dt, 0.f);
        unsigned kv = (__float_as_uint(d2) & 0xFFFFF800u) | (unsigned)m;
        ins6(c1, c2, c3, c4, c5, c6, kv);
    }
    // merge stream C into A -> per-lane sorted top-6
    ins6(a1, a2, a3, a4, a5, a6, c1);
    ins6(a1, a2, a3, a4, a5, a6, c2);
    ins6(a1, a2, a3, a4, a5, a6, c3);
    ins6(a1, a2, a3, a4, a5, a6, c4);
    ins6(a1, a2, a3, a4, a5, a6, c5);
    ins6(a1, a2, a3, a4, a5, a6, c6);

    unsigned winkey = 0xFFFFFFFFu;
    {
        // 32-round multiway merge-pop over per-lane sorted fronts.
        // Exact while no lane pops all 6 (checked below; keys unique via index bits).
        unsigned fr = a1, p2 = a2, p3 = a3, p4 = a4, p5 = a5, p6 = a6;
#pragma unroll
        for (int kk = 0; kk < 32; kk++) {
            unsigned win = wave_min_u32(fr);
            if (lane == kk) winkey = win;
            bool own = (fr == win);
            fr = own ? p2 : fr;
            p2 = own ? p3 : p2;
            p3 = own ? p4 : p3;
            p4 = own ? p5 : p4;
            p5 = own ? p6 : p5;
            p6 = own ? 0xFFFFFFFFu : p6;
        }
        if (__ballot(fr == 0xFFFFFFFFu) != 0ULL) {
            // rare fallback (some lane contributed >=6 of top-32): exact serial
            // extraction, recomputing keys from the untouched SXQ each round
            // (deterministic FP -> identical key values); taken-mask replaces
            // the old key[]-overwrite.
            winkey = 0xFFFFFFFFu;
            unsigned taken = 0u;
            for (int kk = 0; kk < 32; kk++) {
                unsigned lv = 0xFFFFFFFFu;
#pragma unroll
                for (int i = 0; i < 32; i++) {
                    int m = lane + (i << 6);
                    float4 p = SXQ[m];
                    float dt = (qx*p.x + qy*p.y) + qz*p.z;
                    float d2 = fmaxf((sqn + p.w) - 2.0f*dt, 0.f);
                    unsigned kv = (__float_as_uint(d2) & 0xFFFFF800u) | (unsigned)m;
                    kv = ((taken >> i) & 1u) ? 0xFFFFFFFFu : kv;
                    lv = (kv < lv) ? kv : lv;
                }
                unsigned win = wave_min_u32(lv);
                if (lane == kk) winkey = win;
                unsigned widx = win & 2047u;
                if (lane == (int)(widx & 63u)) taken |= (1u << (widx >> 6));
            }
        }
    }
    double d2r;
    int mr;
    {
        double qx64 = (double)qx, qy64 = (double)qy, qz64 = (double)qz;
        double sqn64 = qx64*qx64 + qy64*qy64 + qz64*qz64;
        if (lane < 32) {
            mr = (int)(winkey & 2047u);
            float4 p = SXQ[mr];
            double x = (double)p.x, y = (double)p.y, z = (double)p.z;
            double sqm = x*x + y*y + z*z;
            double dt  = qx64*x + qy64*y + qz64*z;
            d2r = (sqn64 + sqm) - 2.0*dt;
        } else {
            d2r = INFINITY; mr = 0x7FFFFFFF;
        }
    }
#pragma unroll
    for (int k = 2; k <= 32; k <<= 1) {
#pragma unroll
        for (int j = k >> 1; j > 0; j >>= 1) {
            double od = __shfl_xor(d2r, j, 64);
            int    om = __shfl_xor(mr, j, 64);
            bool up    = ((lane & k) == 0);
            bool lower = ((lane & j) == 0);
            bool oless = (od < d2r) || (od == d2r && om < mr);
            bool keepOther = up ? (lower ? oless : !oless) : (lower ? !oless : oless);
            if (keepOther) { d2r = od; mr = om; }
        }
    }
    if (lane < KNBR)
        idx[((size_t)b*NPTS + n)*KNBR + lane] = mr;
}

// ---------------------------------------------------------------- stats + sign-selected extreme over K
__global__ __launch_bounds__(256) void stats_gf(const float* __restrict__ geoBC, const float* __restrict__ featAC,
                                                const int* __restrict__ idx, const float* __restrict__ g_geo,
                                                const float* __restrict__ g_feat,
                                                float* __restrict__ sums, float* __restrict__ xsel) {
    int c = threadIdx.x;
    int cc = c & 127;
    const float* base = (c < 128) ? geoBC : featAC;
    bool wantmax = ((c < 128) ? g_geo[cc] : g_feat[cc]) >= 0.f;
    float s = 0.f, ss = 0.f;
    int r0 = blockIdx.x * 32;
    for (int r = r0; r < r0 + 32; r++) {
        int b = r >> 11;
        float ctr = base[(size_t)r*256 + 128 + cc];
        float mx = -1e30f, mn = 1e30f;
        const int* ip = idx + (size_t)r*KNBR;
        for (int kk = 0; kk < KNBR; kk++) {
            int j = ip[kk];
            float xv = ctr + base[((size_t)(b*NPTS + j))*256 + cc];
            mx = fmaxf(mx, xv); mn = fminf(mn, xv);
            s += xv; ss += xv*xv;
        }
        xsel[(size_t)r*256 + c] = wantmax ? mx : mn;
    }
    atomicAdd(&sums[c], s);
    atomicAdd(&sums[256 + c], ss);
}

// ---------------------------------------------------------------- feature_ = relu(affine(xsel)) with inline BN finalize; + bn1 stats
__global__ __launch_bounds__(256) void feature_maxsel(const float* __restrict__ xsel, const float* __restrict__ sums,
                                                      const float* __restrict__ g_geo, const float* __restrict__ b_geo,
                                                      const float* __restrict__ g_feat, const float* __restrict__ b_feat,
                                                      float* __restrict__ feat, float* __restrict__ sums_bn1) {
    int c = threadIdx.x;
    const float inv = 1.0f / (float)(ROWS*KNBR);
    float mean = sums[c]*inv;
    float var  = sums[256+c]*inv - mean*mean;
    float g  = (c < 128) ? g_geo[c] : g_feat[c-128];
    float bb = (c < 128) ? b_geo[c] : b_feat[c-128];
    float sc = g / sqrtf(var + 1e-5f);
    float tt = bb - mean*sc;
    float s = 0.f, ss = 0.f;
    int r0 = blockIdx.x*32;
    for (int r = r0; r < r0+32; r++) {
        size_t i = (size_t)r*256 + c;
        float y = fmaxf(fmaf(sc, xsel[i], tt), 0.f);
        feat[i] = y; s += y; ss += y*y;
    }
    atomicAdd(&sums_bn1[c], s); atomicAdd(&sums_bn1[256+c], ss);
}

// ---------------------------------------------------------------- q/k/v GEMM via bf16 MFMA; inline bn1 finalize on A
__global__ __launch_bounds__(256) void gemm_qkv(const float* __restrict__ Af, const float* __restrict__ sums_in,
                                                const float* __restrict__ g_bn, const float* __restrict__ b_bn,
                                                const ushort* __restrict__ Wb,
                                                float* __restrict__ QKVF, float* __restrict__ sums) {
    __shared__ float bns[2][256];
    __shared__ float red[4][256][2];
    int t = threadIdx.x;
    int r0 = blockIdx.x * 64, g = blockIdx.y;
    int w = t >> 6, lane = t & 63;
    int r15 = lane & 15, quad = lane >> 4;
    {
        float mean = sums_in[512 + t] * (1.0f/(float)ROWS);
        float var  = sums_in[768 + t] * (1.0f/(float)ROWS) - mean*mean;
        float sc = g_bn[t] / sqrtf(var + 1e-5f);
        bns[0][t] = sc;
        bns[1][t] = b_bn[t] - mean*sc;
    }
    __syncthreads();
    short8 aq[8];
    {
        const float* ap = Af + (size_t)(r0 + 16*w + r15)*256;
#pragma unroll
        for (int kc = 0; kc < 8; kc++) {
            int k0 = 32*kc + 8*quad;
            float4 a0 = *(const float4*)&ap[k0];
            float4 a1 = *(const float4*)&ap[k0+4];
            float4 s0 = *(const float4*)&bns[0][k0];
            float4 s1 = *(const float4*)&bns[0][k0+4];
            float4 h0 = *(const float4*)&bns[1][k0];
            float4 h1 = *(const float4*)&bns[1][k0+4];
            ushort u8[8];
            u8[0] = f2bf(fmaf(s0.x, a0.x, h0.x)); u8[1] = f2bf(fmaf(s0.y, a0.y, h0.y));
            u8[2] = f2bf(fmaf(s0.z, a0.z, h0.z)); u8[3] = f2bf(fmaf(s0.w, a0.w, h0.w));
            u8[4] = f2bf(fmaf(s1.x, a1.x, h1.x)); u8[5] = f2bf(fmaf(s1.y, a1.y, h1.y));
            u8[6] = f2bf(fmaf(s1.z, a1.z, h1.z)); u8[7] = f2bf(fmaf(s1.w, a1.w, h1.w));
            aq[kc] = *(short8*)u8;
        }
    }
    floatx4 zero4 = {0.f, 0.f, 0.f, 0.f};
    floatx4 acc[16];
#pragma unroll
    for (int st = 0; st < 16; st++) acc[st] = zero4;
    const ushort* wbase = Wb + (size_t)g*65536 + (size_t)r15*256 + 8*quad;
#pragma unroll
    for (int st = 0; st < 16; st++) {
        const ushort* wp = wbase + (size_t)(16*st)*256;
#pragma unroll
        for (int kc = 0; kc < 8; kc++) {
            short8 bf = *(const short8*)(wp + 32*kc);
            acc[st] = __builtin_amdgcn_mfma_f32_16x16x32_bf16(aq[kc], bf, acc[st], 0, 0, 0);
        }
    }
#pragma unroll
    for (int st = 0; st < 16; st++) {
        float s  = (acc[st][0] + acc[st][1]) + (acc[st][2] + acc[st][3]);
        float q2 = (acc[st][0]*acc[st][0] + acc[st][1]*acc[st][1]) +
                   (acc[st][2]*acc[st][2] + acc[st][3]*acc[st][3]);
        s  += __shfl_xor(s, 16, 64);  s  += __shfl_xor(s, 32, 64);
        q2 += __shfl_xor(q2, 16, 64); q2 += __shfl_xor(q2, 32, 64);
        if (lane < 16) { red[w][16*st + r15][0] = s; red[w][16*st + r15][1] = q2; }
#pragma unroll
        for (int reg = 0; reg < 4; reg++)
            QKVF[(size_t)(r0 + 16*w + 4*quad + reg)*768 + g*256 + 16*st + r15] = acc[st][reg];
    }
    __syncthreads();
    {
        float s = red[0][t][0] + red[1][t][0] + red[2][t][0] + red[3][t][0];
        float q = red[0][t][1] + red[1][t][1] + red[2][t][1] + red[3][t][1];
        atomicAdd(&sums[1024 + g*512 + t], s);
        atomicAdd(&sums[1024 + g*512 + 256 + t], q);
    }
}

// ---------------------------------------------------------------- affine+relu+bf16 (inline qkv BN finalize): q/k row-major (q scaled by log2e), v transposed
__global__ __launch_bounds__(256) void affine_qkv(const float* __restrict__ QKVF, const float* __restrict__ sums,
                                                  const float* __restrict__ g_q, const float* __restrict__ b_q,
                                                  const float* __restrict__ g_k, const float* __restrict__ b_k,
                                                  const float* __restrict__ g_v, const float* __restrict__ b_v,
                                                  ushort* __restrict__ qk, ushort* __restrict__ vt) {
    __shared__ float sts[6][256];
    __shared__ ushort tile[64][72];
    int t = threadIdx.x;
    {
        const float* gs[3] = {g_q, g_k, g_v};
        const float* bs[3] = {b_q, b_k, b_v};
#pragma unroll
        for (int g = 0; g < 3; g++) {
            float mean = sums[1024 + g*512 + t] * (1.0f/(float)ROWS);
            float var  = sums[1024 + g*512 + 256 + t] * (1.0f/(float)ROWS) - mean*mean;
            float sc = gs[g][t] / sqrtf(var + 1e-5f);
            float sh = bs[g][t] - mean*sc;
            if (g == 0) { sc *= LOG2E; sh *= LOG2E; }   // exp2-domain softmax
            sts[2*g][t] = sc;
            sts[2*g+1][t] = sh;
        }
    }
    __syncthreads();
    int r0 = blockIdx.x * 64, c0 = blockIdx.y * 64;
    int b = r0 >> 11, nbase = r0 & 2047;
    if (c0 < 512) {
#pragma unroll
        for (int rep = 0; rep < 16; rep++) {
            int e = t + 256*rep;
            int row = e >> 6, c = e & 63;
            int col = c0 + c, g = col >> 8, cc = col & 255;
            float v = QKVF[(size_t)(r0 + row)*768 + col];
            v = fmaxf(fmaf(sts[2*g][cc], v, sts[2*g+1][cc]), 0.f);
            qk[(size_t)(r0 + row)*512 + col] = f2bf(v);
        }
    } else {
#pragma unroll
        for (int rep = 0; rep < 16; rep++) {
            int e = t + 256*rep;
            int row = e >> 6, c = e & 63;
            int col = c0 + c, cc = col & 255;
            float v = QKVF[(size_t)(r0 + row)*768 + col];
            v = fmaxf(fmaf(sts[4][cc], v, sts[5][cc]), 0.f);
            tile[c][row] = f2bf(v);
        }
        __syncthreads();
#pragma unroll
        for (int rep = 0; rep < 16; rep++) {
            int e = t + 256*rep;
            int cc = e >> 6, nn = e & 63;
            vt[((size_t)(b*256 + (c0 - 512) + cc))*2048 + nbase + nn] = tile[cc][nn];
        }
    }
}

// ---------------------------------------------------------------- MFMA bf16 flash attention v9: split-K + QBLK=32/wave.
// LDS-throughput-bound regime (R10 counters): each K/V fragment read now feeds
// BOTH u-tiles' MFMAs -> ~1.8x fewer LDS cycles per Q-row. 8 waves x QBLK=32 =
// 256 rows/block; split-K halves (16 KV tiles each) keep grid at 448 blocks.
// sigma-permuted V, P in registers, K+V LDS double-buffered (KLD=72=144B),
// raw-barrier pipeline. Emits unnormalized bf16 partials + (m,l); merge in gemm_fus.
__global__ __launch_bounds__(512) void attn2(const ushort* __restrict__ qk, const ushort* __restrict__ vt,
                                             ushort* __restrict__ obp, float* __restrict__ ml) {
    __shared__ ushort Ksh[2][64*KLD];
    __shared__ ushort Vts[2][64*KLD];
    int h = blockIdx.y;
    int z = blockIdx.z, b = z >> 1, half = z & 1;
    int r0 = blockIdx.x * 256;
    int t = threadIdx.x;
    int w = t >> 6, lane = t & 63;
    int r15 = lane & 15, quad = lane >> 4;
    size_t rowbase = (size_t)b*NPTS;
    int hoff = h*DSH;
    int rr = t >> 3, c8 = t & 7;
    int mstart = half << 10, mend = mstart + 1024;

    const ushort* ksrc = qk + (rowbase + rr)*512 + 256 + hoff + 8*c8;     // + m0*512
    const ushort* vsrc = vt + ((size_t)(b*256 + hoff + rr))*2048 + 8*c8;  // + m0
    int ldstK = rr*KLD + 8*c8;
    // sigma-mapped V staging base: local keys 8*c8+jj -> slots vb+jj (jj<4), vb+8+(jj-4)
    int vb = 4*((c8 >> 1) & 1) + 16*(c8 & 1) + 32*(c8 >> 2);
    int ldstV = rr*KLD + vb;

    short8 aq[2][2];
#pragma unroll
    for (int u = 0; u < 2; u++)
#pragma unroll
        for (int s = 0; s < 2; s++)
            aq[u][s] = *(const short8*)(qk + (rowbase + r0 + 32*w + 16*u + r15)*512 + hoff + 32*s + 8*quad);

    // stage this half's first tile into buffer 0
    {
        uint4 k0 = *(const uint4*)(ksrc + (size_t)mstart*512);
        uint4 v0 = *(const uint4*)(vsrc + mstart);
        *(uint4*)&Ksh[0][ldstK] = k0;
        *(uint2*)&Vts[0][ldstV]     = make_uint2(v0.x, v0.y);
        *(uint2*)&Vts[0][ldstV + 8] = make_uint2(v0.z, v0.w);
    }

    floatx4 zero4 = {0.f, 0.f, 0.f, 0.f};
    floatx4 oacc[2][4];
    float mrun[2], lrun[2];
#pragma unroll
    for (int u = 0; u < 2; u++) {
        mrun[u] = -1e30f; lrun[u] = 0.f;
#pragma unroll
        for (int i = 0; i < 4; i++) oacc[u][i] = zero4;
    }

    asm volatile("s_waitcnt lgkmcnt(0)" ::: "memory");
    __builtin_amdgcn_s_barrier();
    __builtin_amdgcn_sched_barrier(0);

    int cur = 0;
    for (int m0 = mstart; m0 < mend; m0 += 64) {
        // prefetch next KV tile into registers (latency hides under compute)
        int mnext = (m0 + 64 < mend) ? (m0 + 64) : mstart;
        uint4 kreg = *(const uint4*)(ksrc + (size_t)mnext*512);
        uint4 vreg = *(const uint4*)(vsrc + mnext);

        const ushort* Kc = Ksh[cur];
        const ushort* Vc = Vts[cur];

        // S = K * Q^T for both u-tiles: one K-frag read feeds 2 MFMAs
        floatx4 sacc[2][4];
#pragma unroll
        for (int u = 0; u < 2; u++)
#pragma unroll
            for (int tt = 0; tt < 4; tt++) sacc[u][tt] = zero4;
        __builtin_amdgcn_s_setprio(1);
#pragma unroll
        for (int tt = 0; tt < 4; tt++) {
            int key = 16*tt + r15;
#pragma unroll
            for (int s = 0; s < 2; s++) {
                short8 kf = *(const short8*)&Kc[key*KLD + 32*s + 8*quad];
                sacc[0][tt] = __builtin_amdgcn_mfma_f32_16x16x32_bf16(kf, aq[0][s], sacc[0][tt], 0, 0, 0);
                sacc[1][tt] = __builtin_amdgcn_mfma_f32_16x16x32_bf16(kf, aq[1][s], sacc[1][tt], 0, 0, 0);
            }
        }
        __builtin_amdgcn_s_setprio(0);

        // softmax per u-tile; P packed directly into PV B-frags (sigma space)
        short8 pf[2][2];
#pragma unroll
        for (int u = 0; u < 2; u++) {
            float mx = sacc[u][0][0];
#pragma unroll
            for (int tt = 0; tt < 4; tt++)
#pragma unroll
                for (int reg = 0; reg < 4; reg++) mx = fmaxf(mx, sacc[u][tt][reg]);
            mx = fmaxf(mx, __shfl_xor(mx, 16, 64));
            mx = fmaxf(mx, __shfl_xor(mx, 32, 64));

            // defer-rescale: alpha==1 exactly when no row in the wave got a new max
            if (!__all(mx <= mrun[u])) {
                float mnew = fmaxf(mrun[u], mx);
                float alpha = EXP2(mrun[u] - mnew);
                lrun[u] *= alpha;
#pragma unroll
                for (int td = 0; td < 4; td++) oacc[u][td] *= alpha;
                mrun[u] = mnew;
            }

            float pm[4][4];
            float rs = 0.f;
#pragma unroll
            for (int tt = 0; tt < 4; tt++) {
#pragma unroll
                for (int reg = 0; reg < 4; reg++) {
                    float p = EXP2(sacc[u][tt][reg] - mrun[u]);
                    pm[tt][reg] = p; rs += p;
                }
            }
            rs += __shfl_xor(rs, 16, 64);
            rs += __shfl_xor(rs, 32, 64);
            lrun[u] += rs;

            uint4 pk0, pk1;
            pk0.x = cvt_pk_bf16(pm[0][0], pm[0][1]); pk0.y = cvt_pk_bf16(pm[0][2], pm[0][3]);
            pk0.z = cvt_pk_bf16(pm[1][0], pm[1][1]); pk0.w = cvt_pk_bf16(pm[1][2], pm[1][3]);
            pk1.x = cvt_pk_bf16(pm[2][0], pm[2][1]); pk1.y = cvt_pk_bf16(pm[2][2], pm[2][3]);
            pk1.z = cvt_pk_bf16(pm[3][0], pm[3][1]); pk1.w = cvt_pk_bf16(pm[3][2], pm[3][3]);
            pf[u][0] = *(short8*)&pk0;
            pf[u][1] = *(short8*)&pk1;
        }

        // O^T += V^T * P^T : one V-frag read feeds both u-tiles
        __builtin_amdgcn_s_setprio(1);
#pragma unroll
        for (int td = 0; td < 4; td++) {
            short8 vf0 = *(const short8*)&Vc[(16*td + r15)*KLD + 8*quad];
            oacc[0][td] = __builtin_amdgcn_mfma_f32_16x16x32_bf16(vf0, pf[0][0], oacc[0][td], 0, 0, 0);
            oacc[1][td] = __builtin_amdgcn_mfma_f32_16x16x32_bf16(vf0, pf[1][0], oacc[1][td], 0, 0, 0);
            short8 vf1 = *(const short8*)&Vc[(16*td + r15)*KLD + 32 + 8*quad];
            oacc[0][td] = __builtin_amdgcn_mfma_f32_16x16x32_bf16(vf1, pf[0][1], oacc[0][td], 0, 0, 0);
            oacc[1][td] = __builtin_amdgcn_mfma_f32_16x16x32_bf16(vf1, pf[1][1], oacc[1][td], 0, 0, 0);
        }
        __builtin_amdgcn_s_setprio(0);

        // write prefetched tile into the other buffer (vmcnt wait is ~free by now)
        *(uint4*)&Ksh[cur ^ 1][ldstK] = kreg;
        *(uint2*)&Vts[cur ^ 1][ldstV]     = make_uint2(vreg.x, vreg.y);
        *(uint2*)&Vts[cur ^ 1][ldstV + 8] = make_uint2(vreg.z, vreg.w);
        cur ^= 1;

        // drain own LDS ops, raw barrier (no vmcnt drain), fence scheduler
        asm volatile("s_waitcnt lgkmcnt(0)" ::: "memory");
        __builtin_amdgcn_s_barrier();
        __builtin_amdgcn_sched_barrier(0);
    }

    // emit UNNORMALIZED partials: lane holds O^T[vchan=16td+4quad+reg][qrow=r15]
#pragma unroll
    for (int u = 0; u < 2; u++) {
        size_t grow = rowbase + r0 + 32*w + 16*u + r15;
        ushort* op = obp + (size_t)half*((size_t)ROWS*448) + grow*448 + h*WCH;
#pragma unroll
        for (int td = 0; td < 4; td++) {
            uint2 o2;
            o2.x = cvt_pk_bf16(oacc[u][td][0], oacc[u][td][1]);
            o2.y = cvt_pk_bf16(oacc[u][td][2], oacc[u][td][3]);
            *(uint2*)&op[16*td + 4*quad] = o2;
        }
        if (quad == 0) {
            *(float2*)&ml[(grow*7 + h)*4 + half*2] = make_float2(mrun[u], lrun[u]);
        }
    }
}

// ---------------------------------------------------------------- fus GEMM (bf16 MFMA); A = split-K merge of bf16 partials; bias; stats
__global__ __launch_bounds__(256) void gemm_fus(const ushort* __restrict__ OBP, const float* __restrict__ ML,
                                                const ushort* __restrict__ Wb,
                                                const float* __restrict__ bias, float* __restrict__ C,
                                                float* __restrict__ sums) {
    __shared__ float red[4][128][2];
    int t = threadIdx.x;
    int r0 = blockIdx.x * 64, n0 = blockIdx.y * 128;
    int w = t >> 6, lane = t & 63;
    int r15 = lane & 15, quad = lane >> 4;
    int arow = 16*w + r15;
    short8 aq[14];
    {
        const ushort* p1 = OBP + (size_t)(r0 + arow)*448;
        const ushort* p2 = p1 + (size_t)ROWS*448;
        const float* mlr = ML + (size_t)(r0 + arow)*28;
        float w1[7], w2[7];
#pragma unroll
        for (int hh = 0; hh < 7; hh++) {
            float m1 = mlr[hh*4+0], l1 = mlr[hh*4+1];
            float m2 = mlr[hh*4+2], l2 = mlr[hh*4+3];
            float M  = fmaxf(m1, m2);
            float e1 = EXP2(m1 - M), e2 = EXP2(m2 - M);
            float inv = RCP(fmaf(e1, l1, e2*l2));
            w1[hh] = e1*inv; w2[hh] = e2*inv;
        }
#pragma unroll
        for (int kc = 0; kc < 14; kc++) {
            int k0 = 32*kc + 8*quad;
            short8 a1 = *(const short8*)(p1 + k0);
            short8 a2 = *(const short8*)(p2 + k0);
            const int hh = kc >> 1;   // head = (32kc+8q)>>6 = kc>>1 (8q<32)
            float c0 = fmaf(w1[hh], bf2f(a1[0]), w2[hh]*bf2f(a2[0]));
            float c1 = fmaf(w1[hh], bf2f(a1[1]), w2[hh]*bf2f(a2[1]));
            float c2 = fmaf(w1[hh], bf2f(a1[2]), w2[hh]*bf2f(a2[2]));
            float c3 = fmaf(w1[hh], bf2f(a1[3]), w2[hh]*bf2f(a2[3]));
            float c4 = fmaf(w1[hh], bf2f(a1[4]), w2[hh]*bf2f(a2[4]));
            float c5 = fmaf(w1[hh], bf2f(a1[5]), w2[hh]*bf2f(a2[5]));
            float c6 = fmaf(w1[hh], bf2f(a1[6]), w2[hh]*bf2f(a2[6]));
            float c7 = fmaf(w1[hh], bf2f(a1[7]), w2[hh]*bf2f(a2[7]));
            uint4 pk;
            pk.x = cvt_pk_bf16(c0, c1); pk.y = cvt_pk_bf16(c2, c3);
            pk.z = cvt_pk_bf16(c4, c5); pk.w = cvt_pk_bf16(c6, c7);
            aq[kc] = *(short8*)&pk;
        }
    }
    floatx4 zero4 = {0.f, 0.f, 0.f, 0.f};
    floatx4 acc[8];
#pragma unroll
    for (int st = 0; st < 8; st++) acc[st] = zero4;
    const ushort* wbase = Wb + 196608 + (size_t)(n0 + r15)*448 + 8*quad;
#pragma unroll
    for (int st = 0; st < 8; st++) {
        const ushort* wp = wbase + (size_t)(16*st)*448;
#pragma unroll
        for (int kc = 0; kc < 14; kc++) {
            short8 bf = *(const short8*)(wp + 32*kc);
            acc[st] = __builtin_amdgcn_mfma_f32_16x16x32_bf16(aq[kc], bf, acc[st], 0, 0, 0);
        }
    }
#pragma unroll
    for (int st = 0; st < 8; st++) {
        int col = n0 + 16*st + r15;
        float bi = bias[col];
        float v0 = acc[st][0] + bi, v1 = acc[st][1] + bi, v2 = acc[st][2] + bi, v3 = acc[st][3] + bi;
        float s  = (v0 + v1) + (v2 + v3);
        float q2 = (v0*v0 + v1*v1) + (v2*v2 + v3*v3);
        s  += __shfl_xor(s, 16, 64);  s  += __shfl_xor(s, 32, 64);
        q2 += __shfl_xor(q2, 16, 64); q2 += __shfl_xor(q2, 32, 64);
        if (lane < 16) { red[w][16*st + r15][0] = s; red[w][16*st + r15][1] = q2; }
        C[(size_t)(r0 + 16*w + 4*quad + 0)*256 + col] = v0;
        C[(size_t)(r0 + 16*w + 4*quad + 1)*256 + col] = v1;
        C[(size_t)(r0 + 16*w + 4*quad + 2)*256 + col] = v2;
        C[(size_t)(r0 + 16*w + 4*quad + 3)*256 + col] = v3;
    }
    __syncthreads();
    {
        int col = t >> 1, which = t & 1;
        float v = red[0][col][which] + red[1][col][which] + red[2][col][which] + red[3][col][which];
        atomicAdd(&sums[2560 + which*256 + n0 + col], v);
    }
}

// ---------------------------------------------------------------- fused: fus-BN+relu+residual+LN (per-row) + MLP GEMM + residual + transposed out
__global__ __launch_bounds__(256) void gemm_mlp_ln(const float* __restrict__ FUSP, const float* __restrict__ A,
                                                   const float* __restrict__ sums,
                                                   const float* __restrict__ g_fus, const float* __restrict__ b_fus,
                                                   const float* __restrict__ g_ln, const float* __restrict__ b_ln,
                                                   const float* __restrict__ W, const float* __restrict__ bias,
                                                   float* __restrict__ outp) {
    __shared__ float Ys[256][68];    // y (LN out), k-major: Ys[c][row]
    __shared__ float FFs[64][65];    // feature__ tile (cols n0..n0+63)
    __shared__ float Ws[16][68];
    __shared__ float tr[64][65];
    __shared__ float SC[256], SH[256], GL[256], BL[256];
    int t = threadIdx.x;
    int r0 = blockIdx.x*64, n0 = blockIdx.y*64;
    {
        float mean0 = sums[2560 + t] * (1.0f/(float)ROWS);
        float var0  = sums[2560 + 256 + t] * (1.0f/(float)ROWS) - mean0*mean0;
        float sc = g_fus[t] / sqrtf(var0 + 1e-5f);
        SC[t] = sc; SH[t] = b_fus[t] - mean0*sc;
        GL[t] = g_ln[t]; BL[t] = b_ln[t];
    }
    __syncthreads();
    int row = t >> 2, seg = t & 3;
    size_t rb = (size_t)(r0 + row)*256;
    float4 vv[16];
    float s = 0.f, ss = 0.f;
#pragma unroll
    for (int j = 0; j < 16; j++) {
        int c = seg*64 + 4*j;
        float4 fp = *(const float4*)&FUSP[rb + c];
        float4 fe = *(const float4*)&A[rb + c];
        float4 sc4 = *(const float4*)&SC[c];
        float4 sh4 = *(const float4*)&SH[c];
        float4 v;
        v.x = fmaxf(fmaf(sc4.x, fp.x, sh4.x), 0.f) + fe.x;
        v.y = fmaxf(fmaf(sc4.y, fp.y, sh4.y), 0.f) + fe.y;
        v.z = fmaxf(fmaf(sc4.z, fp.z, sh4.z), 0.f) + fe.z;
        v.w = fmaxf(fmaf(sc4.w, fp.w, sh4.w), 0.f) + fe.w;
        vv[j] = v;
        s  += (v.x + v.y) + (v.z + v.w);
        ss += (v.x*v.x + v.y*v.y) + (v.z*v.z + v.w*v.w);
        if (seg == blockIdx.y) *(float4*)&FFs[row][4*j] = v;
    }
    s  += __shfl_xor(s, 1, 64);  s  += __shfl_xor(s, 2, 64);
    ss += __shfl_xor(ss, 1, 64); ss += __shfl_xor(ss, 2, 64);
    float mean = s * (1.f/256.f);
    float var  = ss * (1.f/256.f) - mean*mean;
    float rin  = 1.f/sqrtf(var + 1e-5f);
#pragma unroll
    for (int j = 0; j < 16; j++) {
        int c = seg*64 + 4*j;
        float4 gl = *(const float4*)&GL[c];
        float4 bl = *(const float4*)&BL[c];
        float4 v = vv[j];
        Ys[c+0][row] = (v.x - mean)*rin*gl.x + bl.x;
        Ys[c+1][row] = (v.y - mean)*rin*gl.y + bl.y;
        Ys[c+2][row] = (v.z - mean)*rin*gl.z + bl.z;
        Ys[c+3][row] = (v.w - mean)*rin*gl.w + bl.w;
    }
    __syncthreads();
    // GEMM: y[64rows x 256] * W_mlp[n0..n0+63][256]^T
    int tx = t & 15, ty = t >> 4;
    int lk = t & 15, lm = t >> 4;
    float acc[4][4];
#pragma unroll
    for (int i = 0; i < 4; i++)
#pragma unroll
        for (int j = 0; j < 4; j++) acc[i][j] = 0.f;
    for (int k0 = 0; k0 < 256; k0 += 16) {
#pragma unroll
        for (int i2 = 0; i2 < 4; i2++)
            Ws[lk][lm + 16*i2] = W[(size_t)(n0 + lm + 16*i2)*256 + k0 + lk];
        __syncthreads();
#pragma unroll
        for (int kq = 0; kq < 16; kq++) {
            float4 a  = *(const float4*)&Ys[k0 + kq][4*ty];
            float4 b4 = *(const float4*)&Ws[kq][4*tx];
            float av[4] = {a.x, a.y, a.z, a.w};
            float bv[4] = {b4.x, b4.y, b4.z, b4.w};
#pragma unroll
            for (int i = 0; i < 4; i++)
#pragma unroll
                for (int j = 0; j < 4; j++) acc[i][j] = fmaf(av[i], bv[j], acc[i][j]);
        }
        __syncthreads();
    }
#pragma unroll
    for (int i = 0; i < 4; i++)
#pragma unroll
        for (int j = 0; j < 4; j++) {
            float v = acc[i][j] + bias[n0 + 4*tx + j] + FFs[4*ty + i][4*tx + j];
            tr[4*tx + j][4*ty + i] = v;
        }
    __syncthreads();
    int b = r0 >> 11, nbase = r0 & 2047;
#pragma unroll
    for (int rep = 0; rep < 16; rep++) {
        int e = t + 256*rep;
        int cl = e >> 6, nl = e & 63;
        outp[((size_t)(b*256 + n0 + cl))*2048 + nbase + nl] = tr[cl][nl];
    }
}

// ================================================================ host
extern "C" void kernel_launch(void* const* d_in, const int* in_sizes, int n_in,
                              void* d_out, int out_size, void* d_ws, size_t ws_size,
                              hipStream_t stream) {
    const float* xyz    = (const float*)d_in[0];
    const float* f      = (const float*)d_in[1];
    const float* W_geo  = (const float*)d_in[2];
    const float* g_geo  = (const float*)d_in[3];
    const float* b_geo  = (const float*)d_in[4];
    const float* W_feat = (const float*)d_in[5];
    const float* g_feat = (const float*)d_in[6];
    const float* b_feat = (const float*)d_in[7];
    const float* g_bn   = (const float*)d_in[8];
    const float* b_bn   = (const float*)d_in[9];
    const float* W_q    = (const float*)d_in[10];
    const float* g_q    = (const float*)d_in[11];
    const float* b_q    = (const float*)d_in[12];
    const float* W_k    = (const float*)d_in[13];
    const float* g_k    = (const float*)d_in[14];
    const float* b_k    = (const float*)d_in[15];
    const float* W_v    = (const float*)d_in[16];
    const float* g_v    = (const float*)d_in[17];
    const float* b_v    = (const float*)d_in[18];
    const float* W_fus  = (const float*)d_in[19];
    const float* bias_fus = (const float*)d_in[20];
    const float* g_fus  = (const float*)d_in[21];
    const float* b_fus  = (const float*)d_in[22];
    const float* g_ln   = (const float*)d_in[23];
    const float* b_ln   = (const float*)d_in[24];
    const float* W_mlp  = (const float*)d_in[25];
    const float* bias_mlp = (const float*)d_in[26];

    float* ws = (float*)d_ws;
    const size_t MBF = 262144;  // floats per MiB
    float* SUMS  = ws;
    int*   IDX   = (int*)(ws + 16384);
    float* A     = ws + 1*MBF;
    float* X     = ws + 9*MBF;
    ushort* QK16 = (ushort*)(ws + 9*MBF);
    float* FUSP  = ws + 9*MBF;
    float* CSEL  = ws + 17*MBF;
    float* QKVF  = ws + 17*MBF;
    ushort* OBP  = (ushort*)(ws + 17*MBF);   // 2 x 8192 x 448 bf16 = 14.7 MiB (17..31.7)
    float* ML    = ws + 33*MBF;              // 8192 x 7 x 4 floats = 0.92 MiB (33..34)
    ushort* VT16 = (ushort*)(ws + 45*MBF);
    ushort* WB16 = (ushort*)(ws + 49*MBF);

    prep_knn<<<2560, 256, 0, stream>>>(f, W_feat, xyz, W_geo, W_q, W_k, W_v, W_fus,
                                       X, A, WB16, SUMS, IDX);
    stats_gf<<<256, 256, 0, stream>>>(A, X, IDX, g_geo, g_feat, SUMS, CSEL);
    feature_maxsel<<<256, 256, 0, stream>>>(CSEL, SUMS, g_geo, b_geo, g_feat, b_feat, A, SUMS + 512);
    gemm_qkv<<<dim3(128, 3), 256, 0, stream>>>(A, SUMS, g_bn, b_bn, WB16, QKVF, SUMS);
    affine_qkv<<<dim3(128, 12), 256, 0, stream>>>(QKVF, SUMS, g_q, b_q, g_k, b_k, g_v, b_v, QK16, VT16);
    attn2<<<dim3(NPTS/256, NHEADS, NB*2), 512, 0, stream>>>(QK16, VT16, OBP, ML);
    gemm_fus<<<dim3(128, 2), 256, 0, stream>>>(OBP, ML, WB16, bias_fus, FUSP, SUMS);
    gemm_mlp_ln<<<dim3(128, 4), 256, 0, stream>>>(FUSP, A, SUMS, g_fus, b_fus, g_ln, b_ln,
                                                  W_mlp, bias_mlp, (float*)d_out);
}